// Round 1
// baseline (3575.611 us; speedup 1.0000x reference)
//
#include <hip/hip_runtime.h>
#include <hip/hip_bf16.h>

#define NN 50000
#define EE 400000
#define MM 3

// ---------------- CSR build ----------------

__global__ __launch_bounds__(256) void init_kernel(int* counts, float* wsum) {
    int idx = blockIdx.x * 256 + threadIdx.x;
    if (idx < MM * NN) counts[idx] = 0;
    if (idx < MM) wsum[idx] = 0.0f;
}

__global__ __launch_bounds__(256) void hist_kernel(const int* __restrict__ dst,
                                                   int* __restrict__ counts) {
    int m = blockIdx.y;
    int e = blockIdx.x * 256 + threadIdx.x;
    if (e < EE) atomicAdd(&counts[m * NN + dst[m * EE + e]], 1);
}

__global__ __launch_bounds__(1024) void scan_kernel(const int* __restrict__ counts,
                                                    int* __restrict__ row_ptr,
                                                    int* __restrict__ cursor) {
    int m = blockIdx.x;
    const int* c = counts + m * NN;
    int* rp = row_ptr + m * (NN + 1);
    int* cur = cursor + m * (NN + 1);
    __shared__ int sh[1024];
    int carry = 0;
    for (int base = 0; base < NN; base += 1024) {
        int i = base + threadIdx.x;
        int v = (i < NN) ? c[i] : 0;
        sh[threadIdx.x] = v;
        __syncthreads();
        for (int off = 1; off < 1024; off <<= 1) {
            int t = (threadIdx.x >= off) ? sh[threadIdx.x - off] : 0;
            __syncthreads();
            sh[threadIdx.x] += t;
            __syncthreads();
        }
        int incl = sh[threadIdx.x];
        if (i < NN) { int excl = carry + incl - v; rp[i] = excl; cur[i] = excl; }
        int tot = sh[1023];
        __syncthreads();
        carry += tot;
    }
    if (threadIdx.x == 0) { rp[NN] = carry; cur[NN] = carry; }
}

__global__ __launch_bounds__(256) void scatter_kernel(const int* __restrict__ src,
                                                      const int* __restrict__ dst,
                                                      int* __restrict__ cursor,
                                                      int* __restrict__ ssrc) {
    int m = blockIdx.y;
    int e = blockIdx.x * 256 + threadIdx.x;
    if (e < EE) {
        int d = dst[m * EE + e];
        int pos = atomicAdd(&cursor[m * (NN + 1) + d], 1);
        ssrc[m * EE + pos] = src[m * EE + e];
    }
}

// ---------------- GEMM: C[nrows x ncols] = A[nrows x 256] @ W[256 x ldw] ----------------
// BM=64, BN=64, KT=32, 256 threads, 4x4 micro-tile. K fixed at 256.

__global__ __launch_bounds__(256) void gemm64(const float* __restrict__ A,
                                              const float* __restrict__ W,
                                              float* __restrict__ C,
                                              const float* __restrict__ bias,
                                              int nrows, int ldw, int ldc) {
    __shared__ float As[32][68];   // [k][m]
    __shared__ float Bs[32][68];   // [k][n]
    const int t = threadIdx.x;
    const int tm = t & 15, tn = t >> 4;
    const int row0 = blockIdx.x * 64;
    const int col0 = blockIdx.y * 64;
    float acc[4][4] = {};
    for (int k0 = 0; k0 < 256; k0 += 32) {
#pragma unroll
        for (int u = 0; u < 2; ++u) {
            int idx = t * 2 + u;          // 0..511
            int r = idx >> 3;             // 0..63
            int kc = (idx & 7) << 2;      // 0,4,..,28
            int row = row0 + r;
            float4 v = make_float4(0.f, 0.f, 0.f, 0.f);
            if (row < nrows) v = *(const float4*)(A + (size_t)row * 256 + k0 + kc);
            As[kc + 0][r] = v.x; As[kc + 1][r] = v.y;
            As[kc + 2][r] = v.z; As[kc + 3][r] = v.w;
        }
#pragma unroll
        for (int u = 0; u < 2; ++u) {
            int idx = t * 2 + u;
            int kr = idx >> 4;            // 0..31
            int c4 = (idx & 15) << 2;     // 0..60
            float4 v = *(const float4*)(W + (size_t)(k0 + kr) * ldw + col0 + c4);
            Bs[kr][c4 + 0] = v.x; Bs[kr][c4 + 1] = v.y;
            Bs[kr][c4 + 2] = v.z; Bs[kr][c4 + 3] = v.w;
        }
        __syncthreads();
#pragma unroll
        for (int k = 0; k < 32; ++k) {
            float a[4], b[4];
#pragma unroll
            for (int i = 0; i < 4; ++i) a[i] = As[k][tm * 4 + i];
#pragma unroll
            for (int j = 0; j < 4; ++j) b[j] = Bs[k][tn * 4 + j];
#pragma unroll
            for (int i = 0; i < 4; ++i)
#pragma unroll
                for (int j = 0; j < 4; ++j)
                    acc[i][j] = fmaf(a[i], b[j], acc[i][j]);
        }
        __syncthreads();
    }
#pragma unroll
    for (int i = 0; i < 4; ++i) {
        int row = row0 + tm * 4 + i;
        if (row >= nrows) continue;
#pragma unroll
        for (int j = 0; j < 4; ++j) {
            int col = col0 + tn * 4 + j;
            float v = acc[i][j];
            if (bias) v += bias[col];
            C[(size_t)row * ldc + col] = v;
        }
    }
}

// ---------------- per-node attention scores el/er ----------------

__global__ __launch_bounds__(256) void eler_kernel(const float* __restrict__ feat,
                                                   const float* __restrict__ al,
                                                   const float* __restrict__ ar,
                                                   float* __restrict__ el,
                                                   float* __restrict__ er) {
    int wave = threadIdx.x >> 6;
    int lane = threadIdx.x & 63;
    int n = blockIdx.x * 4 + wave;
    if (n >= NN) return;
    const float* f = feat + (size_t)n * 256;
#pragma unroll
    for (int h = 0; h < 4; ++h) {
        float v = f[h * 64 + lane];
        float pl = v * al[h * 64 + lane];
        float pr = v * ar[h * 64 + lane];
#pragma unroll
        for (int off = 32; off; off >>= 1) {
            pl += __shfl_down(pl, off);
            pr += __shfl_down(pr, off);
        }
        if (lane == 0) { el[n * 4 + h] = pl; er[n * 4 + h] = pr; }
    }
}

// ---------------- edge-softmax aggregation (one wave per dst node) ----------------
// out[n] = elu( sum_j exp(leaky(el[s_j]+er[n])) * feat[s_j] / sum_j exp(...) + bias )
// (segment_max skipped: it cancels exactly in msg/denom; |e| is small.)

__global__ __launch_bounds__(256) void agg_edges_kernel(const float* __restrict__ feat,
                                                        const float* __restrict__ el,
                                                        const float* __restrict__ er,
                                                        const int* __restrict__ row_ptr,
                                                        const int* __restrict__ ssrc,
                                                        const float* __restrict__ bias,
                                                        float* __restrict__ out) {
    int wave = threadIdx.x >> 6;
    int lane = threadIdx.x & 63;
    int n = blockIdx.x * 4 + wave;
    if (n >= NN) return;
    int beg = row_ptr[n], end = row_ptr[n + 1];
    float4 ern = ((const float4*)er)[n];
    float acc[4] = {0.f, 0.f, 0.f, 0.f};
    float den[4] = {0.f, 0.f, 0.f, 0.f};
    for (int j = beg; j < end; ++j) {
        int s = ssrc[j];
        float4 els = ((const float4*)el)[s];
        const float* fs = feat + (size_t)s * 256;
        float e0 = els.x + ern.x; e0 = e0 > 0.f ? e0 : 0.2f * e0; float w0 = __expf(e0);
        float e1 = els.y + ern.y; e1 = e1 > 0.f ? e1 : 0.2f * e1; float w1 = __expf(e1);
        float e2 = els.z + ern.z; e2 = e2 > 0.f ? e2 : 0.2f * e2; float w2 = __expf(e2);
        float e3 = els.w + ern.w; e3 = e3 > 0.f ? e3 : 0.2f * e3; float w3 = __expf(e3);
        acc[0] = fmaf(w0, fs[lane], acc[0]);       den[0] += w0;
        acc[1] = fmaf(w1, fs[64 + lane], acc[1]);  den[1] += w1;
        acc[2] = fmaf(w2, fs[128 + lane], acc[2]); den[2] += w2;
        acc[3] = fmaf(w3, fs[192 + lane], acc[3]); den[3] += w3;
    }
#pragma unroll
    for (int h = 0; h < 4; ++h) {
        float o = acc[h] / fmaxf(den[h], 1e-9f) + bias[h * 64 + lane];
        out[(size_t)n * 256 + h * 64 + lane] = o > 0.f ? o : __expf(o) - 1.0f;
    }
}

// ---------------- semantic attention ----------------

__global__ __launch_bounds__(256) void sem_reduce_kernel(const float* __restrict__ v,
                                                         const float* __restrict__ b1,
                                                         const float* __restrict__ W2,
                                                         float* __restrict__ wsum, int m) {
    int wave = threadIdx.x >> 6;
    int lane = threadIdx.x & 63;
    int n = blockIdx.x * 4 + wave;
    if (n >= NN) return;
    float t = tanhf(v[(size_t)n * 64 + lane] + b1[lane]) * W2[lane];
#pragma unroll
    for (int off = 32; off; off >>= 1) t += __shfl_down(t, off);
    if (lane == 0) atomicAdd(&wsum[m], t);
}

__global__ void beta_kernel(const float* __restrict__ wsum, float* __restrict__ beta) {
    if (threadIdx.x == 0 && blockIdx.x == 0) {
        float w0 = wsum[0] / (float)NN, w1 = wsum[1] / (float)NN, w2 = wsum[2] / (float)NN;
        float mx = fmaxf(w0, fmaxf(w1, w2));
        float e0 = __expf(w0 - mx), e1 = __expf(w1 - mx), e2 = __expf(w2 - mx);
        float s = e0 + e1 + e2;
        beta[0] = e0 / s; beta[1] = e1 / s; beta[2] = e2 / s;
    }
}

__global__ __launch_bounds__(256) void combine_kernel(const float* __restrict__ Hb,
                                                      const float* __restrict__ beta,
                                                      float* __restrict__ aggout) {
    size_t idx = (size_t)blockIdx.x * 256 + threadIdx.x;
    if (idx >= (size_t)NN * 256) return;
    float b0 = beta[0], b1 = beta[1], b2 = beta[2];
    aggout[idx] = Hb[idx] * b0 + Hb[(size_t)NN * 256 + idx] * b1
                + Hb[2 * (size_t)NN * 256 + idx] * b2;
}

// ---------------- host launch ----------------

extern "C" void kernel_launch(void* const* d_in, const int* in_sizes, int n_in,
                              void* d_out, int out_size, void* d_ws, size_t ws_size,
                              hipStream_t stream) {
    const float* x        = (const float*)d_in[0];   // (M,N,256)
    const float* W_gat    = (const float*)d_in[1];   // (L,M,256,256)
    const float* attn_l   = (const float*)d_in[2];   // (L,M,4,64)
    const float* attn_r   = (const float*)d_in[3];
    const float* bias_gat = (const float*)d_in[4];   // (L,M,256)
    const float* W1       = (const float*)d_in[5];   // (256,64)
    const float* b1       = (const float*)d_in[6];   // (64,)
    const float* W2       = (const float*)d_in[7];   // (64,1)
    const float* Wp       = (const float*)d_in[8];   // (256,64)
    const float* bp       = (const float*)d_in[9];   // (64,)
    const int*   src      = (const int*)d_in[10];    // (M,E)
    const int*   dst      = (const int*)d_in[11];    // (M,E)
    float* out = (float*)d_out;                      // (N,64)

    char* ws = (char*)d_ws;
    size_t off = 0;
    auto alloc = [&](size_t bytes) { size_t o = off; off = (off + bytes + 255) & ~(size_t)255; return o; };
    float* Hbuf    = (float*)(ws + alloc((size_t)MM * NN * 256 * 4));
    float* feat    = (float*)(ws + alloc((size_t)NN * 256 * 4));
    float* el      = (float*)(ws + alloc((size_t)NN * 4 * 4));
    float* er      = (float*)(ws + alloc((size_t)NN * 4 * 4));
    int*   counts  = (int*)(ws + alloc((size_t)MM * NN * 4));
    int*   row_ptr = (int*)(ws + alloc((size_t)MM * (NN + 1) * 4));
    int*   cursor  = (int*)(ws + alloc((size_t)MM * (NN + 1) * 4));
    int*   ssrc    = (int*)(ws + alloc((size_t)MM * EE * 4));
    float* wsum    = (float*)(ws + alloc(16));
    float* beta    = (float*)(ws + alloc(16));

    // CSR build (src/dst shared across both layers)
    init_kernel<<<dim3((MM * NN + 255) / 256), 256, 0, stream>>>(counts, wsum);
    hist_kernel<<<dim3((EE + 255) / 256, MM), 256, 0, stream>>>(dst, counts);
    scan_kernel<<<dim3(MM), 1024, 0, stream>>>(counts, row_ptr, cursor);
    scatter_kernel<<<dim3((EE + 255) / 256, MM), 256, 0, stream>>>(src, dst, cursor, ssrc);

    const int rowTiles = (NN + 63) / 64;
    const int nodeBlocks = (NN + 3) / 4;

    for (int l = 0; l < 2; ++l) {
        for (int i = 0; i < MM; ++i) {
            const float* A = (l == 0) ? (x + (size_t)i * NN * 256)
                                      : (Hbuf + (size_t)i * NN * 256);
            const float* W = W_gat + (size_t)(l * MM + i) * 256 * 256;
            gemm64<<<dim3(rowTiles, 4), 256, 0, stream>>>(A, W, feat, nullptr, NN, 256, 256);
            eler_kernel<<<dim3(nodeBlocks), 256, 0, stream>>>(
                feat, attn_l + (size_t)(l * MM + i) * 256, attn_r + (size_t)(l * MM + i) * 256,
                el, er);
            agg_edges_kernel<<<dim3(nodeBlocks), 256, 0, stream>>>(
                feat, el, er, row_ptr + (size_t)i * (NN + 1), ssrc + (size_t)i * EE,
                bias_gat + (size_t)(l * MM + i) * 256, Hbuf + (size_t)i * NN * 256);
        }
    }

    // semantic attention: w_m = mean_n tanh(z @ W1 + b1) @ W2 ; beta = softmax(w)
    for (int i = 0; i < MM; ++i) {
        gemm64<<<dim3(rowTiles, 1), 256, 0, stream>>>(
            Hbuf + (size_t)i * NN * 256, W1, feat, nullptr, NN, 64, 64);
        sem_reduce_kernel<<<dim3(nodeBlocks), 256, 0, stream>>>(feat, b1, W2, wsum, i);
    }
    beta_kernel<<<dim3(1), 64, 0, stream>>>(wsum, beta);
    combine_kernel<<<dim3((NN * 256 + 255) / 256), 256, 0, stream>>>(Hbuf, beta, feat);
    // final projection: out = agg @ Wp + bp
    gemm64<<<dim3(rowTiles, 1), 256, 0, stream>>>(feat, Wp, out, bp, NN, 64, 64);
}

// Round 2
// 1627.591 us; speedup vs baseline: 2.1969x; 2.1969x over previous
//
#include <hip/hip_runtime.h>
#include <hip/hip_bf16.h>

#define NN 50000
#define EE 400000
#define MM 3

// ---------------- CSR build ----------------

__global__ __launch_bounds__(256) void init_kernel(int* counts, float* wsum) {
    int idx = blockIdx.x * 256 + threadIdx.x;
    if (idx < MM * NN) counts[idx] = 0;
    if (idx < MM) wsum[idx] = 0.0f;
}

__global__ __launch_bounds__(256) void hist_kernel(const int* __restrict__ dst,
                                                   int* __restrict__ counts) {
    int m = blockIdx.y;
    int e = blockIdx.x * 256 + threadIdx.x;
    if (e < EE) atomicAdd(&counts[m * NN + dst[m * EE + e]], 1);
}

__global__ __launch_bounds__(1024) void scan_kernel(const int* __restrict__ counts,
                                                    int* __restrict__ row_ptr,
                                                    int* __restrict__ cursor) {
    int m = blockIdx.x;
    const int* c = counts + m * NN;
    int* rp = row_ptr + m * (NN + 1);
    int* cur = cursor + m * (NN + 1);
    __shared__ int sh[1024];
    int carry = 0;
    for (int base = 0; base < NN; base += 1024) {
        int i = base + threadIdx.x;
        int v = (i < NN) ? c[i] : 0;
        sh[threadIdx.x] = v;
        __syncthreads();
        for (int off = 1; off < 1024; off <<= 1) {
            int t = (threadIdx.x >= off) ? sh[threadIdx.x - off] : 0;
            __syncthreads();
            sh[threadIdx.x] += t;
            __syncthreads();
        }
        int incl = sh[threadIdx.x];
        if (i < NN) { int excl = carry + incl - v; rp[i] = excl; cur[i] = excl; }
        int tot = sh[1023];
        __syncthreads();
        carry += tot;
    }
    if (threadIdx.x == 0) { rp[NN] = carry; cur[NN] = carry; }
}

__global__ __launch_bounds__(256) void scatter_kernel(const int* __restrict__ src,
                                                      const int* __restrict__ dst,
                                                      int* __restrict__ cursor,
                                                      int* __restrict__ ssrc) {
    int m = blockIdx.y;
    int e = blockIdx.x * 256 + threadIdx.x;
    if (e < EE) {
        int d = dst[m * EE + e];
        int pos = atomicAdd(&cursor[m * (NN + 1) + d], 1);
        ssrc[m * EE + pos] = src[m * EE + e];
    }
}

// ---------------- GEMM: C[nrows x ncols] = A[nrows x 256] @ W[256 x ldw] ----------------
// BM=64, BN=64, KT=32, 256 threads, 4x4 micro-tile. K fixed at 256.

__global__ __launch_bounds__(256) void gemm64(const float* __restrict__ A,
                                              const float* __restrict__ W,
                                              float* __restrict__ C,
                                              const float* __restrict__ bias,
                                              int nrows, int ldw, int ldc) {
    __shared__ float As[32][68];   // [k][m]
    __shared__ float Bs[32][68];   // [k][n]
    const int t = threadIdx.x;
    const int tm = t & 15, tn = t >> 4;
    const int row0 = blockIdx.x * 64;
    const int col0 = blockIdx.y * 64;
    float acc[4][4] = {};
    for (int k0 = 0; k0 < 256; k0 += 32) {
#pragma unroll
        for (int u = 0; u < 2; ++u) {
            int idx = t * 2 + u;          // 0..511
            int r = idx >> 3;             // 0..63
            int kc = (idx & 7) << 2;      // 0,4,..,28
            int row = row0 + r;
            float4 v = make_float4(0.f, 0.f, 0.f, 0.f);
            if (row < nrows) v = *(const float4*)(A + (size_t)row * 256 + k0 + kc);
            As[kc + 0][r] = v.x; As[kc + 1][r] = v.y;
            As[kc + 2][r] = v.z; As[kc + 3][r] = v.w;
        }
#pragma unroll
        for (int u = 0; u < 2; ++u) {
            int idx = t * 2 + u;
            int kr = idx >> 4;            // 0..31
            int c4 = (idx & 15) << 2;     // 0..60
            float4 v = *(const float4*)(W + (size_t)(k0 + kr) * ldw + col0 + c4);
            Bs[kr][c4 + 0] = v.x; Bs[kr][c4 + 1] = v.y;
            Bs[kr][c4 + 2] = v.z; Bs[kr][c4 + 3] = v.w;
        }
        __syncthreads();
#pragma unroll
        for (int k = 0; k < 32; ++k) {
            float a[4], b[4];
#pragma unroll
            for (int i = 0; i < 4; ++i) a[i] = As[k][tm * 4 + i];
#pragma unroll
            for (int j = 0; j < 4; ++j) b[j] = Bs[k][tn * 4 + j];
#pragma unroll
            for (int i = 0; i < 4; ++i)
#pragma unroll
                for (int j = 0; j < 4; ++j)
                    acc[i][j] = fmaf(a[i], b[j], acc[i][j]);
        }
        __syncthreads();
    }
#pragma unroll
    for (int i = 0; i < 4; ++i) {
        int row = row0 + tm * 4 + i;
        if (row >= nrows) continue;
#pragma unroll
        for (int j = 0; j < 4; ++j) {
            int col = col0 + tn * 4 + j;
            float v = acc[i][j];
            if (bias) v += bias[col];
            C[(size_t)row * ldc + col] = v;
        }
    }
}

// ---------------- per-node attention scores el/er ----------------

__global__ __launch_bounds__(256) void eler_kernel(const float* __restrict__ feat,
                                                   const float* __restrict__ al,
                                                   const float* __restrict__ ar,
                                                   float* __restrict__ el,
                                                   float* __restrict__ er) {
    int wave = threadIdx.x >> 6;
    int lane = threadIdx.x & 63;
    int n = blockIdx.x * 4 + wave;
    if (n >= NN) return;
    const float* f = feat + (size_t)n * 256;
#pragma unroll
    for (int h = 0; h < 4; ++h) {
        float v = f[h * 64 + lane];
        float pl = v * al[h * 64 + lane];
        float pr = v * ar[h * 64 + lane];
#pragma unroll
        for (int off = 32; off; off >>= 1) {
            pl += __shfl_down(pl, off);
            pr += __shfl_down(pr, off);
        }
        if (lane == 0) { el[n * 4 + h] = pl; er[n * 4 + h] = pr; }
    }
}

// ---------------- edge-softmax aggregation (one wave per dst node) ----------------
// out[n] = elu( sum_j exp(leaky(el[s_j]+er[n])) * feat[s_j] / sum_j exp(...) + bias )
// (segment_max skipped: it cancels exactly in msg/denom; |e| is small.)

__global__ __launch_bounds__(256) void agg_edges_kernel(const float* __restrict__ feat,
                                                        const float* __restrict__ el,
                                                        const float* __restrict__ er,
                                                        const int* __restrict__ row_ptr,
                                                        const int* __restrict__ ssrc,
                                                        const float* __restrict__ bias,
                                                        float* __restrict__ out) {
    int wave = threadIdx.x >> 6;
    int lane = threadIdx.x & 63;
    int n = blockIdx.x * 4 + wave;
    if (n >= NN) return;
    int beg = row_ptr[n], end = row_ptr[n + 1];
    float4 ern = ((const float4*)er)[n];
    float acc[4] = {0.f, 0.f, 0.f, 0.f};
    float den[4] = {0.f, 0.f, 0.f, 0.f};
    for (int j = beg; j < end; ++j) {
        int s = ssrc[j];
        float4 els = ((const float4*)el)[s];
        const float* fs = feat + (size_t)s * 256;
        float e0 = els.x + ern.x; e0 = e0 > 0.f ? e0 : 0.2f * e0; float w0 = __expf(e0);
        float e1 = els.y + ern.y; e1 = e1 > 0.f ? e1 : 0.2f * e1; float w1 = __expf(e1);
        float e2 = els.z + ern.z; e2 = e2 > 0.f ? e2 : 0.2f * e2; float w2 = __expf(e2);
        float e3 = els.w + ern.w; e3 = e3 > 0.f ? e3 : 0.2f * e3; float w3 = __expf(e3);
        acc[0] = fmaf(w0, fs[lane], acc[0]);       den[0] += w0;
        acc[1] = fmaf(w1, fs[64 + lane], acc[1]);  den[1] += w1;
        acc[2] = fmaf(w2, fs[128 + lane], acc[2]); den[2] += w2;
        acc[3] = fmaf(w3, fs[192 + lane], acc[3]); den[3] += w3;
    }
#pragma unroll
    for (int h = 0; h < 4; ++h) {
        float o = acc[h] / fmaxf(den[h], 1e-9f) + bias[h * 64 + lane];
        out[(size_t)n * 256 + h * 64 + lane] = o > 0.f ? o : __expf(o) - 1.0f;
    }
}

// ---------------- semantic attention ----------------
// Grid-stride + block-level reduction: ONE atomicAdd per block (was: one per
// wave = 50000 serialized atomics on a single address = 636 us/launch).

__global__ __launch_bounds__(256) void sem_reduce_kernel(const float* __restrict__ v,
                                                         const float* __restrict__ b1,
                                                         const float* __restrict__ W2,
                                                         float* __restrict__ wsum, int m) {
    __shared__ float sh[4];
    int wave = threadIdx.x >> 6;
    int lane = threadIdx.x & 63;
    float bw = b1[lane];
    float w2 = W2[lane];
    float t = 0.f;
    for (int n = blockIdx.x * 4 + wave; n < NN; n += gridDim.x * 4) {
        t += tanhf(v[(size_t)n * 64 + lane] + bw) * w2;
    }
#pragma unroll
    for (int off = 32; off; off >>= 1) t += __shfl_down(t, off);
    if (lane == 0) sh[wave] = t;
    __syncthreads();
    if (threadIdx.x == 0) atomicAdd(&wsum[m], sh[0] + sh[1] + sh[2] + sh[3]);
}

__global__ void beta_kernel(const float* __restrict__ wsum, float* __restrict__ beta) {
    if (threadIdx.x == 0 && blockIdx.x == 0) {
        float w0 = wsum[0] / (float)NN, w1 = wsum[1] / (float)NN, w2 = wsum[2] / (float)NN;
        float mx = fmaxf(w0, fmaxf(w1, w2));
        float e0 = __expf(w0 - mx), e1 = __expf(w1 - mx), e2 = __expf(w2 - mx);
        float s = e0 + e1 + e2;
        beta[0] = e0 / s; beta[1] = e1 / s; beta[2] = e2 / s;
    }
}

__global__ __launch_bounds__(256) void combine_kernel(const float* __restrict__ Hb,
                                                      const float* __restrict__ beta,
                                                      float* __restrict__ aggout) {
    size_t idx = (size_t)blockIdx.x * 256 + threadIdx.x;
    if (idx >= (size_t)NN * 256) return;
    float b0 = beta[0], b1 = beta[1], b2 = beta[2];
    aggout[idx] = Hb[idx] * b0 + Hb[(size_t)NN * 256 + idx] * b1
                + Hb[2 * (size_t)NN * 256 + idx] * b2;
}

// ---------------- host launch ----------------

extern "C" void kernel_launch(void* const* d_in, const int* in_sizes, int n_in,
                              void* d_out, int out_size, void* d_ws, size_t ws_size,
                              hipStream_t stream) {
    const float* x        = (const float*)d_in[0];   // (M,N,256)
    const float* W_gat    = (const float*)d_in[1];   // (L,M,256,256)
    const float* attn_l   = (const float*)d_in[2];   // (L,M,4,64)
    const float* attn_r   = (const float*)d_in[3];
    const float* bias_gat = (const float*)d_in[4];   // (L,M,256)
    const float* W1       = (const float*)d_in[5];   // (256,64)
    const float* b1       = (const float*)d_in[6];   // (64,)
    const float* W2       = (const float*)d_in[7];   // (64,1)
    const float* Wp       = (const float*)d_in[8];   // (256,64)
    const float* bp       = (const float*)d_in[9];   // (64,)
    const int*   src      = (const int*)d_in[10];    // (M,E)
    const int*   dst      = (const int*)d_in[11];    // (M,E)
    float* out = (float*)d_out;                      // (N,64)

    char* ws = (char*)d_ws;
    size_t off = 0;
    auto alloc = [&](size_t bytes) { size_t o = off; off = (off + bytes + 255) & ~(size_t)255; return o; };
    float* Hbuf    = (float*)(ws + alloc((size_t)MM * NN * 256 * 4));
    float* feat    = (float*)(ws + alloc((size_t)NN * 256 * 4));
    float* el      = (float*)(ws + alloc((size_t)NN * 4 * 4));
    float* er      = (float*)(ws + alloc((size_t)NN * 4 * 4));
    int*   counts  = (int*)(ws + alloc((size_t)MM * NN * 4));
    int*   row_ptr = (int*)(ws + alloc((size_t)MM * (NN + 1) * 4));
    int*   cursor  = (int*)(ws + alloc((size_t)MM * (NN + 1) * 4));
    int*   ssrc    = (int*)(ws + alloc((size_t)MM * EE * 4));
    float* wsum    = (float*)(ws + alloc(16));
    float* beta    = (float*)(ws + alloc(16));

    // CSR build (src/dst shared across both layers)
    init_kernel<<<dim3((MM * NN + 255) / 256), 256, 0, stream>>>(counts, wsum);
    hist_kernel<<<dim3((EE + 255) / 256, MM), 256, 0, stream>>>(dst, counts);
    scan_kernel<<<dim3(MM), 1024, 0, stream>>>(counts, row_ptr, cursor);
    scatter_kernel<<<dim3((EE + 255) / 256, MM), 256, 0, stream>>>(src, dst, cursor, ssrc);

    const int rowTiles = (NN + 63) / 64;
    const int nodeBlocks = (NN + 3) / 4;

    for (int l = 0; l < 2; ++l) {
        for (int i = 0; i < MM; ++i) {
            const float* A = (l == 0) ? (x + (size_t)i * NN * 256)
                                      : (Hbuf + (size_t)i * NN * 256);
            const float* W = W_gat + (size_t)(l * MM + i) * 256 * 256;
            gemm64<<<dim3(rowTiles, 4), 256, 0, stream>>>(A, W, feat, nullptr, NN, 256, 256);
            eler_kernel<<<dim3(nodeBlocks), 256, 0, stream>>>(
                feat, attn_l + (size_t)(l * MM + i) * 256, attn_r + (size_t)(l * MM + i) * 256,
                el, er);
            agg_edges_kernel<<<dim3(nodeBlocks), 256, 0, stream>>>(
                feat, el, er, row_ptr + (size_t)i * (NN + 1), ssrc + (size_t)i * EE,
                bias_gat + (size_t)(l * MM + i) * 256, Hbuf + (size_t)i * NN * 256);
        }
    }

    // semantic attention: w_m = mean_n tanh(z @ W1 + b1) @ W2 ; beta = softmax(w)
    for (int i = 0; i < MM; ++i) {
        gemm64<<<dim3(rowTiles, 1), 256, 0, stream>>>(
            Hbuf + (size_t)i * NN * 256, W1, feat, nullptr, NN, 64, 64);
        sem_reduce_kernel<<<dim3(256), 256, 0, stream>>>(feat, b1, W2, wsum, i);
    }
    beta_kernel<<<dim3(1), 64, 0, stream>>>(wsum, beta);
    combine_kernel<<<dim3((NN * 256 + 255) / 256), 256, 0, stream>>>(Hbuf, beta, feat);
    // final projection: out = agg @ Wp + bp
    gemm64<<<dim3(rowTiles, 1), 256, 0, stream>>>(feat, Wp, out, bp, NN, 64, 64);
}

// Round 3
// 1364.386 us; speedup vs baseline: 2.6207x; 1.1929x over previous
//
#include <hip/hip_runtime.h>

#define NN 50000
#define EE 400000
#define MM 3

typedef float f32x4 __attribute__((ext_vector_type(4)));
typedef short s16x8 __attribute__((ext_vector_type(8)));
typedef short s16x4 __attribute__((ext_vector_type(4)));

union FU { float f; unsigned u; };

// round-to-nearest-even fp32 -> bf16 (bit pattern as short)
__device__ inline short bfhi(float x) {
    FU c; c.f = x;
    unsigned u = c.u;
    return (short)((u + 0x7fffu + ((u >> 16) & 1u)) >> 16);
}
__device__ inline float bf2f(short h) {
    FU c; c.u = ((unsigned)(unsigned short)h) << 16;
    return c.f;
}

// ---------------- CSR build ----------------

__global__ __launch_bounds__(256) void init_kernel(int* counts, float* wsum) {
    int idx = blockIdx.x * 256 + threadIdx.x;
    if (idx < MM * NN) counts[idx] = 0;
    if (idx < MM) wsum[idx] = 0.0f;
}

__global__ __launch_bounds__(256) void hist_kernel(const int* __restrict__ dst,
                                                   int* __restrict__ counts) {
    int m = blockIdx.y;
    int e = blockIdx.x * 256 + threadIdx.x;
    if (e < EE) atomicAdd(&counts[m * NN + dst[m * EE + e]], 1);
}

__global__ __launch_bounds__(1024) void scan_kernel(const int* __restrict__ counts,
                                                    int* __restrict__ row_ptr,
                                                    int* __restrict__ cursor) {
    int m = blockIdx.x;
    const int* c = counts + m * NN;
    int* rp = row_ptr + m * (NN + 1);
    int* cur = cursor + m * (NN + 1);
    __shared__ int sh[1024];
    int carry = 0;
    for (int base = 0; base < NN; base += 1024) {
        int i = base + threadIdx.x;
        int v = (i < NN) ? c[i] : 0;
        sh[threadIdx.x] = v;
        __syncthreads();
        for (int off = 1; off < 1024; off <<= 1) {
            int t = (threadIdx.x >= off) ? sh[threadIdx.x - off] : 0;
            __syncthreads();
            sh[threadIdx.x] += t;
            __syncthreads();
        }
        int incl = sh[threadIdx.x];
        if (i < NN) { int excl = carry + incl - v; rp[i] = excl; cur[i] = excl; }
        int tot = sh[1023];
        __syncthreads();
        carry += tot;
    }
    if (threadIdx.x == 0) { rp[NN] = carry; cur[NN] = carry; }
}

__global__ __launch_bounds__(256) void scatter_kernel(const int* __restrict__ src,
                                                      const int* __restrict__ dst,
                                                      int* __restrict__ cursor,
                                                      int* __restrict__ ssrc) {
    int m = blockIdx.y;
    int e = blockIdx.x * 256 + threadIdx.x;
    if (e < EE) {
        int d = dst[m * EE + e];
        int pos = atomicAdd(&cursor[m * (NN + 1) + d], 1);
        ssrc[m * EE + pos] = src[m * EE + e];
    }
}

// ---------------- weight transpose + split ----------------
// Wt layout: [6][256n][256k] for W_gat, then [64n][256k] W1, then [64n][256k] Wp.

#define WG_ELEMS (6 * 256 * 256)
#define W_TOT (WG_ELEMS + 2 * 64 * 256)

__global__ __launch_bounds__(256) void splitW_kernel(const float* __restrict__ Wg,
                                                     const float* __restrict__ W1,
                                                     const float* __restrict__ Wp,
                                                     short* __restrict__ Whi,
                                                     short* __restrict__ Wlo) {
    int idx = blockIdx.x * 256 + threadIdx.x;
    if (idx >= W_TOT) return;
    float v;
    if (idx < WG_ELEMS) {
        int mat = idx >> 16, rem = idx & 65535;
        int n = rem >> 8, k = rem & 255;
        v = Wg[mat * 65536 + k * 256 + n];
    } else {
        int i2 = idx - WG_ELEMS;
        int mat = i2 >> 14, rem = i2 & 16383;
        int n = rem >> 8, k = rem & 255;
        v = (mat ? Wp : W1)[k * 64 + n];
    }
    short h = bfhi(v);
    Whi[idx] = h;
    Wlo[idx] = bfhi(v - bf2f(h));
}

// ---------------- MFMA GEMM: C[nrows x ncols] = A[nrows x 256] @ W ----------------
// BM=128, BN=64, BK=32, 256 threads = 4 waves (2M x 2N), split-bf16 3-product.
// AMODE 0: A fp32 (split at stage). AMODE 1: A bf16 hi/lo. AMODE 2: A = sum_m
// beta[m] * (Ahi+Alo)[m] over MM metapaths (fused semantic combine).

template<int AMODE>
__global__ __launch_bounds__(256) void mfma_gemm(
    const float* __restrict__ Af,
    const short* __restrict__ Ahi, const short* __restrict__ Alo,
    const short* __restrict__ Wthi, const short* __restrict__ Wtlo,
    float* __restrict__ C, const float* __restrict__ bias,
    const float* __restrict__ beta,
    int nrows, int ldc) {
    __shared__ short Ah[128 * 32], Al[128 * 32], Bh[64 * 32], Bl[64 * 32];
    const int t = threadIdx.x;
    const int lane = t & 63;
    const int wave = t >> 6;
    const int wm = wave >> 1, wn = wave & 1;
    const int row0 = blockIdx.x * 128;
    const int col0 = blockIdx.y * 64;
    float b0 = 0.f, b1 = 0.f, b2 = 0.f;
    if (AMODE == 2) { b0 = beta[0]; b1 = beta[1]; b2 = beta[2]; }
    f32x4 acc[4][2] = {};

    for (int k0 = 0; k0 < 256; k0 += 32) {
        // ---- stage A (bf16 hi/lo, XOR-swizzled 16B chunks) ----
        if (AMODE == 1) {
#pragma unroll
            for (int u = 0; u < 2; ++u) {
                int idx = t * 2 + u;
                int r = idx >> 2, c = idx & 3;
                int row = row0 + r;
                s16x8 h = {0, 0, 0, 0, 0, 0, 0, 0};
                s16x8 l = {0, 0, 0, 0, 0, 0, 0, 0};
                if (row < nrows) {
                    h = *(const s16x8*)(Ahi + (size_t)row * 256 + k0 + c * 8);
                    l = *(const s16x8*)(Alo + (size_t)row * 256 + k0 + c * 8);
                }
                int off = r * 32 + ((c ^ ((r >> 1) & 3)) << 3);
                *(s16x8*)&Ah[off] = h;
                *(s16x8*)&Al[off] = l;
            }
        } else {
#pragma unroll
            for (int u = 0; u < 4; ++u) {
                int idx = t * 4 + u;
                int r = idx >> 3, kc = (idx & 7) << 2;
                int row = row0 + r;
                float v[4] = {0.f, 0.f, 0.f, 0.f};
                if (row < nrows) {
                    if (AMODE == 0) {
                        float4 q = *(const float4*)(Af + (size_t)row * 256 + k0 + kc);
                        v[0] = q.x; v[1] = q.y; v[2] = q.z; v[3] = q.w;
                    } else {
                        size_t base = (size_t)row * 256 + k0 + kc;
                        s16x4 h0 = *(const s16x4*)(Ahi + base);
                        s16x4 l0 = *(const s16x4*)(Alo + base);
                        s16x4 h1 = *(const s16x4*)(Ahi + (size_t)NN * 256 + base);
                        s16x4 l1 = *(const s16x4*)(Alo + (size_t)NN * 256 + base);
                        s16x4 h2 = *(const s16x4*)(Ahi + (size_t)2 * NN * 256 + base);
                        s16x4 l2 = *(const s16x4*)(Alo + (size_t)2 * NN * 256 + base);
#pragma unroll
                        for (int j = 0; j < 4; ++j)
                            v[j] = b0 * (bf2f(h0[j]) + bf2f(l0[j]))
                                 + b1 * (bf2f(h1[j]) + bf2f(l1[j]))
                                 + b2 * (bf2f(h2[j]) + bf2f(l2[j]));
                    }
                }
                s16x4 hh, ll;
#pragma unroll
                for (int j = 0; j < 4; ++j) {
                    short hs = bfhi(v[j]);
                    hh[j] = hs;
                    ll[j] = bfhi(v[j] - bf2f(hs));
                }
                int c = kc >> 3, sub = kc & 7;
                int off = r * 32 + ((c ^ ((r >> 1) & 3)) << 3) + sub;
                *(s16x4*)&Ah[off] = hh;
                *(s16x4*)&Al[off] = ll;
            }
        }
        // ---- stage B from pre-transposed/split weights [n][k] ----
        {
            int n = t >> 2, c = t & 3;
            s16x8 h = *(const s16x8*)(Wthi + (size_t)(col0 + n) * 256 + k0 + c * 8);
            s16x8 l = *(const s16x8*)(Wtlo + (size_t)(col0 + n) * 256 + k0 + c * 8);
            int off = n * 32 + ((c ^ ((n >> 1) & 3)) << 3);
            *(s16x8*)&Bh[off] = h;
            *(s16x8*)&Bl[off] = l;
        }
        __syncthreads();
        // ---- MFMA compute: 8 frag-pairs x 3 products ----
        int ar = lane & 15, ac = lane >> 4;
        s16x8 afh[4], afl[4], bfh[2], bfl[2];
#pragma unroll
        for (int i = 0; i < 4; ++i) {
            int r = wm * 64 + i * 16 + ar;
            int off = r * 32 + ((ac ^ ((r >> 1) & 3)) << 3);
            afh[i] = *(const s16x8*)&Ah[off];
            afl[i] = *(const s16x8*)&Al[off];
        }
#pragma unroll
        for (int j = 0; j < 2; ++j) {
            int n = wn * 32 + j * 16 + ar;
            int off = n * 32 + ((ac ^ ((n >> 1) & 3)) << 3);
            bfh[j] = *(const s16x8*)&Bh[off];
            bfl[j] = *(const s16x8*)&Bl[off];
        }
#pragma unroll
        for (int i = 0; i < 4; ++i)
#pragma unroll
            for (int j = 0; j < 2; ++j) {
                acc[i][j] = __builtin_amdgcn_mfma_f32_16x16x32_bf16(afh[i], bfh[j], acc[i][j], 0, 0, 0);
                acc[i][j] = __builtin_amdgcn_mfma_f32_16x16x32_bf16(afh[i], bfl[j], acc[i][j], 0, 0, 0);
                acc[i][j] = __builtin_amdgcn_mfma_f32_16x16x32_bf16(afl[i], bfh[j], acc[i][j], 0, 0, 0);
            }
        __syncthreads();
    }
    // ---- epilogue: C/D layout col=lane&15, row=(lane>>4)*4+q ----
#pragma unroll
    for (int i = 0; i < 4; ++i) {
        int rbase = row0 + wm * 64 + i * 16 + (lane >> 4) * 4;
#pragma unroll
        for (int j = 0; j < 2; ++j) {
            int col = col0 + wn * 32 + j * 16 + (lane & 15);
            float badd = bias ? bias[col] : 0.f;
#pragma unroll
            for (int q = 0; q < 4; ++q) {
                int row = rbase + q;
                if (row < nrows) C[(size_t)row * ldc + col] = acc[i][j][q] + badd;
            }
        }
    }
}

// ---------------- per-node attention scores el/er ----------------

__global__ __launch_bounds__(256) void eler_kernel(const float* __restrict__ feat,
                                                   const float* __restrict__ al,
                                                   const float* __restrict__ ar,
                                                   float* __restrict__ el,
                                                   float* __restrict__ er) {
    int wave = threadIdx.x >> 6;
    int lane = threadIdx.x & 63;
    int n = blockIdx.x * 4 + wave;
    if (n >= NN) return;
    const float* f = feat + (size_t)n * 256;
#pragma unroll
    for (int h = 0; h < 4; ++h) {
        float v = f[h * 64 + lane];
        float pl = v * al[h * 64 + lane];
        float pr = v * ar[h * 64 + lane];
#pragma unroll
        for (int off = 32; off; off >>= 1) {
            pl += __shfl_down(pl, off);
            pr += __shfl_down(pr, off);
        }
        if (lane == 0) { el[n * 4 + h] = pl; er[n * 4 + h] = pr; }
    }
}

// ---------------- edge-softmax aggregation (one wave per dst node) ----------------
// Writes the layer output directly as bf16 hi/lo pair (feeds next MFMA GEMM).

__global__ __launch_bounds__(256) void agg_edges_kernel(const float* __restrict__ feat,
                                                        const float* __restrict__ el,
                                                        const float* __restrict__ er,
                                                        const int* __restrict__ row_ptr,
                                                        const int* __restrict__ ssrc,
                                                        const float* __restrict__ bias,
                                                        short* __restrict__ out_hi,
                                                        short* __restrict__ out_lo) {
    int wave = threadIdx.x >> 6;
    int lane = threadIdx.x & 63;
    int n = blockIdx.x * 4 + wave;
    if (n >= NN) return;
    int beg = row_ptr[n], end = row_ptr[n + 1];
    float4 ern = ((const float4*)er)[n];
    float acc[4] = {0.f, 0.f, 0.f, 0.f};
    float den[4] = {0.f, 0.f, 0.f, 0.f};
    for (int j = beg; j < end; ++j) {
        int s = ssrc[j];
        float4 els = ((const float4*)el)[s];
        const float* fs = feat + (size_t)s * 256;
        float e0 = els.x + ern.x; e0 = e0 > 0.f ? e0 : 0.2f * e0; float w0 = __expf(e0);
        float e1 = els.y + ern.y; e1 = e1 > 0.f ? e1 : 0.2f * e1; float w1 = __expf(e1);
        float e2 = els.z + ern.z; e2 = e2 > 0.f ? e2 : 0.2f * e2; float w2 = __expf(e2);
        float e3 = els.w + ern.w; e3 = e3 > 0.f ? e3 : 0.2f * e3; float w3 = __expf(e3);
        acc[0] = fmaf(w0, fs[lane], acc[0]);       den[0] += w0;
        acc[1] = fmaf(w1, fs[64 + lane], acc[1]);  den[1] += w1;
        acc[2] = fmaf(w2, fs[128 + lane], acc[2]); den[2] += w2;
        acc[3] = fmaf(w3, fs[192 + lane], acc[3]); den[3] += w3;
    }
#pragma unroll
    for (int h = 0; h < 4; ++h) {
        float o = acc[h] / fmaxf(den[h], 1e-9f) + bias[h * 64 + lane];
        o = o > 0.f ? o : __expf(o) - 1.0f;
        short hs = bfhi(o);
        size_t idx = (size_t)n * 256 + h * 64 + lane;
        out_hi[idx] = hs;
        out_lo[idx] = bfhi(o - bf2f(hs));
    }
}

// ---------------- semantic attention ----------------

__global__ __launch_bounds__(256) void sem_reduce_kernel(const float* __restrict__ v,
                                                         const float* __restrict__ b1,
                                                         const float* __restrict__ W2,
                                                         float* __restrict__ wsum, int m) {
    __shared__ float sh[4];
    int wave = threadIdx.x >> 6;
    int lane = threadIdx.x & 63;
    float bw = b1[lane];
    float w2 = W2[lane];
    float t = 0.f;
    for (int n = blockIdx.x * 4 + wave; n < NN; n += gridDim.x * 4) {
        t += tanhf(v[(size_t)n * 64 + lane] + bw) * w2;
    }
#pragma unroll
    for (int off = 32; off; off >>= 1) t += __shfl_down(t, off);
    if (lane == 0) sh[wave] = t;
    __syncthreads();
    if (threadIdx.x == 0) atomicAdd(&wsum[m], sh[0] + sh[1] + sh[2] + sh[3]);
}

__global__ void beta_kernel(const float* __restrict__ wsum, float* __restrict__ beta) {
    if (threadIdx.x == 0 && blockIdx.x == 0) {
        float w0 = wsum[0] / (float)NN, w1 = wsum[1] / (float)NN, w2 = wsum[2] / (float)NN;
        float mx = fmaxf(w0, fmaxf(w1, w2));
        float e0 = __expf(w0 - mx), e1 = __expf(w1 - mx), e2 = __expf(w2 - mx);
        float s = e0 + e1 + e2;
        beta[0] = e0 / s; beta[1] = e1 / s; beta[2] = e2 / s;
    }
}

// ---------------- host launch ----------------

extern "C" void kernel_launch(void* const* d_in, const int* in_sizes, int n_in,
                              void* d_out, int out_size, void* d_ws, size_t ws_size,
                              hipStream_t stream) {
    const float* x        = (const float*)d_in[0];
    const float* W_gat    = (const float*)d_in[1];
    const float* attn_l   = (const float*)d_in[2];
    const float* attn_r   = (const float*)d_in[3];
    const float* bias_gat = (const float*)d_in[4];
    const float* W1       = (const float*)d_in[5];
    const float* b1       = (const float*)d_in[6];
    const float* W2       = (const float*)d_in[7];
    const float* Wp       = (const float*)d_in[8];
    const float* bp       = (const float*)d_in[9];
    const int*   src      = (const int*)d_in[10];
    const int*   dst      = (const int*)d_in[11];
    float* out = (float*)d_out;

    char* ws = (char*)d_ws;
    size_t off = 0;
    auto alloc = [&](size_t bytes) { size_t o = off; off = (off + bytes + 255) & ~(size_t)255; return o; };
    short* Hb_hi   = (short*)(ws + alloc((size_t)MM * NN * 256 * 2));
    short* Hb_lo   = (short*)(ws + alloc((size_t)MM * NN * 256 * 2));
    float* feat    = (float*)(ws + alloc((size_t)NN * 256 * 4));  // also aliased as z1 (150000x64 fits)
    float* el      = (float*)(ws + alloc((size_t)NN * 4 * 4));
    float* er      = (float*)(ws + alloc((size_t)NN * 4 * 4));
    int*   counts  = (int*)(ws + alloc((size_t)MM * NN * 4));
    int*   row_ptr = (int*)(ws + alloc((size_t)MM * (NN + 1) * 4));
    int*   cursor  = (int*)(ws + alloc((size_t)MM * (NN + 1) * 4));
    int*   ssrc    = (int*)(ws + alloc((size_t)MM * EE * 4));
    short* Whi     = (short*)(ws + alloc((size_t)W_TOT * 2));
    short* Wlo     = (short*)(ws + alloc((size_t)W_TOT * 2));
    float* wsum    = (float*)(ws + alloc(16));
    float* beta    = (float*)(ws + alloc(16));

    // CSR build + weight split (src/dst and W shared across calls but rebuilt each call)
    init_kernel<<<dim3((MM * NN + 255) / 256), 256, 0, stream>>>(counts, wsum);
    hist_kernel<<<dim3((EE + 255) / 256, MM), 256, 0, stream>>>(dst, counts);
    scan_kernel<<<dim3(MM), 1024, 0, stream>>>(counts, row_ptr, cursor);
    scatter_kernel<<<dim3((EE + 255) / 256, MM), 256, 0, stream>>>(src, dst, cursor, ssrc);
    splitW_kernel<<<dim3((W_TOT + 255) / 256), 256, 0, stream>>>(W_gat, W1, Wp, Whi, Wlo);

    const int rowTiles = (NN + 127) / 128;
    const int nodeBlocks = (NN + 3) / 4;

    for (int l = 0; l < 2; ++l) {
        for (int i = 0; i < MM; ++i) {
            const short* wh = Whi + (size_t)(l * MM + i) * 65536;
            const short* wl = Wlo + (size_t)(l * MM + i) * 65536;
            if (l == 0)
                mfma_gemm<0><<<dim3(rowTiles, 4), 256, 0, stream>>>(
                    x + (size_t)i * NN * 256, nullptr, nullptr, wh, wl,
                    feat, nullptr, nullptr, NN, 256);
            else
                mfma_gemm<1><<<dim3(rowTiles, 4), 256, 0, stream>>>(
                    nullptr, Hb_hi + (size_t)i * NN * 256, Hb_lo + (size_t)i * NN * 256,
                    wh, wl, feat, nullptr, nullptr, NN, 256);
            eler_kernel<<<dim3(nodeBlocks), 256, 0, stream>>>(
                feat, attn_l + (size_t)(l * MM + i) * 256, attn_r + (size_t)(l * MM + i) * 256,
                el, er);
            agg_edges_kernel<<<dim3(nodeBlocks), 256, 0, stream>>>(
                feat, el, er, row_ptr + (size_t)i * (NN + 1), ssrc + (size_t)i * EE,
                bias_gat + (size_t)(l * MM + i) * 256,
                Hb_hi + (size_t)i * NN * 256, Hb_lo + (size_t)i * NN * 256);
        }
    }

    // semantic attention: one batched GEMM over all 3 metapaths (rows contiguous)
    float* z1 = feat;  // 150000*64 floats fit in feat buffer
    mfma_gemm<1><<<dim3((MM * NN + 127) / 128, 1), 256, 0, stream>>>(
        nullptr, Hb_hi, Hb_lo, Whi + WG_ELEMS, Wlo + WG_ELEMS,
        z1, nullptr, nullptr, MM * NN, 64);
    for (int i = 0; i < MM; ++i)
        sem_reduce_kernel<<<dim3(256), 256, 0, stream>>>(
            z1 + (size_t)i * NN * 64, b1, W2, wsum, i);
    beta_kernel<<<dim3(1), 64, 0, stream>>>(wsum, beta);
    // final projection with fused beta-combine: out = (sum_m beta_m H_m) @ Wp + bp
    mfma_gemm<2><<<dim3(rowTiles, 1), 256, 0, stream>>>(
        nullptr, Hb_hi, Hb_lo, Whi + WG_ELEMS + 16384, Wlo + WG_ELEMS + 16384,
        out, bp, beta, NN, 64);
}

// Round 4
// 1305.765 us; speedup vs baseline: 2.7383x; 1.0449x over previous
//
#include <hip/hip_runtime.h>

#define NN 50000
#define EE 400000
#define MM 3
#define CHUNK 2048
#define NCHUNK ((NN + CHUNK - 1) / CHUNK)   // 25

typedef float f32x4 __attribute__((ext_vector_type(4)));
typedef short s16x8 __attribute__((ext_vector_type(8)));
typedef short s16x4 __attribute__((ext_vector_type(4)));

union FU { float f; unsigned u; };

// round-to-nearest-even fp32 -> bf16 (bit pattern as short)
__device__ inline short bfhi(float x) {
    FU c; c.f = x;
    unsigned u = c.u;
    return (short)((u + 0x7fffu + ((u >> 16) & 1u)) >> 16);
}
__device__ inline float bf2f(short h) {
    FU c; c.u = ((unsigned)(unsigned short)h) << 16;
    return c.f;
}

// ---------------- CSR build ----------------

__global__ __launch_bounds__(256) void init_kernel(int* counts, float* wsum) {
    int idx = blockIdx.x * 256 + threadIdx.x;
    if (idx < MM * NN) counts[idx] = 0;
    if (idx < MM) wsum[idx] = 0.0f;
}

__global__ __launch_bounds__(256) void hist_kernel(const int* __restrict__ dst,
                                                   int* __restrict__ counts) {
    int m = blockIdx.y;
    int e = blockIdx.x * 256 + threadIdx.x;
    if (e < EE) atomicAdd(&counts[m * NN + dst[m * EE + e]], 1);
}

// Hierarchical scan: per-chunk exclusive scan (wave shfl, no LDS ping-pong).
__global__ __launch_bounds__(256) void scan_partial_kernel(const int* __restrict__ counts,
                                                           int* __restrict__ rp,
                                                           int* __restrict__ bsum) {
    int m = blockIdx.y, ch = blockIdx.x;
    const int* c = counts + m * NN;
    int* r = rp + m * (NN + 1);
    int t = threadIdx.x, lane = t & 63, wave = t >> 6;
    int i0 = ch * CHUNK + t * 8;
    int v[8]; int s = 0;
#pragma unroll
    for (int k = 0; k < 8; ++k) { int i = i0 + k; v[k] = (i < NN) ? c[i] : 0; s += v[k]; }
    int incl = s;
#pragma unroll
    for (int off = 1; off < 64; off <<= 1) {
        int u = __shfl_up(incl, off);
        if (lane >= off) incl += u;
    }
    int excl = incl - s;
    __shared__ int wsh[4];
    if (lane == 63) wsh[wave] = incl;
    __syncthreads();
    int woff = 0;
    for (int w = 0; w < wave; ++w) woff += wsh[w];
    int run = excl + woff;
#pragma unroll
    for (int k = 0; k < 8; ++k) { int i = i0 + k; if (i < NN) r[i] = run; run += v[k]; }
    if (t == 255) bsum[m * NCHUNK + ch] = woff + incl;
}

__global__ __launch_bounds__(256) void scan_top_kernel(int* __restrict__ bsum) {
    int wave = threadIdx.x >> 6, lane = threadIdx.x & 63;
    if (wave < MM) {
        int v = (lane < NCHUNK) ? bsum[wave * NCHUNK + lane] : 0;
        int incl = v;
#pragma unroll
        for (int off = 1; off < 64; off <<= 1) {
            int u = __shfl_up(incl, off);
            if (lane >= off) incl += u;
        }
        if (lane < NCHUNK) bsum[wave * NCHUNK + lane] = incl - v;
    }
}

__global__ __launch_bounds__(256) void scan_add_kernel(const int* __restrict__ bsum,
                                                       int* __restrict__ rp,
                                                       int* __restrict__ cur) {
    int m = blockIdx.y, ch = blockIdx.x;
    int off = bsum[m * NCHUNK + ch];
    int* r = rp + m * (NN + 1);
    int* q = cur + m * (NN + 1);
    int i0 = ch * CHUNK + threadIdx.x * 8;
#pragma unroll
    for (int k = 0; k < 8; ++k) {
        int i = i0 + k;
        if (i < NN) { int val = r[i] + off; r[i] = val; q[i] = val; }
    }
    if (ch == 0 && threadIdx.x == 0) r[NN] = EE;
}

__global__ __launch_bounds__(256) void scatter_kernel(const int* __restrict__ src,
                                                      const int* __restrict__ dst,
                                                      int* __restrict__ cursor,
                                                      int* __restrict__ ssrc) {
    int m = blockIdx.y;
    int e = blockIdx.x * 256 + threadIdx.x;
    if (e < EE) {
        int d = dst[m * EE + e];
        int pos = atomicAdd(&cursor[m * (NN + 1) + d], 1);
        ssrc[m * EE + pos] = src[m * EE + e];
    }
}

// ---------------- weight transpose + split ----------------

#define WG_ELEMS (6 * 256 * 256)
#define W_TOT (WG_ELEMS + 2 * 64 * 256)

__global__ __launch_bounds__(256) void splitW_kernel(const float* __restrict__ Wg,
                                                     const float* __restrict__ W1,
                                                     const float* __restrict__ Wp,
                                                     short* __restrict__ Whi,
                                                     short* __restrict__ Wlo) {
    int idx = blockIdx.x * 256 + threadIdx.x;
    if (idx >= W_TOT) return;
    float v;
    if (idx < WG_ELEMS) {
        int mat = idx >> 16, rem = idx & 65535;
        int n = rem >> 8, k = rem & 255;
        v = Wg[mat * 65536 + k * 256 + n];
    } else {
        int i2 = idx - WG_ELEMS;
        int mat = i2 >> 14, rem = i2 & 16383;
        int n = rem >> 8, k = rem & 255;
        v = (mat ? Wp : W1)[k * 64 + n];
    }
    short h = bfhi(v);
    Whi[idx] = h;
    Wlo[idx] = bfhi(v - bf2f(h));
}

// ---------------- MFMA GEMM (split-bf16 3-product) ----------------

template<int AMODE>
__global__ __launch_bounds__(256) void mfma_gemm(
    const float* __restrict__ Af,
    const short* __restrict__ Ahi, const short* __restrict__ Alo,
    const short* __restrict__ Wthi, const short* __restrict__ Wtlo,
    float* __restrict__ C, const float* __restrict__ bias,
    const float* __restrict__ beta,
    int nrows, int ldc) {
    __shared__ short Ah[128 * 32], Al[128 * 32], Bh[64 * 32], Bl[64 * 32];
    const int t = threadIdx.x;
    const int lane = t & 63;
    const int wave = t >> 6;
    const int wm = wave >> 1, wn = wave & 1;
    const int row0 = blockIdx.x * 128;
    const int col0 = blockIdx.y * 64;
    float b0 = 0.f, b1 = 0.f, b2 = 0.f;
    if (AMODE == 2) { b0 = beta[0]; b1 = beta[1]; b2 = beta[2]; }
    f32x4 acc[4][2] = {};

    for (int k0 = 0; k0 < 256; k0 += 32) {
        if (AMODE == 1) {
#pragma unroll
            for (int u = 0; u < 2; ++u) {
                int idx = t * 2 + u;
                int r = idx >> 2, c = idx & 3;
                int row = row0 + r;
                s16x8 h = {0, 0, 0, 0, 0, 0, 0, 0};
                s16x8 l = {0, 0, 0, 0, 0, 0, 0, 0};
                if (row < nrows) {
                    h = *(const s16x8*)(Ahi + (size_t)row * 256 + k0 + c * 8);
                    l = *(const s16x8*)(Alo + (size_t)row * 256 + k0 + c * 8);
                }
                int off = r * 32 + ((c ^ ((r >> 1) & 3)) << 3);
                *(s16x8*)&Ah[off] = h;
                *(s16x8*)&Al[off] = l;
            }
        } else {
#pragma unroll
            for (int u = 0; u < 4; ++u) {
                int idx = t * 4 + u;
                int r = idx >> 3, kc = (idx & 7) << 2;
                int row = row0 + r;
                float v[4] = {0.f, 0.f, 0.f, 0.f};
                if (row < nrows) {
                    if (AMODE == 0) {
                        float4 q = *(const float4*)(Af + (size_t)row * 256 + k0 + kc);
                        v[0] = q.x; v[1] = q.y; v[2] = q.z; v[3] = q.w;
                    } else {
                        size_t base = (size_t)row * 256 + k0 + kc;
                        s16x4 h0 = *(const s16x4*)(Ahi + base);
                        s16x4 l0 = *(const s16x4*)(Alo + base);
                        s16x4 h1 = *(const s16x4*)(Ahi + (size_t)NN * 256 + base);
                        s16x4 l1 = *(const s16x4*)(Alo + (size_t)NN * 256 + base);
                        s16x4 h2 = *(const s16x4*)(Ahi + (size_t)2 * NN * 256 + base);
                        s16x4 l2 = *(const s16x4*)(Alo + (size_t)2 * NN * 256 + base);
#pragma unroll
                        for (int j = 0; j < 4; ++j)
                            v[j] = b0 * (bf2f(h0[j]) + bf2f(l0[j]))
                                 + b1 * (bf2f(h1[j]) + bf2f(l1[j]))
                                 + b2 * (bf2f(h2[j]) + bf2f(l2[j]));
                    }
                }
                s16x4 hh, ll;
#pragma unroll
                for (int j = 0; j < 4; ++j) {
                    short hs = bfhi(v[j]);
                    hh[j] = hs;
                    ll[j] = bfhi(v[j] - bf2f(hs));
                }
                int c = kc >> 3, sub = kc & 7;
                int off = r * 32 + ((c ^ ((r >> 1) & 3)) << 3) + sub;
                *(s16x4*)&Ah[off] = hh;
                *(s16x4*)&Al[off] = ll;
            }
        }
        {
            int n = t >> 2, c = t & 3;
            s16x8 h = *(const s16x8*)(Wthi + (size_t)(col0 + n) * 256 + k0 + c * 8);
            s16x8 l = *(const s16x8*)(Wtlo + (size_t)(col0 + n) * 256 + k0 + c * 8);
            int off = n * 32 + ((c ^ ((n >> 1) & 3)) << 3);
            *(s16x8*)&Bh[off] = h;
            *(s16x8*)&Bl[off] = l;
        }
        __syncthreads();
        int ar = lane & 15, ac = lane >> 4;
        s16x8 afh[4], afl[4], bfh[2], bfl[2];
#pragma unroll
        for (int i = 0; i < 4; ++i) {
            int r = wm * 64 + i * 16 + ar;
            int off = r * 32 + ((ac ^ ((r >> 1) & 3)) << 3);
            afh[i] = *(const s16x8*)&Ah[off];
            afl[i] = *(const s16x8*)&Al[off];
        }
#pragma unroll
        for (int j = 0; j < 2; ++j) {
            int n = wn * 32 + j * 16 + ar;
            int off = n * 32 + ((ac ^ ((n >> 1) & 3)) << 3);
            bfh[j] = *(const s16x8*)&Bh[off];
            bfl[j] = *(const s16x8*)&Bl[off];
        }
#pragma unroll
        for (int i = 0; i < 4; ++i)
#pragma unroll
            for (int j = 0; j < 2; ++j) {
                acc[i][j] = __builtin_amdgcn_mfma_f32_16x16x32_bf16(afh[i], bfh[j], acc[i][j], 0, 0, 0);
                acc[i][j] = __builtin_amdgcn_mfma_f32_16x16x32_bf16(afh[i], bfl[j], acc[i][j], 0, 0, 0);
                acc[i][j] = __builtin_amdgcn_mfma_f32_16x16x32_bf16(afl[i], bfh[j], acc[i][j], 0, 0, 0);
            }
        __syncthreads();
    }
#pragma unroll
    for (int i = 0; i < 4; ++i) {
        int rbase = row0 + wm * 64 + i * 16 + (lane >> 4) * 4;
#pragma unroll
        for (int j = 0; j < 2; ++j) {
            int col = col0 + wn * 32 + j * 16 + (lane & 15);
            float badd = bias ? bias[col] : 0.f;
#pragma unroll
            for (int q = 0; q < 4; ++q) {
                int row = rbase + q;
                if (row < nrows) C[(size_t)row * ldc + col] = acc[i][j][q] + badd;
            }
        }
    }
}

// ---------------- per-node attention scores el/er ----------------

__global__ __launch_bounds__(256) void eler_kernel(const float* __restrict__ feat,
                                                   const float* __restrict__ al,
                                                   const float* __restrict__ ar,
                                                   float* __restrict__ el,
                                                   float* __restrict__ er) {
    int wave = threadIdx.x >> 6;
    int lane = threadIdx.x & 63;
    int n = blockIdx.x * 4 + wave;
    if (n >= NN) return;
    const float* f = feat + (size_t)n * 256;
#pragma unroll
    for (int h = 0; h < 4; ++h) {
        float v = f[h * 64 + lane];
        float pl = v * al[h * 64 + lane];
        float pr = v * ar[h * 64 + lane];
#pragma unroll
        for (int off = 32; off; off >>= 1) {
            pl += __shfl_down(pl, off);
            pr += __shfl_down(pr, off);
        }
        if (lane == 0) { el[n * 4 + h] = pl; er[n * 4 + h] = pr; }
    }
}

// ---------------- edge-softmax aggregation ----------------
// 2 waves per dst node (2 heads each), edge loop unrolled x2 with independent
// accumulators: ~4x more independent gather chains in flight than 1-wave/node.

__global__ __launch_bounds__(256) void agg_edges_kernel(const float* __restrict__ feat,
                                                        const float* __restrict__ el,
                                                        const float* __restrict__ er,
                                                        const int* __restrict__ row_ptr,
                                                        const int* __restrict__ ssrc,
                                                        const float* __restrict__ bias,
                                                        short* __restrict__ out_hi,
                                                        short* __restrict__ out_lo) {
    int wave = threadIdx.x >> 6;
    int lane = threadIdx.x & 63;
    int gidx = blockIdx.x * 4 + wave;
    int n = gidx >> 1, p = gidx & 1;
    if (n >= NN) return;
    int beg = row_ptr[n], end = row_ptr[n + 1];
    float2 ern = ((const float2*)er)[n * 2 + p];
    const float* fb = feat + p * 128 + lane;
    float acc0 = 0.f, acc1 = 0.f, den0 = 0.f, den1 = 0.f;
    float acc0b = 0.f, acc1b = 0.f, den0b = 0.f, den1b = 0.f;
    int j = beg;
    for (; j + 1 < end; j += 2) {
        int sA = ssrc[j], sB = ssrc[j + 1];
        float2 eA = ((const float2*)el)[sA * 2 + p];
        float2 eB = ((const float2*)el)[sB * 2 + p];
        const float* fA = fb + (size_t)sA * 256;
        const float* fB = fb + (size_t)sB * 256;
        float fA0 = fA[0], fA1 = fA[64];
        float fB0 = fB[0], fB1 = fB[64];
        float a0 = eA.x + ern.x; a0 = a0 > 0.f ? a0 : 0.2f * a0; float wA0 = __expf(a0);
        float a1 = eA.y + ern.y; a1 = a1 > 0.f ? a1 : 0.2f * a1; float wA1 = __expf(a1);
        float c0 = eB.x + ern.x; c0 = c0 > 0.f ? c0 : 0.2f * c0; float wB0 = __expf(c0);
        float c1 = eB.y + ern.y; c1 = c1 > 0.f ? c1 : 0.2f * c1; float wB1 = __expf(c1);
        acc0  = fmaf(wA0, fA0, acc0 );  den0  += wA0;
        acc1  = fmaf(wA1, fA1, acc1 );  den1  += wA1;
        acc0b = fmaf(wB0, fB0, acc0b);  den0b += wB0;
        acc1b = fmaf(wB1, fB1, acc1b);  den1b += wB1;
    }
    if (j < end) {
        int s = ssrc[j];
        float2 e = ((const float2*)el)[s * 2 + p];
        const float* fs = fb + (size_t)s * 256;
        float f0 = fs[0], f1 = fs[64];
        float e0 = e.x + ern.x; e0 = e0 > 0.f ? e0 : 0.2f * e0; float w0 = __expf(e0);
        float e1 = e.y + ern.y; e1 = e1 > 0.f ? e1 : 0.2f * e1; float w1 = __expf(e1);
        acc0 = fmaf(w0, f0, acc0); den0 += w0;
        acc1 = fmaf(w1, f1, acc1); den1 += w1;
    }
    acc0 += acc0b; den0 += den0b;
    acc1 += acc1b; den1 += den1b;
    int h0 = 2 * p, h1 = 2 * p + 1;
    float o0 = acc0 / fmaxf(den0, 1e-9f) + bias[h0 * 64 + lane];
    o0 = o0 > 0.f ? o0 : __expf(o0) - 1.0f;
    float o1 = acc1 / fmaxf(den1, 1e-9f) + bias[h1 * 64 + lane];
    o1 = o1 > 0.f ? o1 : __expf(o1) - 1.0f;
    size_t i0 = (size_t)n * 256 + h0 * 64 + lane;
    size_t i1 = (size_t)n * 256 + h1 * 64 + lane;
    short hs0 = bfhi(o0); out_hi[i0] = hs0; out_lo[i0] = bfhi(o0 - bf2f(hs0));
    short hs1 = bfhi(o1); out_hi[i1] = hs1; out_lo[i1] = bfhi(o1 - bf2f(hs1));
}

// ---------------- semantic attention ----------------

__global__ __launch_bounds__(256) void sem_reduce_kernel(const float* __restrict__ v,
                                                         const float* __restrict__ b1,
                                                         const float* __restrict__ W2,
                                                         float* __restrict__ wsum, int m) {
    __shared__ float sh[4];
    int wave = threadIdx.x >> 6;
    int lane = threadIdx.x & 63;
    float bw = b1[lane];
    float w2 = W2[lane];
    float t = 0.f;
    for (int n = blockIdx.x * 4 + wave; n < NN; n += gridDim.x * 4) {
        t += tanhf(v[(size_t)n * 64 + lane] + bw) * w2;
    }
#pragma unroll
    for (int off = 32; off; off >>= 1) t += __shfl_down(t, off);
    if (lane == 0) sh[wave] = t;
    __syncthreads();
    if (threadIdx.x == 0) atomicAdd(&wsum[m], sh[0] + sh[1] + sh[2] + sh[3]);
}

__global__ void beta_kernel(const float* __restrict__ wsum, float* __restrict__ beta) {
    if (threadIdx.x == 0 && blockIdx.x == 0) {
        float w0 = wsum[0] / (float)NN, w1 = wsum[1] / (float)NN, w2 = wsum[2] / (float)NN;
        float mx = fmaxf(w0, fmaxf(w1, w2));
        float e0 = __expf(w0 - mx), e1 = __expf(w1 - mx), e2 = __expf(w2 - mx);
        float s = e0 + e1 + e2;
        beta[0] = e0 / s; beta[1] = e1 / s; beta[2] = e2 / s;
    }
}

// ---------------- host launch ----------------

extern "C" void kernel_launch(void* const* d_in, const int* in_sizes, int n_in,
                              void* d_out, int out_size, void* d_ws, size_t ws_size,
                              hipStream_t stream) {
    const float* x        = (const float*)d_in[0];
    const float* W_gat    = (const float*)d_in[1];
    const float* attn_l   = (const float*)d_in[2];
    const float* attn_r   = (const float*)d_in[3];
    const float* bias_gat = (const float*)d_in[4];
    const float* W1       = (const float*)d_in[5];
    const float* b1       = (const float*)d_in[6];
    const float* W2       = (const float*)d_in[7];
    const float* Wp       = (const float*)d_in[8];
    const float* bp       = (const float*)d_in[9];
    const int*   src      = (const int*)d_in[10];
    const int*   dst      = (const int*)d_in[11];
    float* out = (float*)d_out;

    char* ws = (char*)d_ws;
    size_t off = 0;
    auto alloc = [&](size_t bytes) { size_t o = off; off = (off + bytes + 255) & ~(size_t)255; return o; };
    short* Hb_hi   = (short*)(ws + alloc((size_t)MM * NN * 256 * 2));
    short* Hb_lo   = (short*)(ws + alloc((size_t)MM * NN * 256 * 2));
    float* feat    = (float*)(ws + alloc((size_t)NN * 256 * 4));  // aliased as z1 (150000x64 fits)
    float* el      = (float*)(ws + alloc((size_t)NN * 4 * 4));
    float* er      = (float*)(ws + alloc((size_t)NN * 4 * 4));
    int*   counts  = (int*)(ws + alloc((size_t)MM * NN * 4));
    int*   row_ptr = (int*)(ws + alloc((size_t)MM * (NN + 1) * 4));
    int*   cursor  = (int*)(ws + alloc((size_t)MM * (NN + 1) * 4));
    int*   ssrc    = (int*)(ws + alloc((size_t)MM * EE * 4));
    int*   bsum    = (int*)(ws + alloc((size_t)MM * NCHUNK * 4));
    short* Whi     = (short*)(ws + alloc((size_t)W_TOT * 2));
    short* Wlo     = (short*)(ws + alloc((size_t)W_TOT * 2));
    float* wsum    = (float*)(ws + alloc(16));
    float* beta    = (float*)(ws + alloc(16));

    // CSR build (hierarchical scan) + weight split
    init_kernel<<<dim3((MM * NN + 255) / 256), 256, 0, stream>>>(counts, wsum);
    hist_kernel<<<dim3((EE + 255) / 256, MM), 256, 0, stream>>>(dst, counts);
    scan_partial_kernel<<<dim3(NCHUNK, MM), 256, 0, stream>>>(counts, row_ptr, bsum);
    scan_top_kernel<<<dim3(1), 256, 0, stream>>>(bsum);
    scan_add_kernel<<<dim3(NCHUNK, MM), 256, 0, stream>>>(bsum, row_ptr, cursor);
    scatter_kernel<<<dim3((EE + 255) / 256, MM), 256, 0, stream>>>(src, dst, cursor, ssrc);
    splitW_kernel<<<dim3((W_TOT + 255) / 256), 256, 0, stream>>>(W_gat, W1, Wp, Whi, Wlo);

    const int rowTiles = (NN + 127) / 128;
    const int nodeBlocks = (NN + 3) / 4;
    const int aggBlocks = (2 * NN + 3) / 4;

    for (int l = 0; l < 2; ++l) {
        for (int i = 0; i < MM; ++i) {
            const short* wh = Whi + (size_t)(l * MM + i) * 65536;
            const short* wl = Wlo + (size_t)(l * MM + i) * 65536;
            if (l == 0)
                mfma_gemm<0><<<dim3(rowTiles, 4), 256, 0, stream>>>(
                    x + (size_t)i * NN * 256, nullptr, nullptr, wh, wl,
                    feat, nullptr, nullptr, NN, 256);
            else
                mfma_gemm<1><<<dim3(rowTiles, 4), 256, 0, stream>>>(
                    nullptr, Hb_hi + (size_t)i * NN * 256, Hb_lo + (size_t)i * NN * 256,
                    wh, wl, feat, nullptr, nullptr, NN, 256);
            eler_kernel<<<dim3(nodeBlocks), 256, 0, stream>>>(
                feat, attn_l + (size_t)(l * MM + i) * 256, attn_r + (size_t)(l * MM + i) * 256,
                el, er);
            agg_edges_kernel<<<dim3(aggBlocks), 256, 0, stream>>>(
                feat, el, er, row_ptr + (size_t)i * (NN + 1), ssrc + (size_t)i * EE,
                bias_gat + (size_t)(l * MM + i) * 256,
                Hb_hi + (size_t)i * NN * 256, Hb_lo + (size_t)i * NN * 256);
        }
    }

    // semantic attention: one batched GEMM over all 3 metapaths
    float* z1 = feat;
    mfma_gemm<1><<<dim3((MM * NN + 127) / 128, 1), 256, 0, stream>>>(
        nullptr, Hb_hi, Hb_lo, Whi + WG_ELEMS, Wlo + WG_ELEMS,
        z1, nullptr, nullptr, MM * NN, 64);
    for (int i = 0; i < MM; ++i)
        sem_reduce_kernel<<<dim3(256), 256, 0, stream>>>(
            z1 + (size_t)i * NN * 64, b1, W2, wsum, i);
    beta_kernel<<<dim3(1), 64, 0, stream>>>(wsum, beta);
    // final projection with fused beta-combine
    mfma_gemm<2><<<dim3(rowTiles, 1), 256, 0, stream>>>(
        nullptr, Hb_hi, Hb_lo, Whi + WG_ELEMS + 16384, Wlo + WG_ELEMS + 16384,
        out, bp, beta, NN, 64);
}

// Round 5
// 1139.091 us; speedup vs baseline: 3.1390x; 1.1463x over previous
//
#include <hip/hip_runtime.h>

#define NN 50000
#define EE 400000
#define MM 3
#define CHUNK 2048
#define NCHUNK ((NN + CHUNK - 1) / CHUNK)   // 25

typedef float f32x4 __attribute__((ext_vector_type(4)));
typedef short s16x8 __attribute__((ext_vector_type(8)));
typedef short s16x4 __attribute__((ext_vector_type(4)));

union FU { float f; unsigned u; };

__device__ inline short bfhi(float x) {
    FU c; c.f = x;
    unsigned u = c.u;
    return (short)((u + 0x7fffu + ((u >> 16) & 1u)) >> 16);
}
__device__ inline float bf2f(short h) {
    FU c; c.u = ((unsigned)(unsigned short)h) << 16;
    return c.f;
}

// ---------------- CSR build ----------------

__global__ __launch_bounds__(256) void init_kernel(int* counts, float* wsum) {
    int idx = blockIdx.x * 256 + threadIdx.x;
    if (idx < MM * NN) counts[idx] = 0;
    if (idx < MM) wsum[idx] = 0.0f;
}

__global__ __launch_bounds__(256) void hist_kernel(const int* __restrict__ dst,
                                                   int* __restrict__ counts) {
    int m = blockIdx.y;
    int e = blockIdx.x * 256 + threadIdx.x;
    if (e < EE) atomicAdd(&counts[m * NN + dst[m * EE + e]], 1);
}

__global__ __launch_bounds__(256) void scan_partial_kernel(const int* __restrict__ counts,
                                                           int* __restrict__ rp,
                                                           int* __restrict__ bsum) {
    int m = blockIdx.y, ch = blockIdx.x;
    const int* c = counts + m * NN;
    int* r = rp + m * (NN + 1);
    int t = threadIdx.x, lane = t & 63, wave = t >> 6;
    int i0 = ch * CHUNK + t * 8;
    int v[8]; int s = 0;
#pragma unroll
    for (int k = 0; k < 8; ++k) { int i = i0 + k; v[k] = (i < NN) ? c[i] : 0; s += v[k]; }
    int incl = s;
#pragma unroll
    for (int off = 1; off < 64; off <<= 1) {
        int u = __shfl_up(incl, off);
        if (lane >= off) incl += u;
    }
    int excl = incl - s;
    __shared__ int wsh[4];
    if (lane == 63) wsh[wave] = incl;
    __syncthreads();
    int woff = 0;
    for (int w = 0; w < wave; ++w) woff += wsh[w];
    int run = excl + woff;
#pragma unroll
    for (int k = 0; k < 8; ++k) { int i = i0 + k; if (i < NN) r[i] = run; run += v[k]; }
    if (t == 255) bsum[m * NCHUNK + ch] = woff + incl;
}

__global__ __launch_bounds__(256) void scan_top_kernel(int* __restrict__ bsum) {
    int wave = threadIdx.x >> 6, lane = threadIdx.x & 63;
    if (wave < MM) {
        int v = (lane < NCHUNK) ? bsum[wave * NCHUNK + lane] : 0;
        int incl = v;
#pragma unroll
        for (int off = 1; off < 64; off <<= 1) {
            int u = __shfl_up(incl, off);
            if (lane >= off) incl += u;
        }
        if (lane < NCHUNK) bsum[wave * NCHUNK + lane] = incl - v;
    }
}

__global__ __launch_bounds__(256) void scan_add_kernel(const int* __restrict__ bsum,
                                                       int* __restrict__ rp,
                                                       int* __restrict__ cur) {
    int m = blockIdx.y, ch = blockIdx.x;
    int off = bsum[m * NCHUNK + ch];
    int* r = rp + m * (NN + 1);
    int* q = cur + m * (NN + 1);
    int i0 = ch * CHUNK + threadIdx.x * 8;
#pragma unroll
    for (int k = 0; k < 8; ++k) {
        int i = i0 + k;
        if (i < NN) { int val = r[i] + off; r[i] = val; q[i] = val; }
    }
    if (ch == 0 && threadIdx.x == 0) r[NN] = EE;
}

__global__ __launch_bounds__(256) void scatter_kernel(const int* __restrict__ src,
                                                      const int* __restrict__ dst,
                                                      int* __restrict__ cursor,
                                                      int* __restrict__ ssrc) {
    int m = blockIdx.y;
    int e = blockIdx.x * 256 + threadIdx.x;
    if (e < EE) {
        int d = dst[m * EE + e];
        int pos = atomicAdd(&cursor[m * (NN + 1) + d], 1);
        ssrc[m * EE + pos] = src[m * EE + e];
    }
}

// ---------------- weight transpose + split ----------------

#define WG_ELEMS (6 * 256 * 256)
#define W_TOT (WG_ELEMS + 2 * 64 * 256)

__global__ __launch_bounds__(256) void splitW_kernel(const float* __restrict__ Wg,
                                                     const float* __restrict__ W1,
                                                     const float* __restrict__ Wp,
                                                     short* __restrict__ Whi,
                                                     short* __restrict__ Wlo) {
    int idx = blockIdx.x * 256 + threadIdx.x;
    if (idx >= W_TOT) return;
    float v;
    if (idx < WG_ELEMS) {
        int mat = idx >> 16, rem = idx & 65535;
        int n = rem >> 8, k = rem & 255;
        v = Wg[mat * 65536 + k * 256 + n];
    } else {
        int i2 = idx - WG_ELEMS;
        int mat = i2 >> 14, rem = i2 & 16383;
        int n = rem >> 8, k = rem & 255;
        v = (mat ? Wp : W1)[k * 64 + n];
    }
    short h = bfhi(v);
    Whi[idx] = h;
    Wlo[idx] = bfhi(v - bf2f(h));
}

// ---------------- MFMA GEMM (split-bf16 3-product) ----------------
// EPI 0: write C (+bias). EPI 1: write C and fused el/er (block = one head's
// 64 cols). EPI 2: no C write; fused tanh-dot-W2 row reduction into wsum.

template<int AMODE, int EPI>
__global__ __launch_bounds__(256) void mfma_gemm(
    const float* __restrict__ Af,
    const short* __restrict__ Ahi, const short* __restrict__ Alo,
    const short* __restrict__ Wthi, const short* __restrict__ Wtlo,
    float* __restrict__ C, const float* __restrict__ bias,
    const float* __restrict__ beta,
    const float* __restrict__ al, const float* __restrict__ ar,
    float* __restrict__ el, float* __restrict__ er,
    float* __restrict__ wsum,
    int nrows, int ldc) {
    __shared__ short Ah[128 * 32], Al[128 * 32], Bh[64 * 32], Bl[64 * 32];
    __shared__ float sred[2][128][2];
    __shared__ float wpart[3];
    const int t = threadIdx.x;
    const int lane = t & 63;
    const int wave = t >> 6;
    const int wm = wave >> 1, wn = wave & 1;
    const int row0 = blockIdx.x * 128;
    const int col0 = blockIdx.y * 64;
    float b0 = 0.f, b1v = 0.f, b2 = 0.f;
    if (AMODE == 2) { b0 = beta[0]; b1v = beta[1]; b2 = beta[2]; }
    f32x4 acc[4][2] = {};

    for (int k0 = 0; k0 < 256; k0 += 32) {
        if (AMODE == 1) {
#pragma unroll
            for (int u = 0; u < 2; ++u) {
                int idx = t * 2 + u;
                int r = idx >> 2, c = idx & 3;
                int row = row0 + r;
                s16x8 h = {0, 0, 0, 0, 0, 0, 0, 0};
                s16x8 l = {0, 0, 0, 0, 0, 0, 0, 0};
                if (row < nrows) {
                    h = *(const s16x8*)(Ahi + (size_t)row * 256 + k0 + c * 8);
                    l = *(const s16x8*)(Alo + (size_t)row * 256 + k0 + c * 8);
                }
                int off = r * 32 + ((c ^ ((r >> 1) & 3)) << 3);
                *(s16x8*)&Ah[off] = h;
                *(s16x8*)&Al[off] = l;
            }
        } else {
#pragma unroll
            for (int u = 0; u < 4; ++u) {
                int idx = t * 4 + u;
                int r = idx >> 3, kc = (idx & 7) << 2;
                int row = row0 + r;
                float v[4] = {0.f, 0.f, 0.f, 0.f};
                if (row < nrows) {
                    if (AMODE == 0) {
                        float4 q = *(const float4*)(Af + (size_t)row * 256 + k0 + kc);
                        v[0] = q.x; v[1] = q.y; v[2] = q.z; v[3] = q.w;
                    } else {
                        size_t base = (size_t)row * 256 + k0 + kc;
                        s16x4 h0 = *(const s16x4*)(Ahi + base);
                        s16x4 l0 = *(const s16x4*)(Alo + base);
                        s16x4 h1 = *(const s16x4*)(Ahi + (size_t)NN * 256 + base);
                        s16x4 l1 = *(const s16x4*)(Alo + (size_t)NN * 256 + base);
                        s16x4 h2 = *(const s16x4*)(Ahi + (size_t)2 * NN * 256 + base);
                        s16x4 l2 = *(const s16x4*)(Alo + (size_t)2 * NN * 256 + base);
#pragma unroll
                        for (int j = 0; j < 4; ++j)
                            v[j] = b0 * (bf2f(h0[j]) + bf2f(l0[j]))
                                 + b1v * (bf2f(h1[j]) + bf2f(l1[j]))
                                 + b2 * (bf2f(h2[j]) + bf2f(l2[j]));
                    }
                }
                s16x4 hh, ll;
#pragma unroll
                for (int j = 0; j < 4; ++j) {
                    short hs = bfhi(v[j]);
                    hh[j] = hs;
                    ll[j] = bfhi(v[j] - bf2f(hs));
                }
                int c = kc >> 3, sub = kc & 7;
                int off = r * 32 + ((c ^ ((r >> 1) & 3)) << 3) + sub;
                *(s16x4*)&Ah[off] = hh;
                *(s16x4*)&Al[off] = ll;
            }
        }
        {
            int n = t >> 2, c = t & 3;
            s16x8 h = *(const s16x8*)(Wthi + (size_t)(col0 + n) * 256 + k0 + c * 8);
            s16x8 l = *(const s16x8*)(Wtlo + (size_t)(col0 + n) * 256 + k0 + c * 8);
            int off = n * 32 + ((c ^ ((n >> 1) & 3)) << 3);
            *(s16x8*)&Bh[off] = h;
            *(s16x8*)&Bl[off] = l;
        }
        __syncthreads();
        int ar_ = lane & 15, ac = lane >> 4;
        s16x8 afh[4], afl[4], bfh[2], bfl[2];
#pragma unroll
        for (int i = 0; i < 4; ++i) {
            int r = wm * 64 + i * 16 + ar_;
            int off = r * 32 + ((ac ^ ((r >> 1) & 3)) << 3);
            afh[i] = *(const s16x8*)&Ah[off];
            afl[i] = *(const s16x8*)&Al[off];
        }
#pragma unroll
        for (int j = 0; j < 2; ++j) {
            int n = wn * 32 + j * 16 + ar_;
            int off = n * 32 + ((ac ^ ((n >> 1) & 3)) << 3);
            bfh[j] = *(const s16x8*)&Bh[off];
            bfl[j] = *(const s16x8*)&Bl[off];
        }
#pragma unroll
        for (int i = 0; i < 4; ++i)
#pragma unroll
            for (int j = 0; j < 2; ++j) {
                acc[i][j] = __builtin_amdgcn_mfma_f32_16x16x32_bf16(afh[i], bfh[j], acc[i][j], 0, 0, 0);
                acc[i][j] = __builtin_amdgcn_mfma_f32_16x16x32_bf16(afh[i], bfl[j], acc[i][j], 0, 0, 0);
                acc[i][j] = __builtin_amdgcn_mfma_f32_16x16x32_bf16(afl[i], bfh[j], acc[i][j], 0, 0, 0);
            }
        __syncthreads();
    }

    // ---- C write (skipped for EPI==2) ----
    if (EPI != 2) {
#pragma unroll
        for (int i = 0; i < 4; ++i) {
            int rbase = row0 + wm * 64 + i * 16 + (lane >> 4) * 4;
#pragma unroll
            for (int j = 0; j < 2; ++j) {
                int col = col0 + wn * 32 + j * 16 + (lane & 15);
                float badd = (EPI == 0 && bias) ? bias[col] : 0.f;
#pragma unroll
                for (int q = 0; q < 4; ++q) {
                    int row = rbase + q;
                    if (row < nrows) C[(size_t)row * ldc + col] = acc[i][j][q] + badd;
                }
            }
        }
    }

    // ---- fused el/er: block = head blockIdx.y, cols col0..col0+63 ----
    if (EPI == 1) {
        int cA = col0 + wn * 32 + (lane & 15);
        int cB = cA + 16;
        float alv0 = al[cA], alv1 = al[cB];
        float arv0 = ar[cA], arv1 = ar[cB];
#pragma unroll
        for (int i = 0; i < 4; ++i)
#pragma unroll
            for (int q = 0; q < 4; ++q) {
                float ep = acc[i][0][q] * alv0 + acc[i][1][q] * alv1;
                float rp_ = acc[i][0][q] * arv0 + acc[i][1][q] * arv1;
#pragma unroll
                for (int msk = 1; msk < 16; msk <<= 1) {
                    ep += __shfl_xor(ep, msk);
                    rp_ += __shfl_xor(rp_, msk);
                }
                if ((lane & 15) == 0) {
                    int rloc = wm * 64 + i * 16 + (lane >> 4) * 4 + q;
                    sred[0][rloc][wn] = ep;
                    sred[1][rloc][wn] = rp_;
                }
            }
        __syncthreads();
        if (t < 128) {
            int row = row0 + t;
            if (row < nrows) {
                el[row * 4 + blockIdx.y] = sred[0][t][0] + sred[0][t][1];
                er[row * 4 + blockIdx.y] = sred[1][t][0] + sred[1][t][1];
            }
        }
    }

    // ---- fused semantic reduce: w_m += sum_rows tanh(acc + b1) . W2 ----
    if (EPI == 2) {
        if (t < 3) wpart[t] = 0.f;
        int cA = col0 + wn * 32 + (lane & 15);
        int cB = cA + 16;
        float b1a = bias[cA], b1b = bias[cB];
        float w2a = al[cA], w2b = al[cB];
#pragma unroll
        for (int i = 0; i < 4; ++i)
#pragma unroll
            for (int q = 0; q < 4; ++q) {
                float ep = tanhf(acc[i][0][q] + b1a) * w2a
                         + tanhf(acc[i][1][q] + b1b) * w2b;
#pragma unroll
                for (int msk = 1; msk < 16; msk <<= 1) ep += __shfl_xor(ep, msk);
                if ((lane & 15) == 0) {
                    int rloc = wm * 64 + i * 16 + (lane >> 4) * 4 + q;
                    sred[0][rloc][wn] = ep;
                }
            }
        __syncthreads();
        if (t < 128) {
            int row = row0 + t;
            if (row < nrows) {
                float tot = sred[0][t][0] + sred[0][t][1];
                atomicAdd(&wpart[row / NN], tot);
            }
        }
        __syncthreads();
        if (t < 3) atomicAdd(&wsum[t], wpart[t]);
    }
}

// ---------------- edge-softmax aggregation ----------------
// 4 waves per dst node (1 head each), unroll x2: 8 independent gather chains
// per node; 200k waves total for latency hiding and tail balance.

__global__ __launch_bounds__(256) void agg_edges_kernel(const float* __restrict__ feat,
                                                        const float* __restrict__ el,
                                                        const float* __restrict__ er,
                                                        const int* __restrict__ row_ptr,
                                                        const int* __restrict__ ssrc,
                                                        const float* __restrict__ bias,
                                                        short* __restrict__ out_hi,
                                                        short* __restrict__ out_lo) {
    int h = threadIdx.x >> 6;
    int lane = threadIdx.x & 63;
    int n = blockIdx.x;
    int beg = row_ptr[n], end = row_ptr[n + 1];
    float ern = er[n * 4 + h];
    const float* fb = feat + h * 64 + lane;
    float accA = 0.f, denA = 0.f, accB = 0.f, denB = 0.f;
    int j = beg;
    for (; j + 1 < end; j += 2) {
        int sA = ssrc[j], sB = ssrc[j + 1];
        float eA = el[sA * 4 + h];
        float eB = el[sB * 4 + h];
        float fA = fb[(size_t)sA * 256];
        float fB = fb[(size_t)sB * 256];
        eA += ern; eA = eA > 0.f ? eA : 0.2f * eA; float wA = __expf(eA);
        eB += ern; eB = eB > 0.f ? eB : 0.2f * eB; float wB = __expf(eB);
        accA = fmaf(wA, fA, accA); denA += wA;
        accB = fmaf(wB, fB, accB); denB += wB;
    }
    if (j < end) {
        int s = ssrc[j];
        float e = el[s * 4 + h] + ern;
        e = e > 0.f ? e : 0.2f * e;
        float w = __expf(e);
        accA = fmaf(w, fb[(size_t)s * 256], accA); denA += w;
    }
    float acc = accA + accB, den = denA + denB;
    float o = acc / fmaxf(den, 1e-9f) + bias[h * 64 + lane];
    o = o > 0.f ? o : __expf(o) - 1.0f;
    size_t idx = (size_t)n * 256 + h * 64 + lane;
    short hs = bfhi(o);
    out_hi[idx] = hs;
    out_lo[idx] = bfhi(o - bf2f(hs));
}

// ---------------- beta ----------------

__global__ void beta_kernel(const float* __restrict__ wsum, float* __restrict__ beta) {
    if (threadIdx.x == 0 && blockIdx.x == 0) {
        float w0 = wsum[0] / (float)NN, w1 = wsum[1] / (float)NN, w2 = wsum[2] / (float)NN;
        float mx = fmaxf(w0, fmaxf(w1, w2));
        float e0 = __expf(w0 - mx), e1 = __expf(w1 - mx), e2 = __expf(w2 - mx);
        float s = e0 + e1 + e2;
        beta[0] = e0 / s; beta[1] = e1 / s; beta[2] = e2 / s;
    }
}

// ---------------- host launch ----------------

extern "C" void kernel_launch(void* const* d_in, const int* in_sizes, int n_in,
                              void* d_out, int out_size, void* d_ws, size_t ws_size,
                              hipStream_t stream) {
    const float* x        = (const float*)d_in[0];
    const float* W_gat    = (const float*)d_in[1];
    const float* attn_l   = (const float*)d_in[2];
    const float* attn_r   = (const float*)d_in[3];
    const float* bias_gat = (const float*)d_in[4];
    const float* W1       = (const float*)d_in[5];
    const float* b1       = (const float*)d_in[6];
    const float* W2       = (const float*)d_in[7];
    const float* Wp       = (const float*)d_in[8];
    const float* bp       = (const float*)d_in[9];
    const int*   src      = (const int*)d_in[10];
    const int*   dst      = (const int*)d_in[11];
    float* out = (float*)d_out;

    char* ws = (char*)d_ws;
    size_t off = 0;
    auto alloc = [&](size_t bytes) { size_t o = off; off = (off + bytes + 255) & ~(size_t)255; return o; };
    short* Hb_hi   = (short*)(ws + alloc((size_t)MM * NN * 256 * 2));
    short* Hb_lo   = (short*)(ws + alloc((size_t)MM * NN * 256 * 2));
    float* feat    = (float*)(ws + alloc((size_t)NN * 256 * 4));
    float* el      = (float*)(ws + alloc((size_t)NN * 4 * 4));
    float* er      = (float*)(ws + alloc((size_t)NN * 4 * 4));
    int*   counts  = (int*)(ws + alloc((size_t)MM * NN * 4));
    int*   row_ptr = (int*)(ws + alloc((size_t)MM * (NN + 1) * 4));
    int*   cursor  = (int*)(ws + alloc((size_t)MM * (NN + 1) * 4));
    int*   ssrc    = (int*)(ws + alloc((size_t)MM * EE * 4));
    int*   bsum    = (int*)(ws + alloc((size_t)MM * NCHUNK * 4));
    short* Whi     = (short*)(ws + alloc((size_t)W_TOT * 2));
    short* Wlo     = (short*)(ws + alloc((size_t)W_TOT * 2));
    float* wsum    = (float*)(ws + alloc(16));
    float* beta    = (float*)(ws + alloc(16));

    init_kernel<<<dim3((MM * NN + 255) / 256), 256, 0, stream>>>(counts, wsum);
    hist_kernel<<<dim3((EE + 255) / 256, MM), 256, 0, stream>>>(dst, counts);
    scan_partial_kernel<<<dim3(NCHUNK, MM), 256, 0, stream>>>(counts, row_ptr, bsum);
    scan_top_kernel<<<dim3(1), 256, 0, stream>>>(bsum);
    scan_add_kernel<<<dim3(NCHUNK, MM), 256, 0, stream>>>(bsum, row_ptr, cursor);
    scatter_kernel<<<dim3((EE + 255) / 256, MM), 256, 0, stream>>>(src, dst, cursor, ssrc);
    splitW_kernel<<<dim3((W_TOT + 255) / 256), 256, 0, stream>>>(W_gat, W1, Wp, Whi, Wlo);

    const int rowTiles = (NN + 127) / 128;

    for (int l = 0; l < 2; ++l) {
        for (int i = 0; i < MM; ++i) {
            const short* wh = Whi + (size_t)(l * MM + i) * 65536;
            const short* wl = Wlo + (size_t)(l * MM + i) * 65536;
            const float* alp = attn_l + (size_t)(l * MM + i) * 256;
            const float* arp = attn_r + (size_t)(l * MM + i) * 256;
            if (l == 0)
                mfma_gemm<0, 1><<<dim3(rowTiles, 4), 256, 0, stream>>>(
                    x + (size_t)i * NN * 256, nullptr, nullptr, wh, wl,
                    feat, nullptr, nullptr, alp, arp, el, er, nullptr, NN, 256);
            else
                mfma_gemm<1, 1><<<dim3(rowTiles, 4), 256, 0, stream>>>(
                    nullptr, Hb_hi + (size_t)i * NN * 256, Hb_lo + (size_t)i * NN * 256,
                    wh, wl, feat, nullptr, nullptr, alp, arp, el, er, nullptr, NN, 256);
            agg_edges_kernel<<<dim3(NN), 256, 0, stream>>>(
                feat, el, er, row_ptr + (size_t)i * (NN + 1), ssrc + (size_t)i * EE,
                bias_gat + (size_t)(l * MM + i) * 256,
                Hb_hi + (size_t)i * NN * 256, Hb_lo + (size_t)i * NN * 256);
        }
    }

    // semantic attention: batched GEMM with fused tanh/W2 row-reduction (no C write)
    mfma_gemm<1, 2><<<dim3((MM * NN + 127) / 128, 1), 256, 0, stream>>>(
        nullptr, Hb_hi, Hb_lo, Whi + WG_ELEMS, Wlo + WG_ELEMS,
        nullptr, b1, nullptr, W2, nullptr, nullptr, nullptr, wsum, MM * NN, 64);
    beta_kernel<<<dim3(1), 64, 0, stream>>>(wsum, beta);
    // final projection with fused beta-combine
    mfma_gemm<2, 0><<<dim3(rowTiles, 1), 256, 0, stream>>>(
        nullptr, Hb_hi, Hb_lo, Whi + WG_ELEMS + 16384, Wlo + WG_ELEMS + 16384,
        out, bp, beta, nullptr, nullptr, nullptr, nullptr, nullptr, NN, 64);
}

// Round 6
// 1014.441 us; speedup vs baseline: 3.5247x; 1.1229x over previous
//
#include <hip/hip_runtime.h>

#define NN 50000
#define EE 400000
#define MM 3
#define CHUNK 2048
#define NCHUNK ((NN + CHUNK - 1) / CHUNK)   // 25

typedef float f32x4 __attribute__((ext_vector_type(4)));
typedef short s16x8 __attribute__((ext_vector_type(8)));
typedef short s16x4 __attribute__((ext_vector_type(4)));
typedef _Float16 half_t;
typedef _Float16 h16x2 __attribute__((ext_vector_type(2)));

union FU { float f; unsigned u; };

__device__ inline short bfhi(float x) {
    FU c; c.f = x;
    unsigned u = c.u;
    return (short)((u + 0x7fffu + ((u >> 16) & 1u)) >> 16);
}
__device__ inline float bf2f(short h) {
    FU c; c.u = ((unsigned)(unsigned short)h) << 16;
    return c.f;
}

// ---------------- CSR build ----------------

__global__ __launch_bounds__(256) void init_kernel(int* counts, float* wsum) {
    int idx = blockIdx.x * 256 + threadIdx.x;
    if (idx < MM * NN) counts[idx] = 0;
    if (idx < MM) wsum[idx] = 0.0f;
}

__global__ __launch_bounds__(256) void hist_kernel(const int* __restrict__ dst,
                                                   int* __restrict__ counts) {
    int m = blockIdx.y;
    int e = blockIdx.x * 256 + threadIdx.x;
    if (e < EE) atomicAdd(&counts[m * NN + dst[m * EE + e]], 1);
}

__global__ __launch_bounds__(256) void scan_partial_kernel(const int* __restrict__ counts,
                                                           int* __restrict__ rp,
                                                           int* __restrict__ bsum) {
    int m = blockIdx.y, ch = blockIdx.x;
    const int* c = counts + m * NN;
    int* r = rp + m * (NN + 1);
    int t = threadIdx.x, lane = t & 63, wave = t >> 6;
    int i0 = ch * CHUNK + t * 8;
    int v[8]; int s = 0;
#pragma unroll
    for (int k = 0; k < 8; ++k) { int i = i0 + k; v[k] = (i < NN) ? c[i] : 0; s += v[k]; }
    int incl = s;
#pragma unroll
    for (int off = 1; off < 64; off <<= 1) {
        int u = __shfl_up(incl, off);
        if (lane >= off) incl += u;
    }
    int excl = incl - s;
    __shared__ int wsh[4];
    if (lane == 63) wsh[wave] = incl;
    __syncthreads();
    int woff = 0;
    for (int w = 0; w < wave; ++w) woff += wsh[w];
    int run = excl + woff;
#pragma unroll
    for (int k = 0; k < 8; ++k) { int i = i0 + k; if (i < NN) r[i] = run; run += v[k]; }
    if (t == 255) bsum[m * NCHUNK + ch] = woff + incl;
}

__global__ __launch_bounds__(256) void scan_top_kernel(int* __restrict__ bsum) {
    int wave = threadIdx.x >> 6, lane = threadIdx.x & 63;
    if (wave < MM) {
        int v = (lane < NCHUNK) ? bsum[wave * NCHUNK + lane] : 0;
        int incl = v;
#pragma unroll
        for (int off = 1; off < 64; off <<= 1) {
            int u = __shfl_up(incl, off);
            if (lane >= off) incl += u;
        }
        if (lane < NCHUNK) bsum[wave * NCHUNK + lane] = incl - v;
    }
}

__global__ __launch_bounds__(256) void scan_add_kernel(const int* __restrict__ bsum,
                                                       int* __restrict__ rp,
                                                       int* __restrict__ cur) {
    int m = blockIdx.y, ch = blockIdx.x;
    int off = bsum[m * NCHUNK + ch];
    int* r = rp + m * (NN + 1);
    int* q = cur + m * (NN + 1);
    int i0 = ch * CHUNK + threadIdx.x * 8;
#pragma unroll
    for (int k = 0; k < 8; ++k) {
        int i = i0 + k;
        if (i < NN) { int val = r[i] + off; r[i] = val; q[i] = val; }
    }
    if (ch == 0 && threadIdx.x == 0) r[NN] = EE;
}

__global__ __launch_bounds__(256) void scatter_kernel(const int* __restrict__ src,
                                                      const int* __restrict__ dst,
                                                      int* __restrict__ cursor,
                                                      int* __restrict__ ssrc) {
    int m = blockIdx.y;
    int e = blockIdx.x * 256 + threadIdx.x;
    if (e < EE) {
        int d = dst[m * EE + e];
        int pos = atomicAdd(&cursor[m * (NN + 1) + d], 1);
        ssrc[m * EE + pos] = src[m * EE + e];
    }
}

// ---------------- weight transpose + split ----------------

#define WG_ELEMS (6 * 256 * 256)
#define W_TOT (WG_ELEMS + 2 * 64 * 256)

__global__ __launch_bounds__(256) void splitW_kernel(const float* __restrict__ Wg,
                                                     const float* __restrict__ W1,
                                                     const float* __restrict__ Wp,
                                                     short* __restrict__ Whi,
                                                     short* __restrict__ Wlo) {
    int idx = blockIdx.x * 256 + threadIdx.x;
    if (idx >= W_TOT) return;
    float v;
    if (idx < WG_ELEMS) {
        int mat = idx >> 16, rem = idx & 65535;
        int n = rem >> 8, k = rem & 255;
        v = Wg[mat * 65536 + k * 256 + n];
    } else {
        int i2 = idx - WG_ELEMS;
        int mat = i2 >> 14, rem = i2 & 16383;
        int n = rem >> 8, k = rem & 255;
        v = (mat ? Wp : W1)[k * 64 + n];
    }
    short h = bfhi(v);
    Whi[idx] = h;
    Wlo[idx] = bfhi(v - bf2f(h));
}

// ---------------- MFMA GEMM (split-bf16 3-product) ----------------
// EPI 0: write fp32 C (+bias). EPI 1: write fp16 Ch and fused el/er (block =
// one head's 64 cols). EPI 2: no C write; fused tanh-dot-W2 row reduction.

template<int AMODE, int EPI>
__global__ __launch_bounds__(256) void mfma_gemm(
    const float* __restrict__ Af,
    const short* __restrict__ Ahi, const short* __restrict__ Alo,
    const short* __restrict__ Wthi, const short* __restrict__ Wtlo,
    float* __restrict__ C, half_t* __restrict__ Ch,
    const float* __restrict__ bias,
    const float* __restrict__ beta,
    const float* __restrict__ al, const float* __restrict__ ar,
    float* __restrict__ el, float* __restrict__ er,
    float* __restrict__ wsum,
    int nrows, int ldc) {
    __shared__ short Ah[128 * 32], Al[128 * 32], Bh[64 * 32], Bl[64 * 32];
    __shared__ float sred[2][128][2];
    __shared__ float wpart[3];
    const int t = threadIdx.x;
    const int lane = t & 63;
    const int wave = t >> 6;
    const int wm = wave >> 1, wn = wave & 1;
    const int row0 = blockIdx.x * 128;
    const int col0 = blockIdx.y * 64;
    float b0 = 0.f, b1v = 0.f, b2 = 0.f;
    if (AMODE == 2) { b0 = beta[0]; b1v = beta[1]; b2 = beta[2]; }
    f32x4 acc[4][2] = {};

    for (int k0 = 0; k0 < 256; k0 += 32) {
        if (AMODE == 1) {
#pragma unroll
            for (int u = 0; u < 2; ++u) {
                int idx = t * 2 + u;
                int r = idx >> 2, c = idx & 3;
                int row = row0 + r;
                s16x8 h = {0, 0, 0, 0, 0, 0, 0, 0};
                s16x8 l = {0, 0, 0, 0, 0, 0, 0, 0};
                if (row < nrows) {
                    h = *(const s16x8*)(Ahi + (size_t)row * 256 + k0 + c * 8);
                    l = *(const s16x8*)(Alo + (size_t)row * 256 + k0 + c * 8);
                }
                int off = r * 32 + ((c ^ ((r >> 1) & 3)) << 3);
                *(s16x8*)&Ah[off] = h;
                *(s16x8*)&Al[off] = l;
            }
        } else {
#pragma unroll
            for (int u = 0; u < 4; ++u) {
                int idx = t * 4 + u;
                int r = idx >> 3, kc = (idx & 7) << 2;
                int row = row0 + r;
                float v[4] = {0.f, 0.f, 0.f, 0.f};
                if (row < nrows) {
                    if (AMODE == 0) {
                        float4 q = *(const float4*)(Af + (size_t)row * 256 + k0 + kc);
                        v[0] = q.x; v[1] = q.y; v[2] = q.z; v[3] = q.w;
                    } else {
                        size_t base = (size_t)row * 256 + k0 + kc;
                        s16x4 h0 = *(const s16x4*)(Ahi + base);
                        s16x4 l0 = *(const s16x4*)(Alo + base);
                        s16x4 h1 = *(const s16x4*)(Ahi + (size_t)NN * 256 + base);
                        s16x4 l1 = *(const s16x4*)(Alo + (size_t)NN * 256 + base);
                        s16x4 h2 = *(const s16x4*)(Ahi + (size_t)2 * NN * 256 + base);
                        s16x4 l2 = *(const s16x4*)(Alo + (size_t)2 * NN * 256 + base);
#pragma unroll
                        for (int j = 0; j < 4; ++j)
                            v[j] = b0 * (bf2f(h0[j]) + bf2f(l0[j]))
                                 + b1v * (bf2f(h1[j]) + bf2f(l1[j]))
                                 + b2 * (bf2f(h2[j]) + bf2f(l2[j]));
                    }
                }
                s16x4 hh, ll;
#pragma unroll
                for (int j = 0; j < 4; ++j) {
                    short hs = bfhi(v[j]);
                    hh[j] = hs;
                    ll[j] = bfhi(v[j] - bf2f(hs));
                }
                int c = kc >> 3, sub = kc & 7;
                int off = r * 32 + ((c ^ ((r >> 1) & 3)) << 3) + sub;
                *(s16x4*)&Ah[off] = hh;
                *(s16x4*)&Al[off] = ll;
            }
        }
        {
            int n = t >> 2, c = t & 3;
            s16x8 h = *(const s16x8*)(Wthi + (size_t)(col0 + n) * 256 + k0 + c * 8);
            s16x8 l = *(const s16x8*)(Wtlo + (size_t)(col0 + n) * 256 + k0 + c * 8);
            int off = n * 32 + ((c ^ ((n >> 1) & 3)) << 3);
            *(s16x8*)&Bh[off] = h;
            *(s16x8*)&Bl[off] = l;
        }
        __syncthreads();
        int ar_ = lane & 15, ac = lane >> 4;
        s16x8 afh[4], afl[4], bfh[2], bfl[2];
#pragma unroll
        for (int i = 0; i < 4; ++i) {
            int r = wm * 64 + i * 16 + ar_;
            int off = r * 32 + ((ac ^ ((r >> 1) & 3)) << 3);
            afh[i] = *(const s16x8*)&Ah[off];
            afl[i] = *(const s16x8*)&Al[off];
        }
#pragma unroll
        for (int j = 0; j < 2; ++j) {
            int n = wn * 32 + j * 16 + ar_;
            int off = n * 32 + ((ac ^ ((n >> 1) & 3)) << 3);
            bfh[j] = *(const s16x8*)&Bh[off];
            bfl[j] = *(const s16x8*)&Bl[off];
        }
#pragma unroll
        for (int i = 0; i < 4; ++i)
#pragma unroll
            for (int j = 0; j < 2; ++j) {
                acc[i][j] = __builtin_amdgcn_mfma_f32_16x16x32_bf16(afh[i], bfh[j], acc[i][j], 0, 0, 0);
                acc[i][j] = __builtin_amdgcn_mfma_f32_16x16x32_bf16(afh[i], bfl[j], acc[i][j], 0, 0, 0);
                acc[i][j] = __builtin_amdgcn_mfma_f32_16x16x32_bf16(afl[i], bfh[j], acc[i][j], 0, 0, 0);
            }
        __syncthreads();
    }

    // ---- C write ----
    if (EPI == 0) {
#pragma unroll
        for (int i = 0; i < 4; ++i) {
            int rbase = row0 + wm * 64 + i * 16 + (lane >> 4) * 4;
#pragma unroll
            for (int j = 0; j < 2; ++j) {
                int col = col0 + wn * 32 + j * 16 + (lane & 15);
                float badd = bias ? bias[col] : 0.f;
#pragma unroll
                for (int q = 0; q < 4; ++q) {
                    int row = rbase + q;
                    if (row < nrows) C[(size_t)row * ldc + col] = acc[i][j][q] + badd;
                }
            }
        }
    }
    if (EPI == 1) {
#pragma unroll
        for (int i = 0; i < 4; ++i) {
            int rbase = row0 + wm * 64 + i * 16 + (lane >> 4) * 4;
#pragma unroll
            for (int j = 0; j < 2; ++j) {
                int col = col0 + wn * 32 + j * 16 + (lane & 15);
#pragma unroll
                for (int q = 0; q < 4; ++q) {
                    int row = rbase + q;
                    if (row < nrows) Ch[(size_t)row * ldc + col] = (half_t)acc[i][j][q];
                }
            }
        }
        // fused el/er: block = head blockIdx.y, cols col0..col0+63
        int cA = col0 + wn * 32 + (lane & 15);
        int cB = cA + 16;
        float alv0 = al[cA], alv1 = al[cB];
        float arv0 = ar[cA], arv1 = ar[cB];
#pragma unroll
        for (int i = 0; i < 4; ++i)
#pragma unroll
            for (int q = 0; q < 4; ++q) {
                float ep = acc[i][0][q] * alv0 + acc[i][1][q] * alv1;
                float rp_ = acc[i][0][q] * arv0 + acc[i][1][q] * arv1;
#pragma unroll
                for (int msk = 1; msk < 16; msk <<= 1) {
                    ep += __shfl_xor(ep, msk);
                    rp_ += __shfl_xor(rp_, msk);
                }
                if ((lane & 15) == 0) {
                    int rloc = wm * 64 + i * 16 + (lane >> 4) * 4 + q;
                    sred[0][rloc][wn] = ep;
                    sred[1][rloc][wn] = rp_;
                }
            }
        __syncthreads();
        if (t < 128) {
            int row = row0 + t;
            if (row < nrows) {
                el[row * 4 + blockIdx.y] = sred[0][t][0] + sred[0][t][1];
                er[row * 4 + blockIdx.y] = sred[1][t][0] + sred[1][t][1];
            }
        }
    }

    if (EPI == 2) {
        if (t < 3) wpart[t] = 0.f;
        int cA = col0 + wn * 32 + (lane & 15);
        int cB = cA + 16;
        float b1a = bias[cA], b1b = bias[cB];
        float w2a = al[cA], w2b = al[cB];
#pragma unroll
        for (int i = 0; i < 4; ++i)
#pragma unroll
            for (int q = 0; q < 4; ++q) {
                float ep = tanhf(acc[i][0][q] + b1a) * w2a
                         + tanhf(acc[i][1][q] + b1b) * w2b;
#pragma unroll
                for (int msk = 1; msk < 16; msk <<= 1) ep += __shfl_xor(ep, msk);
                if ((lane & 15) == 0) {
                    int rloc = wm * 64 + i * 16 + (lane >> 4) * 4 + q;
                    sred[0][rloc][wn] = ep;
                }
            }
        __syncthreads();
        if (t < 128) {
            int row = row0 + t;
            if (row < nrows) {
                float tot = sred[0][t][0] + sred[0][t][1];
                atomicAdd(&wpart[row / NN], tot);
            }
        }
        __syncthreads();
        if (t < 3) atomicAdd(&wsum[t], wpart[t]);
    }
}

// ---------------- edge-softmax aggregation ----------------
// fp16 feat gather. 2 waves/node, 2 heads/wave: lane<32 -> head 2w, lane>=32
// -> head 2w+1; each lane loads h16x2 (4B) = 2 elements of its head slice.
// Unroll x2 -> 4 independent gather chains per node; per-edge VALU halved.

__global__ __launch_bounds__(256) void agg_edges_kernel(const half_t* __restrict__ feat,
                                                        const float* __restrict__ el,
                                                        const float* __restrict__ er,
                                                        const int* __restrict__ row_ptr,
                                                        const int* __restrict__ ssrc,
                                                        const float* __restrict__ bias,
                                                        short* __restrict__ out_hi,
                                                        short* __restrict__ out_lo) {
    int wave = threadIdx.x >> 6;
    int lane = threadIdx.x & 63;
    int n = blockIdx.x * 2 + (wave >> 1);
    if (n >= NN) return;
    int w = wave & 1;
    int h = 2 * w + (lane >> 5);
    int elem = (lane & 31) * 2;
    int beg = row_ptr[n], end = row_ptr[n + 1];
    float ern = er[n * 4 + h];
    const h16x2* fb = (const h16x2*)feat + w * 64 + lane;
    float accA0 = 0.f, accA1 = 0.f, denA = 0.f;
    float accB0 = 0.f, accB1 = 0.f, denB = 0.f;
    int j = beg;
    for (; j + 1 < end; j += 2) {
        int sA = ssrc[j], sB = ssrc[j + 1];
        float eA = el[sA * 4 + h];
        float eB = el[sB * 4 + h];
        h16x2 fA = fb[(size_t)sA * 128];
        h16x2 fB = fb[(size_t)sB * 128];
        eA += ern; eA = eA > 0.f ? eA : 0.2f * eA; float wA = __expf(eA);
        eB += ern; eB = eB > 0.f ? eB : 0.2f * eB; float wB = __expf(eB);
        accA0 = fmaf(wA, (float)fA.x, accA0);
        accA1 = fmaf(wA, (float)fA.y, accA1); denA += wA;
        accB0 = fmaf(wB, (float)fB.x, accB0);
        accB1 = fmaf(wB, (float)fB.y, accB1); denB += wB;
    }
    if (j < end) {
        int s = ssrc[j];
        float e = el[s * 4 + h] + ern;
        e = e > 0.f ? e : 0.2f * e;
        float wgt = __expf(e);
        h16x2 f = fb[(size_t)s * 128];
        accA0 = fmaf(wgt, (float)f.x, accA0);
        accA1 = fmaf(wgt, (float)f.y, accA1); denA += wgt;
    }
    float den = fmaxf(denA + denB, 1e-9f);
    float o0 = (accA0 + accB0) / den + bias[h * 64 + elem];
    float o1 = (accA1 + accB1) / den + bias[h * 64 + elem + 1];
    o0 = o0 > 0.f ? o0 : __expf(o0) - 1.0f;
    o1 = o1 > 0.f ? o1 : __expf(o1) - 1.0f;
    size_t idx = (size_t)n * 256 + h * 64 + elem;
    short h0 = bfhi(o0), h1 = bfhi(o1);
    short l0 = bfhi(o0 - bf2f(h0)), l1 = bfhi(o1 - bf2f(h1));
    ushort2 hv; hv.x = (unsigned short)h0; hv.y = (unsigned short)h1;
    ushort2 lv; lv.x = (unsigned short)l0; lv.y = (unsigned short)l1;
    *(ushort2*)&out_hi[idx] = hv;
    *(ushort2*)&out_lo[idx] = lv;
}

// ---------------- beta ----------------

__global__ void beta_kernel(const float* __restrict__ wsum, float* __restrict__ beta) {
    if (threadIdx.x == 0 && blockIdx.x == 0) {
        float w0 = wsum[0] / (float)NN, w1 = wsum[1] / (float)NN, w2 = wsum[2] / (float)NN;
        float mx = fmaxf(w0, fmaxf(w1, w2));
        float e0 = __expf(w0 - mx), e1 = __expf(w1 - mx), e2 = __expf(w2 - mx);
        float s = e0 + e1 + e2;
        beta[0] = e0 / s; beta[1] = e1 / s; beta[2] = e2 / s;
    }
}

// ---------------- host launch ----------------

extern "C" void kernel_launch(void* const* d_in, const int* in_sizes, int n_in,
                              void* d_out, int out_size, void* d_ws, size_t ws_size,
                              hipStream_t stream) {
    const float* x        = (const float*)d_in[0];
    const float* W_gat    = (const float*)d_in[1];
    const float* attn_l   = (const float*)d_in[2];
    const float* attn_r   = (const float*)d_in[3];
    const float* bias_gat = (const float*)d_in[4];
    const float* W1       = (const float*)d_in[5];
    const float* b1       = (const float*)d_in[6];
    const float* W2       = (const float*)d_in[7];
    const float* Wp       = (const float*)d_in[8];
    const float* bp       = (const float*)d_in[9];
    const int*   src      = (const int*)d_in[10];
    const int*   dst      = (const int*)d_in[11];
    float* out = (float*)d_out;

    char* ws = (char*)d_ws;
    size_t off = 0;
    auto alloc = [&](size_t bytes) { size_t o = off; off = (off + bytes + 255) & ~(size_t)255; return o; };
    short*  Hb_hi   = (short*)(ws + alloc((size_t)MM * NN * 256 * 2));
    short*  Hb_lo   = (short*)(ws + alloc((size_t)MM * NN * 256 * 2));
    half_t* feat    = (half_t*)(ws + alloc((size_t)NN * 256 * 2));
    float*  el      = (float*)(ws + alloc((size_t)NN * 4 * 4));
    float*  er      = (float*)(ws + alloc((size_t)NN * 4 * 4));
    int*    counts  = (int*)(ws + alloc((size_t)MM * NN * 4));
    int*    row_ptr = (int*)(ws + alloc((size_t)MM * (NN + 1) * 4));
    int*    cursor  = (int*)(ws + alloc((size_t)MM * (NN + 1) * 4));
    int*    ssrc    = (int*)(ws + alloc((size_t)MM * EE * 4));
    int*    bsum    = (int*)(ws + alloc((size_t)MM * NCHUNK * 4));
    short*  Whi     = (short*)(ws + alloc((size_t)W_TOT * 2));
    short*  Wlo     = (short*)(ws + alloc((size_t)W_TOT * 2));
    float*  wsum    = (float*)(ws + alloc(16));
    float*  beta    = (float*)(ws + alloc(16));

    init_kernel<<<dim3((MM * NN + 255) / 256), 256, 0, stream>>>(counts, wsum);
    hist_kernel<<<dim3((EE + 255) / 256, MM), 256, 0, stream>>>(dst, counts);
    scan_partial_kernel<<<dim3(NCHUNK, MM), 256, 0, stream>>>(counts, row_ptr, bsum);
    scan_top_kernel<<<dim3(1), 256, 0, stream>>>(bsum);
    scan_add_kernel<<<dim3(NCHUNK, MM), 256, 0, stream>>>(bsum, row_ptr, cursor);
    scatter_kernel<<<dim3((EE + 255) / 256, MM), 256, 0, stream>>>(src, dst, cursor, ssrc);
    splitW_kernel<<<dim3((W_TOT + 255) / 256), 256, 0, stream>>>(W_gat, W1, Wp, Whi, Wlo);

    const int rowTiles = (NN + 127) / 128;
    const int aggBlocks = (NN + 1) / 2;

    for (int l = 0; l < 2; ++l) {
        for (int i = 0; i < MM; ++i) {
            const short* wh = Whi + (size_t)(l * MM + i) * 65536;
            const short* wl = Wlo + (size_t)(l * MM + i) * 65536;
            const float* alp = attn_l + (size_t)(l * MM + i) * 256;
            const float* arp = attn_r + (size_t)(l * MM + i) * 256;
            if (l == 0)
                mfma_gemm<0, 1><<<dim3(rowTiles, 4), 256, 0, stream>>>(
                    x + (size_t)i * NN * 256, nullptr, nullptr, wh, wl,
                    nullptr, feat, nullptr, nullptr, alp, arp, el, er, nullptr, NN, 256);
            else
                mfma_gemm<1, 1><<<dim3(rowTiles, 4), 256, 0, stream>>>(
                    nullptr, Hb_hi + (size_t)i * NN * 256, Hb_lo + (size_t)i * NN * 256,
                    wh, wl, nullptr, feat, nullptr, nullptr, alp, arp, el, er, nullptr, NN, 256);
            agg_edges_kernel<<<dim3(aggBlocks), 256, 0, stream>>>(
                feat, el, er, row_ptr + (size_t)i * (NN + 1), ssrc + (size_t)i * EE,
                bias_gat + (size_t)(l * MM + i) * 256,
                Hb_hi + (size_t)i * NN * 256, Hb_lo + (size_t)i * NN * 256);
        }
    }

    // semantic attention: batched GEMM with fused tanh/W2 row-reduction (no C write)
    mfma_gemm<1, 2><<<dim3((MM * NN + 127) / 128, 1), 256, 0, stream>>>(
        nullptr, Hb_hi, Hb_lo, Whi + WG_ELEMS, Wlo + WG_ELEMS,
        nullptr, nullptr, b1, nullptr, W2, nullptr, nullptr, nullptr, wsum, MM * NN, 64);
    beta_kernel<<<dim3(1), 64, 0, stream>>>(wsum, beta);
    // final projection with fused beta-combine
    mfma_gemm<2, 0><<<dim3(rowTiles, 1), 256, 0, stream>>>(
        nullptr, Hb_hi, Hb_lo, Whi + WG_ELEMS + 16384, Wlo + WG_ELEMS + 16384,
        out, nullptr, bp, beta, nullptr, nullptr, nullptr, nullptr, nullptr, NN, 64);
}

// Round 7
// 901.851 us; speedup vs baseline: 3.9647x; 1.1248x over previous
//
#include <hip/hip_runtime.h>

#define NN 50000
#define EE 400000
#define MM 3
#define CHUNK 2048
#define NCHUNK ((NN + CHUNK - 1) / CHUNK)   // 25

typedef float f32x4 __attribute__((ext_vector_type(4)));
typedef short s16x8 __attribute__((ext_vector_type(8)));
typedef short s16x4 __attribute__((ext_vector_type(4)));
typedef _Float16 half_t;
typedef _Float16 h16x2 __attribute__((ext_vector_type(2)));

union FU { float f; unsigned u; };

__device__ inline short bfhi(float x) {
    FU c; c.f = x;
    unsigned u = c.u;
    return (short)((u + 0x7fffu + ((u >> 16) & 1u)) >> 16);
}
__device__ inline float bf2f(short h) {
    FU c; c.u = ((unsigned)(unsigned short)h) << 16;
    return c.f;
}

// ---------------- CSR build ----------------

__global__ __launch_bounds__(256) void init_kernel(int* counts, float* wsum) {
    int idx = blockIdx.x * 256 + threadIdx.x;
    if (idx < MM * NN) counts[idx] = 0;
    if (idx < MM) wsum[idx] = 0.0f;
}

__global__ __launch_bounds__(256) void hist_kernel(const int* __restrict__ dst,
                                                   int* __restrict__ counts) {
    int m = blockIdx.y;
    int e = blockIdx.x * 256 + threadIdx.x;
    if (e < EE) atomicAdd(&counts[m * NN + dst[m * EE + e]], 1);
}

__global__ __launch_bounds__(256) void scan_partial_kernel(const int* __restrict__ counts,
                                                           int* __restrict__ rp,
                                                           int* __restrict__ bsum) {
    int m = blockIdx.y, ch = blockIdx.x;
    const int* c = counts + m * NN;
    int* r = rp + m * (NN + 1);
    int t = threadIdx.x, lane = t & 63, wave = t >> 6;
    int i0 = ch * CHUNK + t * 8;
    int v[8]; int s = 0;
#pragma unroll
    for (int k = 0; k < 8; ++k) { int i = i0 + k; v[k] = (i < NN) ? c[i] : 0; s += v[k]; }
    int incl = s;
#pragma unroll
    for (int off = 1; off < 64; off <<= 1) {
        int u = __shfl_up(incl, off);
        if (lane >= off) incl += u;
    }
    int excl = incl - s;
    __shared__ int wsh[4];
    if (lane == 63) wsh[wave] = incl;
    __syncthreads();
    int woff = 0;
    for (int w = 0; w < wave; ++w) woff += wsh[w];
    int run = excl + woff;
#pragma unroll
    for (int k = 0; k < 8; ++k) { int i = i0 + k; if (i < NN) r[i] = run; run += v[k]; }
    if (t == 255) bsum[m * NCHUNK + ch] = woff + incl;
}

__global__ __launch_bounds__(256) void scan_top_kernel(int* __restrict__ bsum) {
    int wave = threadIdx.x >> 6, lane = threadIdx.x & 63;
    if (wave < MM) {
        int v = (lane < NCHUNK) ? bsum[wave * NCHUNK + lane] : 0;
        int incl = v;
#pragma unroll
        for (int off = 1; off < 64; off <<= 1) {
            int u = __shfl_up(incl, off);
            if (lane >= off) incl += u;
        }
        if (lane < NCHUNK) bsum[wave * NCHUNK + lane] = incl - v;
    }
}

__global__ __launch_bounds__(256) void scan_add_kernel(const int* __restrict__ bsum,
                                                       int* __restrict__ rp,
                                                       int* __restrict__ cur) {
    int m = blockIdx.y, ch = blockIdx.x;
    int off = bsum[m * NCHUNK + ch];
    int* r = rp + m * (NN + 1);
    int* q = cur + m * (NN + 1);
    int i0 = ch * CHUNK + threadIdx.x * 8;
#pragma unroll
    for (int k = 0; k < 8; ++k) {
        int i = i0 + k;
        if (i < NN) { int val = r[i] + off; r[i] = val; q[i] = val; }
    }
    if (ch == 0 && threadIdx.x == 0) r[NN] = EE;
}

__global__ __launch_bounds__(256) void scatter_kernel(const int* __restrict__ src,
                                                      const int* __restrict__ dst,
                                                      int* __restrict__ cursor,
                                                      int* __restrict__ ssrc) {
    int m = blockIdx.y;
    int e = blockIdx.x * 256 + threadIdx.x;
    if (e < EE) {
        int d = dst[m * EE + e];
        int pos = atomicAdd(&cursor[m * (NN + 1) + d], 1);
        ssrc[m * EE + pos] = src[m * EE + e];
    }
}

// ---------------- weight transpose + split ----------------
// Layout: [6][256n][256k] W_gat, then [256n][256k] stacked sem weights
// (cols 0-63 = W1, 64-127 = Wp, 128-255 = zero pad).

#define WG_ELEMS (6 * 256 * 256)
#define W_TOT (WG_ELEMS + 256 * 256)

__global__ __launch_bounds__(256) void splitW_kernel(const float* __restrict__ Wg,
                                                     const float* __restrict__ W1,
                                                     const float* __restrict__ Wp,
                                                     short* __restrict__ Whi,
                                                     short* __restrict__ Wlo) {
    int idx = blockIdx.x * 256 + threadIdx.x;
    if (idx >= W_TOT) return;
    float v;
    if (idx < WG_ELEMS) {
        int mat = idx >> 16, rem = idx & 65535;
        int n = rem >> 8, k = rem & 255;
        v = Wg[mat * 65536 + k * 256 + n];
    } else {
        int i2 = idx - WG_ELEMS;
        int n = i2 >> 8, k = i2 & 255;
        v = (n < 64) ? W1[k * 64 + n] : ((n < 128) ? Wp[k * 64 + n - 64] : 0.f);
    }
    short h = bfhi(v);
    Whi[idx] = h;
    Wlo[idx] = bfhi(v - bf2f(h));
}

// ---------------- MFMA GEMM, BM=64 x BN=256, full-width (no col re-read) ----
// 256 threads = 4 waves; wave w computes rows 0-63 x cols [w*64, w*64+64).
// EPI 1: write fp16 feat + per-wave fused el/er (head = wave).
// EPI 3: wave0 = fused tanh-dot-W2 reduce (cols 0-63 = W1); wave1 = write
//        fp32 P (cols 64-127 = Wp); waves 2-3 idle (zero-padded B).

template<int AMODE, int EPI>
__global__ __launch_bounds__(256) void mfma_gemm(
    const float* __restrict__ Af,
    const short* __restrict__ Ahi, const short* __restrict__ Alo,
    const short* __restrict__ Wthi, const short* __restrict__ Wtlo,
    half_t* __restrict__ Ch, float* __restrict__ P,
    const float* __restrict__ al, const float* __restrict__ ar,
    const float* __restrict__ b1, const float* __restrict__ w2,
    float* __restrict__ el, float* __restrict__ er,
    float* __restrict__ wsum,
    int nrows) {
    __shared__ short Ah[64 * 32], Al[64 * 32], Bh[256 * 32], Bl[256 * 32];
    const int t = threadIdx.x;
    const int lane = t & 63;
    const int wn = t >> 6;          // wave = col quadrant (head)
    const int row0 = blockIdx.x * 64;
    f32x4 acc[4][4] = {};

    for (int k0 = 0; k0 < 256; k0 += 32) {
        // ---- stage A (64 rows x 32 k, bf16 hi/lo, XOR-swizzled) ----
        {
            int r = t >> 2, c = t & 3;
            int row = row0 + r;
            int off = r * 32 + ((c ^ ((r >> 1) & 3)) << 3);
            if (AMODE == 1) {
                s16x8 h = {0, 0, 0, 0, 0, 0, 0, 0};
                s16x8 l = {0, 0, 0, 0, 0, 0, 0, 0};
                if (row < nrows) {
                    h = *(const s16x8*)(Ahi + (size_t)row * 256 + k0 + c * 8);
                    l = *(const s16x8*)(Alo + (size_t)row * 256 + k0 + c * 8);
                }
                *(s16x8*)&Ah[off] = h;
                *(s16x8*)&Al[off] = l;
            } else {
                float v[8] = {0, 0, 0, 0, 0, 0, 0, 0};
                if (row < nrows) {
                    float4 q0 = *(const float4*)(Af + (size_t)row * 256 + k0 + c * 8);
                    float4 q1 = *(const float4*)(Af + (size_t)row * 256 + k0 + c * 8 + 4);
                    v[0] = q0.x; v[1] = q0.y; v[2] = q0.z; v[3] = q0.w;
                    v[4] = q1.x; v[5] = q1.y; v[6] = q1.z; v[7] = q1.w;
                }
                s16x8 hh, ll;
#pragma unroll
                for (int j = 0; j < 8; ++j) {
                    short hs = bfhi(v[j]);
                    hh[j] = hs;
                    ll[j] = bfhi(v[j] - bf2f(hs));
                }
                *(s16x8*)&Ah[off] = hh;
                *(s16x8*)&Al[off] = ll;
            }
        }
        // ---- stage B (256 cols x 32 k) ----
#pragma unroll
        for (int u = 0; u < 4; ++u) {
            int n = u * 64 + (t >> 2), c = t & 3;
            s16x8 h = *(const s16x8*)(Wthi + (size_t)n * 256 + k0 + c * 8);
            s16x8 l = *(const s16x8*)(Wtlo + (size_t)n * 256 + k0 + c * 8);
            int off = n * 32 + ((c ^ ((n >> 1) & 3)) << 3);
            *(s16x8*)&Bh[off] = h;
            *(s16x8*)&Bl[off] = l;
        }
        __syncthreads();
        // ---- MFMA: 16 frag pairs x 3 products ----
        int fr = lane & 15, ac = lane >> 4;
        s16x8 afh[4], afl[4], bfh[4], bfl[4];
#pragma unroll
        for (int i = 0; i < 4; ++i) {
            int r = i * 16 + fr;
            int off = r * 32 + ((ac ^ ((r >> 1) & 3)) << 3);
            afh[i] = *(const s16x8*)&Ah[off];
            afl[i] = *(const s16x8*)&Al[off];
        }
#pragma unroll
        for (int j = 0; j < 4; ++j) {
            int n = wn * 64 + j * 16 + fr;
            int off = n * 32 + ((ac ^ ((n >> 1) & 3)) << 3);
            bfh[j] = *(const s16x8*)&Bh[off];
            bfl[j] = *(const s16x8*)&Bl[off];
        }
#pragma unroll
        for (int i = 0; i < 4; ++i)
#pragma unroll
            for (int j = 0; j < 4; ++j) {
                acc[i][j] = __builtin_amdgcn_mfma_f32_16x16x32_bf16(afh[i], bfh[j], acc[i][j], 0, 0, 0);
                acc[i][j] = __builtin_amdgcn_mfma_f32_16x16x32_bf16(afh[i], bfl[j], acc[i][j], 0, 0, 0);
                acc[i][j] = __builtin_amdgcn_mfma_f32_16x16x32_bf16(afl[i], bfh[j], acc[i][j], 0, 0, 0);
            }
        __syncthreads();
    }

    if (EPI == 1) {
        // write fp16 feat
#pragma unroll
        for (int i = 0; i < 4; ++i) {
            int rbase = row0 + i * 16 + (lane >> 4) * 4;
#pragma unroll
            for (int j = 0; j < 4; ++j) {
                int col = wn * 64 + j * 16 + (lane & 15);
#pragma unroll
                for (int q = 0; q < 4; ++q) {
                    int row = rbase + q;
                    if (row < nrows) Ch[(size_t)row * 256 + col] = (half_t)acc[i][j][q];
                }
            }
        }
        // fused el/er for head wn (wave-local, no LDS)
        float alv[4], arv[4];
#pragma unroll
        for (int j = 0; j < 4; ++j) {
            int col = wn * 64 + j * 16 + (lane & 15);
            alv[j] = al[col];
            arv[j] = ar[col];
        }
#pragma unroll
        for (int i = 0; i < 4; ++i)
#pragma unroll
            for (int q = 0; q < 4; ++q) {
                float ep = acc[i][0][q] * alv[0] + acc[i][1][q] * alv[1]
                         + acc[i][2][q] * alv[2] + acc[i][3][q] * alv[3];
                float rp_ = acc[i][0][q] * arv[0] + acc[i][1][q] * arv[1]
                          + acc[i][2][q] * arv[2] + acc[i][3][q] * arv[3];
#pragma unroll
                for (int msk = 1; msk < 16; msk <<= 1) {
                    ep += __shfl_xor(ep, msk);
                    rp_ += __shfl_xor(rp_, msk);
                }
                if ((lane & 15) == 0) {
                    int row = row0 + i * 16 + (lane >> 4) * 4 + q;
                    if (row < nrows) {
                        el[row * 4 + wn] = ep;
                        er[row * 4 + wn] = rp_;
                    }
                }
            }
    }

    if (EPI == 3) {
        __shared__ float wpart[3];
        if (t < 3) wpart[t] = 0.f;
        __syncthreads();
        if (wn == 0) {
            // semantic reduce over cols 0-63 (= W1 block)
            float b1v[4], w2v[4];
#pragma unroll
            for (int j = 0; j < 4; ++j) {
                int col = j * 16 + (lane & 15);
                b1v[j] = b1[col];
                w2v[j] = w2[col];
            }
#pragma unroll
            for (int i = 0; i < 4; ++i)
#pragma unroll
                for (int q = 0; q < 4; ++q) {
                    float ep = tanhf(acc[i][0][q] + b1v[0]) * w2v[0]
                             + tanhf(acc[i][1][q] + b1v[1]) * w2v[1]
                             + tanhf(acc[i][2][q] + b1v[2]) * w2v[2]
                             + tanhf(acc[i][3][q] + b1v[3]) * w2v[3];
#pragma unroll
                    for (int msk = 1; msk < 16; msk <<= 1) ep += __shfl_xor(ep, msk);
                    if ((lane & 15) == 0) {
                        int row = row0 + i * 16 + (lane >> 4) * 4 + q;
                        if (row < nrows) atomicAdd(&wpart[row / NN], ep);
                    }
                }
        } else if (wn == 1) {
            // P = H @ Wp (cols 64-127 -> P cols 0-63), fp32
#pragma unroll
            for (int i = 0; i < 4; ++i) {
                int rbase = row0 + i * 16 + (lane >> 4) * 4;
#pragma unroll
                for (int j = 0; j < 4; ++j) {
                    int pcol = j * 16 + (lane & 15);
#pragma unroll
                    for (int q = 0; q < 4; ++q) {
                        int row = rbase + q;
                        if (row < nrows) P[(size_t)row * 64 + pcol] = acc[i][j][q];
                    }
                }
            }
        }
        __syncthreads();
        if (t < 3) atomicAdd(&wsum[t], wpart[t]);
    }
}

// ---------------- edge-softmax aggregation (unchanged from r6) ----------------

__global__ __launch_bounds__(256) void agg_edges_kernel(const half_t* __restrict__ feat,
                                                        const float* __restrict__ el,
                                                        const float* __restrict__ er,
                                                        const int* __restrict__ row_ptr,
                                                        const int* __restrict__ ssrc,
                                                        const float* __restrict__ bias,
                                                        short* __restrict__ out_hi,
                                                        short* __restrict__ out_lo) {
    int wave = threadIdx.x >> 6;
    int lane = threadIdx.x & 63;
    int n = blockIdx.x * 2 + (wave >> 1);
    if (n >= NN) return;
    int w = wave & 1;
    int h = 2 * w + (lane >> 5);
    int elem = (lane & 31) * 2;
    int beg = row_ptr[n], end = row_ptr[n + 1];
    float ern = er[n * 4 + h];
    const h16x2* fb = (const h16x2*)feat + w * 64 + lane;
    float accA0 = 0.f, accA1 = 0.f, denA = 0.f;
    float accB0 = 0.f, accB1 = 0.f, denB = 0.f;
    int j = beg;
    for (; j + 1 < end; j += 2) {
        int sA = ssrc[j], sB = ssrc[j + 1];
        float eA = el[sA * 4 + h];
        float eB = el[sB * 4 + h];
        h16x2 fA = fb[(size_t)sA * 128];
        h16x2 fB = fb[(size_t)sB * 128];
        eA += ern; eA = eA > 0.f ? eA : 0.2f * eA; float wA = __expf(eA);
        eB += ern; eB = eB > 0.f ? eB : 0.2f * eB; float wB = __expf(eB);
        accA0 = fmaf(wA, (float)fA.x, accA0);
        accA1 = fmaf(wA, (float)fA.y, accA1); denA += wA;
        accB0 = fmaf(wB, (float)fB.x, accB0);
        accB1 = fmaf(wB, (float)fB.y, accB1); denB += wB;
    }
    if (j < end) {
        int s = ssrc[j];
        float e = el[s * 4 + h] + ern;
        e = e > 0.f ? e : 0.2f * e;
        float wgt = __expf(e);
        h16x2 f = fb[(size_t)s * 128];
        accA0 = fmaf(wgt, (float)f.x, accA0);
        accA1 = fmaf(wgt, (float)f.y, accA1); denA += wgt;
    }
    float den = fmaxf(denA + denB, 1e-9f);
    float o0 = (accA0 + accB0) / den + bias[h * 64 + elem];
    float o1 = (accA1 + accB1) / den + bias[h * 64 + elem + 1];
    o0 = o0 > 0.f ? o0 : __expf(o0) - 1.0f;
    o1 = o1 > 0.f ? o1 : __expf(o1) - 1.0f;
    size_t idx = (size_t)n * 256 + h * 64 + elem;
    short h0 = bfhi(o0), h1 = bfhi(o1);
    short l0 = bfhi(o0 - bf2f(h0)), l1 = bfhi(o1 - bf2f(h1));
    ushort2 hv; hv.x = (unsigned short)h0; hv.y = (unsigned short)h1;
    ushort2 lv; lv.x = (unsigned short)l0; lv.y = (unsigned short)l1;
    *(ushort2*)&out_hi[idx] = hv;
    *(ushort2*)&out_lo[idx] = lv;
}

// ---------------- beta + final combine ----------------

__global__ void beta_kernel(const float* __restrict__ wsum, float* __restrict__ beta) {
    if (threadIdx.x == 0 && blockIdx.x == 0) {
        float w0 = wsum[0] / (float)NN, w1 = wsum[1] / (float)NN, w2 = wsum[2] / (float)NN;
        float mx = fmaxf(w0, fmaxf(w1, w2));
        float e0 = __expf(w0 - mx), e1 = __expf(w1 - mx), e2 = __expf(w2 - mx);
        float s = e0 + e1 + e2;
        beta[0] = e0 / s; beta[1] = e1 / s; beta[2] = e2 / s;
    }
}

// out = beta0*P0 + beta1*P1 + beta2*P2 + bp   (P_m = H_m @ Wp precomputed)
__global__ __launch_bounds__(256) void combine_out_kernel(const float* __restrict__ P,
                                                          const float* __restrict__ beta,
                                                          const float* __restrict__ bp,
                                                          float* __restrict__ out) {
    int idx4 = blockIdx.x * 256 + threadIdx.x;
    if (idx4 >= NN * 64 / 4) return;
    float b0 = beta[0], b1 = beta[1], b2 = beta[2];
    float4 p0 = ((const float4*)P)[idx4];
    float4 p1 = ((const float4*)P)[idx4 + NN * 16];
    float4 p2 = ((const float4*)P)[idx4 + NN * 32];
    float4 bpv = *(const float4*)(bp + ((idx4 * 4) & 63));
    float4 o;
    o.x = b0 * p0.x + b1 * p1.x + b2 * p2.x + bpv.x;
    o.y = b0 * p0.y + b1 * p1.y + b2 * p2.y + bpv.y;
    o.z = b0 * p0.z + b1 * p1.z + b2 * p2.z + bpv.z;
    o.w = b0 * p0.w + b1 * p1.w + b2 * p2.w + bpv.w;
    ((float4*)out)[idx4] = o;
}

// ---------------- host launch ----------------

extern "C" void kernel_launch(void* const* d_in, const int* in_sizes, int n_in,
                              void* d_out, int out_size, void* d_ws, size_t ws_size,
                              hipStream_t stream) {
    const float* x        = (const float*)d_in[0];
    const float* W_gat    = (const float*)d_in[1];
    const float* attn_l   = (const float*)d_in[2];
    const float* attn_r   = (const float*)d_in[3];
    const float* bias_gat = (const float*)d_in[4];
    const float* W1       = (const float*)d_in[5];
    const float* b1       = (const float*)d_in[6];
    const float* W2       = (const float*)d_in[7];
    const float* Wp       = (const float*)d_in[8];
    const float* bp       = (const float*)d_in[9];
    const int*   src      = (const int*)d_in[10];
    const int*   dst      = (const int*)d_in[11];
    float* out = (float*)d_out;

    char* ws = (char*)d_ws;
    size_t off = 0;
    auto alloc = [&](size_t bytes) { size_t o = off; off = (off + bytes + 255) & ~(size_t)255; return o; };
    short*  Hb_hi   = (short*)(ws + alloc((size_t)MM * NN * 256 * 2));
    short*  Hb_lo   = (short*)(ws + alloc((size_t)MM * NN * 256 * 2));
    half_t* feat    = (half_t*)(ws + alloc((size_t)NN * 256 * 2));
    float*  P       = (float*)(ws + alloc((size_t)MM * NN * 64 * 4));
    float*  el      = (float*)(ws + alloc((size_t)NN * 4 * 4));
    float*  er      = (float*)(ws + alloc((size_t)NN * 4 * 4));
    int*    counts  = (int*)(ws + alloc((size_t)MM * NN * 4));
    int*    row_ptr = (int*)(ws + alloc((size_t)MM * (NN + 1) * 4));
    int*    cursor  = (int*)(ws + alloc((size_t)MM * (NN + 1) * 4));
    int*    ssrc    = (int*)(ws + alloc((size_t)MM * EE * 4));
    int*    bsum    = (int*)(ws + alloc((size_t)MM * NCHUNK * 4));
    short*  Whi     = (short*)(ws + alloc((size_t)W_TOT * 2));
    short*  Wlo     = (short*)(ws + alloc((size_t)W_TOT * 2));
    float*  wsum    = (float*)(ws + alloc(16));
    float*  beta    = (float*)(ws + alloc(16));

    init_kernel<<<dim3((MM * NN + 255) / 256), 256, 0, stream>>>(counts, wsum);
    hist_kernel<<<dim3((EE + 255) / 256, MM), 256, 0, stream>>>(dst, counts);
    scan_partial_kernel<<<dim3(NCHUNK, MM), 256, 0, stream>>>(counts, row_ptr, bsum);
    scan_top_kernel<<<dim3(1), 256, 0, stream>>>(bsum);
    scan_add_kernel<<<dim3(NCHUNK, MM), 256, 0, stream>>>(bsum, row_ptr, cursor);
    scatter_kernel<<<dim3((EE + 255) / 256, MM), 256, 0, stream>>>(src, dst, cursor, ssrc);
    splitW_kernel<<<dim3((W_TOT + 255) / 256), 256, 0, stream>>>(W_gat, W1, Wp, Whi, Wlo);

    const int rowTiles = (NN + 63) / 64;
    const int aggBlocks = (NN + 1) / 2;

    for (int l = 0; l < 2; ++l) {
        for (int i = 0; i < MM; ++i) {
            const short* wh = Whi + (size_t)(l * MM + i) * 65536;
            const short* wl = Wlo + (size_t)(l * MM + i) * 65536;
            const float* alp = attn_l + (size_t)(l * MM + i) * 256;
            const float* arp = attn_r + (size_t)(l * MM + i) * 256;
            if (l == 0)
                mfma_gemm<0, 1><<<dim3(rowTiles), 256, 0, stream>>>(
                    x + (size_t)i * NN * 256, nullptr, nullptr, wh, wl,
                    feat, nullptr, alp, arp, nullptr, nullptr, el, er, nullptr, NN);
            else
                mfma_gemm<1, 1><<<dim3(rowTiles), 256, 0, stream>>>(
                    nullptr, Hb_hi + (size_t)i * NN * 256, Hb_lo + (size_t)i * NN * 256,
                    wh, wl, feat, nullptr, alp, arp, nullptr, nullptr, el, er, nullptr, NN);
            agg_edges_kernel<<<dim3(aggBlocks), 256, 0, stream>>>(
                feat, el, er, row_ptr + (size_t)i * (NN + 1), ssrc + (size_t)i * EE,
                bias_gat + (size_t)(l * MM + i) * 256,
                Hb_hi + (size_t)i * NN * 256, Hb_lo + (size_t)i * NN * 256);
        }
    }

    // merged semantic + projection pass: z-reduce (wave0) and P = H@Wp (wave1)
    mfma_gemm<1, 3><<<dim3((MM * NN + 63) / 64), 256, 0, stream>>>(
        nullptr, Hb_hi, Hb_lo, Whi + WG_ELEMS, Wlo + WG_ELEMS,
        nullptr, P, nullptr, nullptr, b1, W2, nullptr, nullptr, wsum, MM * NN);
    beta_kernel<<<dim3(1), 64, 0, stream>>>(wsum, beta);
    combine_out_kernel<<<dim3((NN * 16 + 255) / 256), 256, 0, stream>>>(P, beta, bp, out);
}

// Round 8
// 841.095 us; speedup vs baseline: 4.2511x; 1.0722x over previous
//
#include <hip/hip_runtime.h>

#define NN 50000
#define EE 400000
#define MM 3
#define CHUNK 2048
#define NCHUNK ((NN + CHUNK - 1) / CHUNK)   // 25

typedef float f32x4 __attribute__((ext_vector_type(4)));
typedef short s16x8 __attribute__((ext_vector_type(8)));
typedef short s16x4 __attribute__((ext_vector_type(4)));
typedef _Float16 half_t;
typedef _Float16 h16x2 __attribute__((ext_vector_type(2)));

union FU { float f; unsigned u; };

__device__ inline short bfhi(float x) {
    FU c; c.f = x;
    unsigned u = c.u;
    return (short)((u + 0x7fffu + ((u >> 16) & 1u)) >> 16);
}
__device__ inline float bf2f(short h) {
    FU c; c.u = ((unsigned)(unsigned short)h) << 16;
    return c.f;
}

// ---------------- CSR build ----------------

__global__ __launch_bounds__(256) void init_kernel(int* counts, float* wsum) {
    int idx = blockIdx.x * 256 + threadIdx.x;
    if (idx < MM * NN) counts[idx] = 0;
    if (idx < MM) wsum[idx] = 0.0f;
}

__global__ __launch_bounds__(256) void hist_kernel(const int* __restrict__ dst,
                                                   int* __restrict__ counts) {
    int m = blockIdx.y;
    int e = blockIdx.x * 256 + threadIdx.x;
    if (e < EE) atomicAdd(&counts[m * NN + dst[m * EE + e]], 1);
}

__global__ __launch_bounds__(256) void scan_partial_kernel(const int* __restrict__ counts,
                                                           int* __restrict__ rp,
                                                           int* __restrict__ bsum) {
    int m = blockIdx.y, ch = blockIdx.x;
    const int* c = counts + m * NN;
    int* r = rp + m * (NN + 1);
    int t = threadIdx.x, lane = t & 63, wave = t >> 6;
    int i0 = ch * CHUNK + t * 8;
    int v[8]; int s = 0;
#pragma unroll
    for (int k = 0; k < 8; ++k) { int i = i0 + k; v[k] = (i < NN) ? c[i] : 0; s += v[k]; }
    int incl = s;
#pragma unroll
    for (int off = 1; off < 64; off <<= 1) {
        int u = __shfl_up(incl, off);
        if (lane >= off) incl += u;
    }
    int excl = incl - s;
    __shared__ int wsh[4];
    if (lane == 63) wsh[wave] = incl;
    __syncthreads();
    int woff = 0;
    for (int w = 0; w < wave; ++w) woff += wsh[w];
    int run = excl + woff;
#pragma unroll
    for (int k = 0; k < 8; ++k) { int i = i0 + k; if (i < NN) r[i] = run; run += v[k]; }
    if (t == 255) bsum[m * NCHUNK + ch] = woff + incl;
}

__global__ __launch_bounds__(256) void scan_top_kernel(int* __restrict__ bsum) {
    int wave = threadIdx.x >> 6, lane = threadIdx.x & 63;
    if (wave < MM) {
        int v = (lane < NCHUNK) ? bsum[wave * NCHUNK + lane] : 0;
        int incl = v;
#pragma unroll
        for (int off = 1; off < 64; off <<= 1) {
            int u = __shfl_up(incl, off);
            if (lane >= off) incl += u;
        }
        if (lane < NCHUNK) bsum[wave * NCHUNK + lane] = incl - v;
    }
}

__global__ __launch_bounds__(256) void scan_add_kernel(const int* __restrict__ bsum,
                                                       int* __restrict__ rp,
                                                       int* __restrict__ cur) {
    int m = blockIdx.y, ch = blockIdx.x;
    int off = bsum[m * NCHUNK + ch];
    int* r = rp + m * (NN + 1);
    int* q = cur + m * (NN + 1);
    int i0 = ch * CHUNK + threadIdx.x * 8;
#pragma unroll
    for (int k = 0; k < 8; ++k) {
        int i = i0 + k;
        if (i < NN) { int val = r[i] + off; r[i] = val; q[i] = val; }
    }
    if (ch == 0 && threadIdx.x == 0) r[NN] = EE;
}

__global__ __launch_bounds__(256) void scatter_kernel(const int* __restrict__ src,
                                                      const int* __restrict__ dst,
                                                      int* __restrict__ cursor,
                                                      int* __restrict__ ssrc) {
    int m = blockIdx.y;
    int e = blockIdx.x * 256 + threadIdx.x;
    if (e < EE) {
        int d = dst[m * EE + e];
        int pos = atomicAdd(&cursor[m * (NN + 1) + d], 1);
        ssrc[m * EE + pos] = src[m * EE + e];
    }
}

// ---------------- weight transpose + split ----------------
// Layout: [6][256n][256k] W_gat, then [128n][256k] sem weights
// (cols 0-63 = W1, 64-127 = Wp).

#define WG_ELEMS (6 * 256 * 256)
#define W_TOT (WG_ELEMS + 128 * 256)

__global__ __launch_bounds__(256) void splitW_kernel(const float* __restrict__ Wg,
                                                     const float* __restrict__ W1,
                                                     const float* __restrict__ Wp,
                                                     short* __restrict__ Whi,
                                                     short* __restrict__ Wlo) {
    int idx = blockIdx.x * 256 + threadIdx.x;
    if (idx >= W_TOT) return;
    float v;
    if (idx < WG_ELEMS) {
        int mat = idx >> 16, rem = idx & 65535;
        int n = rem >> 8, k = rem & 255;
        v = Wg[mat * 65536 + k * 256 + n];
    } else {
        int i2 = idx - WG_ELEMS;
        int n = i2 >> 8, k = i2 & 255;
        v = (n < 64) ? W1[k * 64 + n] : Wp[k * 64 + n - 64];
    }
    short h = bfhi(v);
    Whi[idx] = h;
    Wlo[idx] = bfhi(v - bf2f(h));
}

// ---------------- main MFMA GEMM: BM=64 x BN=256, fused el/er ----------------
// 256 threads = 4 waves; wave w = cols [w*64, w*64+64) = head w.
// T14 A-prefetch: k+1's A global loads issue before the MFMA cluster.
// LDS exactly 40960 B -> 4 blocks/CU.

template<int AMODE>
__global__ __launch_bounds__(256) void mfma_gemm(
    const float* __restrict__ Af,
    const short* __restrict__ Ahi, const short* __restrict__ Alo,
    const short* __restrict__ Wthi, const short* __restrict__ Wtlo,
    half_t* __restrict__ Ch,
    const float* __restrict__ al, const float* __restrict__ ar,
    float* __restrict__ el, float* __restrict__ er,
    int nrows) {
    __shared__ short Ah[64 * 32], Al[64 * 32], Bh[256 * 32], Bl[256 * 32];  // 40960 B
    const int t = threadIdx.x;
    const int lane = t & 63;
    const int wn = t >> 6;
    const int row0 = blockIdx.x * 64;
    f32x4 acc[4][4] = {};

    const int r = t >> 2, c0 = t & 3;
    const int aoff = r * 32 + ((c0 ^ ((r >> 1) & 3)) << 3);
    const int arow = row0 + r;
    const bool aval = (arow < nrows);

    s16x8 pah = {0,0,0,0,0,0,0,0}, pal = {0,0,0,0,0,0,0,0};
    float4 pf0 = make_float4(0.f,0.f,0.f,0.f), pf1 = make_float4(0.f,0.f,0.f,0.f);

    // prologue: load A(k=0) into regs
    if (AMODE == 1) {
        if (aval) {
            pah = *(const s16x8*)(Ahi + (size_t)arow * 256 + c0 * 8);
            pal = *(const s16x8*)(Alo + (size_t)arow * 256 + c0 * 8);
        }
    } else {
        if (aval) {
            pf0 = *(const float4*)(Af + (size_t)arow * 256 + c0 * 8);
            pf1 = *(const float4*)(Af + (size_t)arow * 256 + c0 * 8 + 4);
        }
    }

    for (int k0 = 0; k0 < 256; k0 += 32) {
        // ---- write prefetched A regs to LDS ----
        if (AMODE == 1) {
            *(s16x8*)&Ah[aoff] = pah;
            *(s16x8*)&Al[aoff] = pal;
        } else {
            float v[8] = {pf0.x, pf0.y, pf0.z, pf0.w, pf1.x, pf1.y, pf1.z, pf1.w};
            s16x8 hh, ll;
#pragma unroll
            for (int j = 0; j < 8; ++j) {
                short hs = bfhi(v[j]);
                hh[j] = hs;
                ll[j] = bfhi(v[j] - bf2f(hs));
            }
            *(s16x8*)&Ah[aoff] = hh;
            *(s16x8*)&Al[aoff] = ll;
        }
        // ---- stage B (256 cols x 32 k) ----
#pragma unroll
        for (int u = 0; u < 4; ++u) {
            int n = u * 64 + (t >> 2), c = t & 3;
            s16x8 h = *(const s16x8*)(Wthi + (size_t)n * 256 + k0 + c * 8);
            s16x8 l = *(const s16x8*)(Wtlo + (size_t)n * 256 + k0 + c * 8);
            int off = n * 32 + ((c ^ ((n >> 1) & 3)) << 3);
            *(s16x8*)&Bh[off] = h;
            *(s16x8*)&Bl[off] = l;
        }
        __syncthreads();
        // ---- prefetch A for k0+32 (vmcnt-wait lands at next iter's ds_write) ----
        if (k0 + 32 < 256) {
            if (AMODE == 1) {
                pah = s16x8{0,0,0,0,0,0,0,0}; pal = s16x8{0,0,0,0,0,0,0,0};
                if (aval) {
                    pah = *(const s16x8*)(Ahi + (size_t)arow * 256 + k0 + 32 + c0 * 8);
                    pal = *(const s16x8*)(Alo + (size_t)arow * 256 + k0 + 32 + c0 * 8);
                }
            } else {
                pf0 = make_float4(0.f,0.f,0.f,0.f); pf1 = make_float4(0.f,0.f,0.f,0.f);
                if (aval) {
                    pf0 = *(const float4*)(Af + (size_t)arow * 256 + k0 + 32 + c0 * 8);
                    pf1 = *(const float4*)(Af + (size_t)arow * 256 + k0 + 32 + c0 * 8 + 4);
                }
            }
        }
        // ---- MFMA ----
        int fr = lane & 15, ac = lane >> 4;
        s16x8 afh[4], afl[4], bfh[4], bfl[4];
#pragma unroll
        for (int i = 0; i < 4; ++i) {
            int rr = i * 16 + fr;
            int off = rr * 32 + ((ac ^ ((rr >> 1) & 3)) << 3);
            afh[i] = *(const s16x8*)&Ah[off];
            afl[i] = *(const s16x8*)&Al[off];
        }
#pragma unroll
        for (int j = 0; j < 4; ++j) {
            int n = wn * 64 + j * 16 + fr;
            int off = n * 32 + ((ac ^ ((n >> 1) & 3)) << 3);
            bfh[j] = *(const s16x8*)&Bh[off];
            bfl[j] = *(const s16x8*)&Bl[off];
        }
#pragma unroll
        for (int i = 0; i < 4; ++i)
#pragma unroll
            for (int j = 0; j < 4; ++j) {
                acc[i][j] = __builtin_amdgcn_mfma_f32_16x16x32_bf16(afh[i], bfh[j], acc[i][j], 0, 0, 0);
                acc[i][j] = __builtin_amdgcn_mfma_f32_16x16x32_bf16(afh[i], bfl[j], acc[i][j], 0, 0, 0);
                acc[i][j] = __builtin_amdgcn_mfma_f32_16x16x32_bf16(afl[i], bfh[j], acc[i][j], 0, 0, 0);
            }
        __syncthreads();
    }

    // ---- write fp16 feat ----
#pragma unroll
    for (int i = 0; i < 4; ++i) {
        int rbase = row0 + i * 16 + (lane >> 4) * 4;
#pragma unroll
        for (int j = 0; j < 4; ++j) {
            int col = wn * 64 + j * 16 + (lane & 15);
#pragma unroll
            for (int q = 0; q < 4; ++q) {
                int row = rbase + q;
                if (row < nrows) Ch[(size_t)row * 256 + col] = (half_t)acc[i][j][q];
            }
        }
    }
    // ---- fused el/er for head wn (wave-local) ----
    float alv[4], arv[4];
#pragma unroll
    for (int j = 0; j < 4; ++j) {
        int col = wn * 64 + j * 16 + (lane & 15);
        alv[j] = al[col];
        arv[j] = ar[col];
    }
#pragma unroll
    for (int i = 0; i < 4; ++i)
#pragma unroll
        for (int q = 0; q < 4; ++q) {
            float ep = acc[i][0][q] * alv[0] + acc[i][1][q] * alv[1]
                     + acc[i][2][q] * alv[2] + acc[i][3][q] * alv[3];
            float rp_ = acc[i][0][q] * arv[0] + acc[i][1][q] * arv[1]
                      + acc[i][2][q] * arv[2] + acc[i][3][q] * arv[3];
#pragma unroll
            for (int msk = 1; msk < 16; msk <<= 1) {
                ep += __shfl_xor(ep, msk);
                rp_ += __shfl_xor(rp_, msk);
            }
            if ((lane & 15) == 0) {
                int row = row0 + i * 16 + (lane >> 4) * 4 + q;
                if (row < nrows) {
                    el[row * 4 + wn] = ep;
                    er[row * 4 + wn] = rp_;
                }
            }
        }
}

// ---------------- semantic GEMM: BM=128 x BN=128 (cols: 64 W1 | 64 Wp) ------
// 4 waves 2x2: wn=0 -> fused tanh-dot-W2 reduce, wn=1 -> write fp32 P.
// LDS 32 KB -> 5 blocks/CU; wpart reuses dead A-tile LDS.

__global__ __launch_bounds__(256) void sem_gemm(
    const short* __restrict__ Ahi, const short* __restrict__ Alo,
    const short* __restrict__ Wthi, const short* __restrict__ Wtlo,
    float* __restrict__ P,
    const float* __restrict__ b1, const float* __restrict__ w2,
    float* __restrict__ wsum,
    int nrows) {
    __shared__ short Ah[128 * 32], Al[128 * 32], Bh[128 * 32], Bl[128 * 32]; // 32 KB
    const int t = threadIdx.x;
    const int lane = t & 63;
    const int wave = t >> 6;
    const int wm = wave >> 1, wn = wave & 1;
    const int row0 = blockIdx.x * 128;
    f32x4 acc[4][4] = {};

    const int r0 = (t * 2) >> 2, c0 = (t * 2) & 3;      // unit 0
    const int r1 = (t * 2 + 1) >> 2, c1 = (t * 2 + 1) & 3;
    const int aoff0 = r0 * 32 + ((c0 ^ ((r0 >> 1) & 3)) << 3);
    const int aoff1 = r1 * 32 + ((c1 ^ ((r1 >> 1) & 3)) << 3);
    const int arow0 = row0 + r0, arow1 = row0 + r1;

    s16x8 pah0 = {0,0,0,0,0,0,0,0}, pal0 = {0,0,0,0,0,0,0,0};
    s16x8 pah1 = {0,0,0,0,0,0,0,0}, pal1 = {0,0,0,0,0,0,0,0};
    if (arow0 < nrows) {
        pah0 = *(const s16x8*)(Ahi + (size_t)arow0 * 256 + c0 * 8);
        pal0 = *(const s16x8*)(Alo + (size_t)arow0 * 256 + c0 * 8);
    }
    if (arow1 < nrows) {
        pah1 = *(const s16x8*)(Ahi + (size_t)arow1 * 256 + c1 * 8);
        pal1 = *(const s16x8*)(Alo + (size_t)arow1 * 256 + c1 * 8);
    }

    for (int k0 = 0; k0 < 256; k0 += 32) {
        *(s16x8*)&Ah[aoff0] = pah0;
        *(s16x8*)&Al[aoff0] = pal0;
        *(s16x8*)&Ah[aoff1] = pah1;
        *(s16x8*)&Al[aoff1] = pal1;
        // stage B: 128 rows x 4 chunks = 512 units, 2/thread
#pragma unroll
        for (int u = 0; u < 2; ++u) {
            int idx = t * 2 + u;
            int n = idx >> 2, c = idx & 3;
            s16x8 h = *(const s16x8*)(Wthi + (size_t)n * 256 + k0 + c * 8);
            s16x8 l = *(const s16x8*)(Wtlo + (size_t)n * 256 + k0 + c * 8);
            int off = n * 32 + ((c ^ ((n >> 1) & 3)) << 3);
            *(s16x8*)&Bh[off] = h;
            *(s16x8*)&Bl[off] = l;
        }
        __syncthreads();
        if (k0 + 32 < 256) {
            pah0 = s16x8{0,0,0,0,0,0,0,0}; pal0 = s16x8{0,0,0,0,0,0,0,0};
            pah1 = s16x8{0,0,0,0,0,0,0,0}; pal1 = s16x8{0,0,0,0,0,0,0,0};
            if (arow0 < nrows) {
                pah0 = *(const s16x8*)(Ahi + (size_t)arow0 * 256 + k0 + 32 + c0 * 8);
                pal0 = *(const s16x8*)(Alo + (size_t)arow0 * 256 + k0 + 32 + c0 * 8);
            }
            if (arow1 < nrows) {
                pah1 = *(const s16x8*)(Ahi + (size_t)arow1 * 256 + k0 + 32 + c1 * 8);
                pal1 = *(const s16x8*)(Alo + (size_t)arow1 * 256 + k0 + 32 + c1 * 8);
            }
        }
        int fr = lane & 15, ac = lane >> 4;
        s16x8 afh[4], afl[4], bfh[4], bfl[4];
#pragma unroll
        for (int i = 0; i < 4; ++i) {
            int rr = wm * 64 + i * 16 + fr;
            int off = rr * 32 + ((ac ^ ((rr >> 1) & 3)) << 3);
            afh[i] = *(const s16x8*)&Ah[off];
            afl[i] = *(const s16x8*)&Al[off];
        }
#pragma unroll
        for (int j = 0; j < 4; ++j) {
            int n = wn * 64 + j * 16 + fr;
            int off = n * 32 + ((ac ^ ((n >> 1) & 3)) << 3);
            bfh[j] = *(const s16x8*)&Bh[off];
            bfl[j] = *(const s16x8*)&Bl[off];
        }
#pragma unroll
        for (int i = 0; i < 4; ++i)
#pragma unroll
            for (int j = 0; j < 4; ++j) {
                acc[i][j] = __builtin_amdgcn_mfma_f32_16x16x32_bf16(afh[i], bfh[j], acc[i][j], 0, 0, 0);
                acc[i][j] = __builtin_amdgcn_mfma_f32_16x16x32_bf16(afh[i], bfl[j], acc[i][j], 0, 0, 0);
                acc[i][j] = __builtin_amdgcn_mfma_f32_16x16x32_bf16(afl[i], bfh[j], acc[i][j], 0, 0, 0);
            }
        __syncthreads();
    }

    // wpart reuses dead A-tile LDS (k-loop ended with a barrier)
    float* wp = (float*)&Ah[0];
    if (t < 3) wp[t] = 0.f;
    __syncthreads();
    int fr = lane & 15, ac = lane >> 4;
    if (wn == 0) {
        float b1v[4], w2v[4];
#pragma unroll
        for (int j = 0; j < 4; ++j) {
            int col = j * 16 + fr;
            b1v[j] = b1[col];
            w2v[j] = w2[col];
        }
#pragma unroll
        for (int i = 0; i < 4; ++i)
#pragma unroll
            for (int q = 0; q < 4; ++q) {
                float ep = tanhf(acc[i][0][q] + b1v[0]) * w2v[0]
                         + tanhf(acc[i][1][q] + b1v[1]) * w2v[1]
                         + tanhf(acc[i][2][q] + b1v[2]) * w2v[2]
                         + tanhf(acc[i][3][q] + b1v[3]) * w2v[3];
#pragma unroll
                for (int msk = 1; msk < 16; msk <<= 1) ep += __shfl_xor(ep, msk);
                if (fr == 0) {
                    int row = row0 + wm * 64 + i * 16 + ac * 4 + q;
                    if (row < nrows) atomicAdd(&wp[row / NN], ep);
                }
            }
    } else {
#pragma unroll
        for (int i = 0; i < 4; ++i) {
            int rbase = row0 + wm * 64 + i * 16 + ac * 4;
#pragma unroll
            for (int j = 0; j < 4; ++j) {
                int pcol = j * 16 + fr;
#pragma unroll
                for (int q = 0; q < 4; ++q) {
                    int row = rbase + q;
                    if (row < nrows) P[(size_t)row * 64 + pcol] = acc[i][j][q];
                }
            }
        }
    }
    __syncthreads();
    if (t < 3) atomicAdd(&wsum[t], wp[t]);
}

// ---------------- edge-softmax aggregation ----------------

__global__ __launch_bounds__(256) void agg_edges_kernel(const half_t* __restrict__ feat,
                                                        const float* __restrict__ el,
                                                        const float* __restrict__ er,
                                                        const int* __restrict__ row_ptr,
                                                        const int* __restrict__ ssrc,
                                                        const float* __restrict__ bias,
                                                        short* __restrict__ out_hi,
                                                        short* __restrict__ out_lo) {
    int wave = threadIdx.x >> 6;
    int lane = threadIdx.x & 63;
    int n = blockIdx.x * 2 + (wave >> 1);
    if (n >= NN) return;
    int w = wave & 1;
    int h = 2 * w + (lane >> 5);
    int elem = (lane & 31) * 2;
    int beg = row_ptr[n], end = row_ptr[n + 1];
    float ern = er[n * 4 + h];
    const h16x2* fb = (const h16x2*)feat + w * 64 + lane;
    float accA0 = 0.f, accA1 = 0.f, denA = 0.f;
    float accB0 = 0.f, accB1 = 0.f, denB = 0.f;
    int j = beg;
    for (; j + 1 < end; j += 2) {
        int sA = ssrc[j], sB = ssrc[j + 1];
        float eA = el[sA * 4 + h];
        float eB = el[sB * 4 + h];
        h16x2 fA = fb[(size_t)sA * 128];
        h16x2 fB = fb[(size_t)sB * 128];
        eA += ern; eA = eA > 0.f ? eA : 0.2f * eA; float wA = __expf(eA);
        eB += ern; eB = eB > 0.f ? eB : 0.2f * eB; float wB = __expf(eB);
        accA0 = fmaf(wA, (float)fA.x, accA0);
        accA1 = fmaf(wA, (float)fA.y, accA1); denA += wA;
        accB0 = fmaf(wB, (float)fB.x, accB0);
        accB1 = fmaf(wB, (float)fB.y, accB1); denB += wB;
    }
    if (j < end) {
        int s = ssrc[j];
        float e = el[s * 4 + h] + ern;
        e = e > 0.f ? e : 0.2f * e;
        float wgt = __expf(e);
        h16x2 f = fb[(size_t)s * 128];
        accA0 = fmaf(wgt, (float)f.x, accA0);
        accA1 = fmaf(wgt, (float)f.y, accA1); denA += wgt;
    }
    float den = fmaxf(denA + denB, 1e-9f);
    float o0 = (accA0 + accB0) / den + bias[h * 64 + elem];
    float o1 = (accA1 + accB1) / den + bias[h * 64 + elem + 1];
    o0 = o0 > 0.f ? o0 : __expf(o0) - 1.0f;
    o1 = o1 > 0.f ? o1 : __expf(o1) - 1.0f;
    size_t idx = (size_t)n * 256 + h * 64 + elem;
    short h0 = bfhi(o0), h1 = bfhi(o1);
    short l0 = bfhi(o0 - bf2f(h0)), l1 = bfhi(o1 - bf2f(h1));
    ushort2 hv; hv.x = (unsigned short)h0; hv.y = (unsigned short)h1;
    ushort2 lv; lv.x = (unsigned short)l0; lv.y = (unsigned short)l1;
    *(ushort2*)&out_hi[idx] = hv;
    *(ushort2*)&out_lo[idx] = lv;
}

// ---------------- beta + final combine ----------------

__global__ void beta_kernel(const float* __restrict__ wsum, float* __restrict__ beta) {
    if (threadIdx.x == 0 && blockIdx.x == 0) {
        float w0 = wsum[0] / (float)NN, w1 = wsum[1] / (float)NN, w2 = wsum[2] / (float)NN;
        float mx = fmaxf(w0, fmaxf(w1, w2));
        float e0 = __expf(w0 - mx), e1 = __expf(w1 - mx), e2 = __expf(w2 - mx);
        float s = e0 + e1 + e2;
        beta[0] = e0 / s; beta[1] = e1 / s; beta[2] = e2 / s;
    }
}

__global__ __launch_bounds__(256) void combine_out_kernel(const float* __restrict__ P,
                                                          const float* __restrict__ beta,
                                                          const float* __restrict__ bp,
                                                          float* __restrict__ out) {
    int idx4 = blockIdx.x * 256 + threadIdx.x;
    if (idx4 >= NN * 64 / 4) return;
    float b0 = beta[0], b1 = beta[1], b2 = beta[2];
    float4 p0 = ((const float4*)P)[idx4];
    float4 p1 = ((const float4*)P)[idx4 + NN * 16];
    float4 p2 = ((const float4*)P)[idx4 + NN * 32];
    float4 bpv = *(const float4*)(bp + ((idx4 * 4) & 63));
    float4 o;
    o.x = b0 * p0.x + b1 * p1.x + b2 * p2.x + bpv.x;
    o.y = b0 * p0.y + b1 * p1.y + b2 * p2.y + bpv.y;
    o.z = b0 * p0.z + b1 * p1.z + b2 * p2.z + bpv.z;
    o.w = b0 * p0.w + b1 * p1.w + b2 * p2.w + bpv.w;
    ((float4*)out)[idx4] = o;
}

// ---------------- host launch ----------------

extern "C" void kernel_launch(void* const* d_in, const int* in_sizes, int n_in,
                              void* d_out, int out_size, void* d_ws, size_t ws_size,
                              hipStream_t stream) {
    const float* x        = (const float*)d_in[0];
    const float* W_gat    = (const float*)d_in[1];
    const float* attn_l   = (const float*)d_in[2];
    const float* attn_r   = (const float*)d_in[3];
    const float* bias_gat = (const float*)d_in[4];
    const float* W1       = (const float*)d_in[5];
    const float* b1       = (const float*)d_in[6];
    const float* W2       = (const float*)d_in[7];
    const float* Wp       = (const float*)d_in[8];
    const float* bp       = (const float*)d_in[9];
    const int*   src      = (const int*)d_in[10];
    const int*   dst      = (const int*)d_in[11];
    float* out = (float*)d_out;

    char* ws = (char*)d_ws;
    size_t off = 0;
    auto alloc = [&](size_t bytes) { size_t o = off; off = (off + bytes + 255) & ~(size_t)255; return o; };
    short*  Hb_hi   = (short*)(ws + alloc((size_t)MM * NN * 256 * 2));
    short*  Hb_lo   = (short*)(ws + alloc((size_t)MM * NN * 256 * 2));
    half_t* feat    = (half_t*)(ws + alloc((size_t)NN * 256 * 2));
    float*  P       = (float*)(ws + alloc((size_t)MM * NN * 64 * 4));
    float*  el      = (float*)(ws + alloc((size_t)NN * 4 * 4));
    float*  er      = (float*)(ws + alloc((size_t)NN * 4 * 4));
    int*    counts  = (int*)(ws + alloc((size_t)MM * NN * 4));
    int*    row_ptr = (int*)(ws + alloc((size_t)MM * (NN + 1) * 4));
    int*    cursor  = (int*)(ws + alloc((size_t)MM * (NN + 1) * 4));
    int*    ssrc    = (int*)(ws + alloc((size_t)MM * EE * 4));
    int*    bsum    = (int*)(ws + alloc((size_t)MM * NCHUNK * 4));
    short*  Whi     = (short*)(ws + alloc((size_t)W_TOT * 2));
    short*  Wlo     = (short*)(ws + alloc((size_t)W_TOT * 2));
    float*  wsum    = (float*)(ws + alloc(16));
    float*  beta    = (float*)(ws + alloc(16));

    init_kernel<<<dim3((MM * NN + 255) / 256), 256, 0, stream>>>(counts, wsum);
    hist_kernel<<<dim3((EE + 255) / 256, MM), 256, 0, stream>>>(dst, counts);
    scan_partial_kernel<<<dim3(NCHUNK, MM), 256, 0, stream>>>(counts, row_ptr, bsum);
    scan_top_kernel<<<dim3(1), 256, 0, stream>>>(bsum);
    scan_add_kernel<<<dim3(NCHUNK, MM), 256, 0, stream>>>(bsum, row_ptr, cursor);
    scatter_kernel<<<dim3((EE + 255) / 256, MM), 256, 0, stream>>>(src, dst, cursor, ssrc);
    splitW_kernel<<<dim3((W_TOT + 255) / 256), 256, 0, stream>>>(W_gat, W1, Wp, Whi, Wlo);

    const int rowTiles = (NN + 63) / 64;
    const int aggBlocks = (NN + 1) / 2;

    for (int l = 0; l < 2; ++l) {
        for (int i = 0; i < MM; ++i) {
            const short* wh = Whi + (size_t)(l * MM + i) * 65536;
            const short* wl = Wlo + (size_t)(l * MM + i) * 65536;
            const float* alp = attn_l + (size_t)(l * MM + i) * 256;
            const float* arp = attn_r + (size_t)(l * MM + i) * 256;
            if (l == 0)
                mfma_gemm<0><<<dim3(rowTiles), 256, 0, stream>>>(
                    x + (size_t)i * NN * 256, nullptr, nullptr, wh, wl,
                    feat, alp, arp, el, er, NN);
            else
                mfma_gemm<1><<<dim3(rowTiles), 256, 0, stream>>>(
                    nullptr, Hb_hi + (size_t)i * NN * 256, Hb_lo + (size_t)i * NN * 256,
                    wh, wl, feat, alp, arp, el, er, NN);
            agg_edges_kernel<<<dim3(aggBlocks), 256, 0, stream>>>(
                feat, el, er, row_ptr + (size_t)i * (NN + 1), ssrc + (size_t)i * EE,
                bias_gat + (size_t)(l * MM + i) * 256,
                Hb_hi + (size_t)i * NN * 256, Hb_lo + (size_t)i * NN * 256);
        }
    }

    // merged semantic + projection pass
    sem_gemm<<<dim3((MM * NN + 127) / 128), 256, 0, stream>>>(
        Hb_hi, Hb_lo, Whi + WG_ELEMS, Wlo + WG_ELEMS,
        P, b1, W2, wsum, MM * NN);
    beta_kernel<<<dim3(1), 64, 0, stream>>>(wsum, beta);
    combine_out_kernel<<<dim3((NN * 16 + 255) / 256), 256, 0, stream>>>(P, beta, bp, out);
}

// Round 9
// 795.993 us; speedup vs baseline: 4.4920x; 1.0567x over previous
//
#include <hip/hip_runtime.h>

#define NN 50000
#define EE 400000
#define MM 3
#define CHUNK 2048
#define NCHUNK ((NN + CHUNK - 1) / CHUNK)   // 25

typedef float f32x4 __attribute__((ext_vector_type(4)));
typedef short s16x8 __attribute__((ext_vector_type(8)));
typedef _Float16 half_t;
typedef _Float16 h16x2 __attribute__((ext_vector_type(2)));

union FU { float f; unsigned u; };

__device__ inline short bfhi(float x) {
    FU c; c.f = x;
    unsigned u = c.u;
    return (short)((u + 0x7fffu + ((u >> 16) & 1u)) >> 16);
}
__device__ inline float bf2f(short h) {
    FU c; c.u = ((unsigned)(unsigned short)h) << 16;
    return c.f;
}
__device__ inline float h2f(short bits) {
    union HU { short s; _Float16 h; } u; u.s = bits; return (float)u.h;
}

// ---------------- CSR build ----------------

__global__ __launch_bounds__(256) void init_kernel(int* counts, float* wsum) {
    int idx = blockIdx.x * 256 + threadIdx.x;
    if (idx < MM * NN) counts[idx] = 0;
    if (idx < MM) wsum[idx] = 0.0f;
}

__global__ __launch_bounds__(256) void hist_kernel(const int* __restrict__ dst,
                                                   int* __restrict__ counts) {
    int m = blockIdx.y;
    int e = blockIdx.x * 256 + threadIdx.x;
    if (e < EE) atomicAdd(&counts[m * NN + dst[m * EE + e]], 1);
}

__global__ __launch_bounds__(256) void scan_partial_kernel(const int* __restrict__ counts,
                                                           int* __restrict__ rp,
                                                           int* __restrict__ bsum) {
    int m = blockIdx.y, ch = blockIdx.x;
    const int* c = counts + m * NN;
    int* r = rp + m * (NN + 1);
    int t = threadIdx.x, lane = t & 63, wave = t >> 6;
    int i0 = ch * CHUNK + t * 8;
    int v[8]; int s = 0;
#pragma unroll
    for (int k = 0; k < 8; ++k) { int i = i0 + k; v[k] = (i < NN) ? c[i] : 0; s += v[k]; }
    int incl = s;
#pragma unroll
    for (int off = 1; off < 64; off <<= 1) {
        int u = __shfl_up(incl, off);
        if (lane >= off) incl += u;
    }
    int excl = incl - s;
    __shared__ int wsh[4];
    if (lane == 63) wsh[wave] = incl;
    __syncthreads();
    int woff = 0;
    for (int w = 0; w < wave; ++w) woff += wsh[w];
    int run = excl + woff;
#pragma unroll
    for (int k = 0; k < 8; ++k) { int i = i0 + k; if (i < NN) r[i] = run; run += v[k]; }
    if (t == 255) bsum[m * NCHUNK + ch] = woff + incl;
}

__global__ __launch_bounds__(256) void scan_top_kernel(int* __restrict__ bsum) {
    int wave = threadIdx.x >> 6, lane = threadIdx.x & 63;
    if (wave < MM) {
        int v = (lane < NCHUNK) ? bsum[wave * NCHUNK + lane] : 0;
        int incl = v;
#pragma unroll
        for (int off = 1; off < 64; off <<= 1) {
            int u = __shfl_up(incl, off);
            if (lane >= off) incl += u;
        }
        if (lane < NCHUNK) bsum[wave * NCHUNK + lane] = incl - v;
    }
}

__global__ __launch_bounds__(256) void scan_add_kernel(const int* __restrict__ bsum,
                                                       int* __restrict__ rp,
                                                       int* __restrict__ cur) {
    int m = blockIdx.y, ch = blockIdx.x;
    int off = bsum[m * NCHUNK + ch];
    int* r = rp + m * (NN + 1);
    int* q = cur + m * (NN + 1);
    int i0 = ch * CHUNK + threadIdx.x * 8;
#pragma unroll
    for (int k = 0; k < 8; ++k) {
        int i = i0 + k;
        if (i < NN) { int val = r[i] + off; r[i] = val; q[i] = val; }
    }
    if (ch == 0 && threadIdx.x == 0) r[NN] = EE;
}

__global__ __launch_bounds__(256) void scatter_kernel(const int* __restrict__ src,
                                                      const int* __restrict__ dst,
                                                      int* __restrict__ cursor,
                                                      int* __restrict__ ssrc) {
    int m = blockIdx.y;
    int e = blockIdx.x * 256 + threadIdx.x;
    if (e < EE) {
        int d = dst[m * EE + e];
        int pos = atomicAdd(&cursor[m * (NN + 1) + d], 1);
        __builtin_nontemporal_store(src[m * EE + e], &ssrc[m * EE + pos]);
    }
}

// ---------------- weight transpose + split ----------------
// Layout: [6][256n][256k] W_gat, then [128n][256k] sem weights (64 W1 | 64 Wp).

#define WG_ELEMS (6 * 256 * 256)
#define W_TOT (WG_ELEMS + 128 * 256)

__global__ __launch_bounds__(256) void splitW_kernel(const float* __restrict__ Wg,
                                                     const float* __restrict__ W1,
                                                     const float* __restrict__ Wp,
                                                     short* __restrict__ Whi,
                                                     short* __restrict__ Wlo) {
    int idx = blockIdx.x * 256 + threadIdx.x;
    if (idx >= W_TOT) return;
    float v;
    if (idx < WG_ELEMS) {
        int mat = idx >> 16, rem = idx & 65535;
        int n = rem >> 8, k = rem & 255;
        v = Wg[mat * 65536 + k * 256 + n];
    } else {
        int i2 = idx - WG_ELEMS;
        int n = i2 >> 8, k = i2 & 255;
        v = (n < 64) ? W1[k * 64 + n] : Wp[k * 64 + n - 64];
    }
    short h = bfhi(v);
    Whi[idx] = h;
    Wlo[idx] = bfhi(v - bf2f(h));
}

// ---------------- main MFMA GEMM: BM=64 x BN=256, metapath-merged ----------
// grid (rowTiles, MM); wave w = head w's 64 cols. AMODE 0: A fp32 (x);
// AMODE 1: A fp16 (Hb) — fp16 splits LOSSLESSLY into bf16 hi+lo.
// T14 A-prefetch; LDS 40960 B -> 4 blocks/CU. Fused el/er epilogue.

template<int AMODE>
__global__ __launch_bounds__(256) void mfma_gemm(
    const float* __restrict__ Af, const half_t* __restrict__ A16,
    const short* __restrict__ Wthi, const short* __restrict__ Wtlo,
    half_t* __restrict__ featA,
    const float* __restrict__ alA, const float* __restrict__ arA,
    float* __restrict__ elA, float* __restrict__ erA) {
    __shared__ short Ah[64 * 32], Al[64 * 32], Bh[256 * 32], Bl[256 * 32];  // 40960 B
    const int m = blockIdx.y;
    const int t = threadIdx.x;
    const int lane = t & 63;
    const int wn = t >> 6;
    const int row0 = blockIdx.x * 64;
    const float*  A0 = Af + (size_t)m * NN * 256;
    const short*  A1 = (const short*)(A16 + (size_t)m * NN * 256);
    const short*  Bgh = Wthi + (size_t)m * 65536;
    const short*  Bgl = Wtlo + (size_t)m * 65536;
    half_t* Ch = featA + (size_t)m * NN * 256;
    const float* al = alA + m * 256;
    const float* ar = arA + m * 256;
    float* el = elA + (size_t)m * NN * 4;
    float* er = erA + (size_t)m * NN * 4;
    f32x4 acc[4][4] = {};

    const int r = t >> 2, c0 = t & 3;
    const int aoff = r * 32 + ((c0 ^ ((r >> 1) & 3)) << 3);
    const int arow = row0 + r;
    const bool aval = (arow < NN);

    s16x8 praw = {0,0,0,0,0,0,0,0};
    float4 pf0 = make_float4(0.f,0.f,0.f,0.f), pf1 = make_float4(0.f,0.f,0.f,0.f);

    if (AMODE == 1) {
        if (aval) praw = *(const s16x8*)(A1 + (size_t)arow * 256 + c0 * 8);
    } else {
        if (aval) {
            pf0 = *(const float4*)(A0 + (size_t)arow * 256 + c0 * 8);
            pf1 = *(const float4*)(A0 + (size_t)arow * 256 + c0 * 8 + 4);
        }
    }

    for (int k0 = 0; k0 < 256; k0 += 32) {
        // ---- split prefetched A into bf16 hi/lo, write LDS ----
        {
            float v[8];
            if (AMODE == 1) {
#pragma unroll
                for (int j = 0; j < 8; ++j) v[j] = h2f(praw[j]);
            } else {
                v[0] = pf0.x; v[1] = pf0.y; v[2] = pf0.z; v[3] = pf0.w;
                v[4] = pf1.x; v[5] = pf1.y; v[6] = pf1.z; v[7] = pf1.w;
            }
            s16x8 hh, ll;
#pragma unroll
            for (int j = 0; j < 8; ++j) {
                short hs = bfhi(v[j]);
                hh[j] = hs;
                ll[j] = bfhi(v[j] - bf2f(hs));
            }
            *(s16x8*)&Ah[aoff] = hh;
            *(s16x8*)&Al[aoff] = ll;
        }
        // ---- stage B (256 cols x 32 k) ----
#pragma unroll
        for (int u = 0; u < 4; ++u) {
            int n = u * 64 + (t >> 2), c = t & 3;
            s16x8 h = *(const s16x8*)(Bgh + (size_t)n * 256 + k0 + c * 8);
            s16x8 l = *(const s16x8*)(Bgl + (size_t)n * 256 + k0 + c * 8);
            int off = n * 32 + ((c ^ ((n >> 1) & 3)) << 3);
            *(s16x8*)&Bh[off] = h;
            *(s16x8*)&Bl[off] = l;
        }
        __syncthreads();
        // ---- prefetch A for k0+32 ----
        if (k0 + 32 < 256) {
            if (AMODE == 1) {
                praw = s16x8{0,0,0,0,0,0,0,0};
                if (aval) praw = *(const s16x8*)(A1 + (size_t)arow * 256 + k0 + 32 + c0 * 8);
            } else {
                pf0 = make_float4(0.f,0.f,0.f,0.f); pf1 = make_float4(0.f,0.f,0.f,0.f);
                if (aval) {
                    pf0 = *(const float4*)(A0 + (size_t)arow * 256 + k0 + 32 + c0 * 8);
                    pf1 = *(const float4*)(A0 + (size_t)arow * 256 + k0 + 32 + c0 * 8 + 4);
                }
            }
        }
        // ---- MFMA ----
        int fr = lane & 15, ac = lane >> 4;
        s16x8 afh[4], afl[4], bfh[4], bfl[4];
#pragma unroll
        for (int i = 0; i < 4; ++i) {
            int rr = i * 16 + fr;
            int off = rr * 32 + ((ac ^ ((rr >> 1) & 3)) << 3);
            afh[i] = *(const s16x8*)&Ah[off];
            afl[i] = *(const s16x8*)&Al[off];
        }
#pragma unroll
        for (int j = 0; j < 4; ++j) {
            int n = wn * 64 + j * 16 + fr;
            int off = n * 32 + ((ac ^ ((n >> 1) & 3)) << 3);
            bfh[j] = *(const s16x8*)&Bh[off];
            bfl[j] = *(const s16x8*)&Bl[off];
        }
#pragma unroll
        for (int i = 0; i < 4; ++i)
#pragma unroll
            for (int j = 0; j < 4; ++j) {
                acc[i][j] = __builtin_amdgcn_mfma_f32_16x16x32_bf16(afh[i], bfh[j], acc[i][j], 0, 0, 0);
                acc[i][j] = __builtin_amdgcn_mfma_f32_16x16x32_bf16(afh[i], bfl[j], acc[i][j], 0, 0, 0);
                acc[i][j] = __builtin_amdgcn_mfma_f32_16x16x32_bf16(afl[i], bfh[j], acc[i][j], 0, 0, 0);
            }
        __syncthreads();
    }

    // ---- write fp16 feat ----
#pragma unroll
    for (int i = 0; i < 4; ++i) {
        int rbase = row0 + i * 16 + (lane >> 4) * 4;
#pragma unroll
        for (int j = 0; j < 4; ++j) {
            int col = wn * 64 + j * 16 + (lane & 15);
#pragma unroll
            for (int q = 0; q < 4; ++q) {
                int row = rbase + q;
                if (row < NN) Ch[(size_t)row * 256 + col] = (half_t)acc[i][j][q];
            }
        }
    }
    // ---- fused el/er for head wn ----
    float alv[4], arv[4];
#pragma unroll
    for (int j = 0; j < 4; ++j) {
        int col = wn * 64 + j * 16 + (lane & 15);
        alv[j] = al[col];
        arv[j] = ar[col];
    }
#pragma unroll
    for (int i = 0; i < 4; ++i)
#pragma unroll
        for (int q = 0; q < 4; ++q) {
            float ep = acc[i][0][q] * alv[0] + acc[i][1][q] * alv[1]
                     + acc[i][2][q] * alv[2] + acc[i][3][q] * alv[3];
            float rp_ = acc[i][0][q] * arv[0] + acc[i][1][q] * arv[1]
                      + acc[i][2][q] * arv[2] + acc[i][3][q] * arv[3];
#pragma unroll
            for (int msk = 1; msk < 16; msk <<= 1) {
                ep += __shfl_xor(ep, msk);
                rp_ += __shfl_xor(rp_, msk);
            }
            if ((lane & 15) == 0) {
                int row = row0 + i * 16 + (lane >> 4) * 4 + q;
                if (row < NN) {
                    el[row * 4 + wn] = ep;
                    er[row * 4 + wn] = rp_;
                }
            }
        }
}

// ---------------- semantic GEMM: BM=128 x BN=128, fp16 A ----------------

__global__ __launch_bounds__(256) void sem_gemm(
    const half_t* __restrict__ A16,
    const short* __restrict__ Wthi, const short* __restrict__ Wtlo,
    float* __restrict__ P,
    const float* __restrict__ b1, const float* __restrict__ w2,
    float* __restrict__ wsum,
    int nrows) {
    __shared__ short Ah[128 * 32], Al[128 * 32], Bh[128 * 32], Bl[128 * 32]; // 32 KB
    const int t = threadIdx.x;
    const int lane = t & 63;
    const int wave = t >> 6;
    const int wm = wave >> 1, wn = wave & 1;
    const int row0 = blockIdx.x * 128;
    const short* A1 = (const short*)A16;
    f32x4 acc[4][4] = {};

    const int r0 = (t * 2) >> 2, c0 = (t * 2) & 3;
    const int r1 = (t * 2 + 1) >> 2, c1 = (t * 2 + 1) & 3;
    const int aoff0 = r0 * 32 + ((c0 ^ ((r0 >> 1) & 3)) << 3);
    const int aoff1 = r1 * 32 + ((c1 ^ ((r1 >> 1) & 3)) << 3);
    const int arow0 = row0 + r0, arow1 = row0 + r1;

    s16x8 p0 = {0,0,0,0,0,0,0,0}, p1 = {0,0,0,0,0,0,0,0};
    if (arow0 < nrows) p0 = *(const s16x8*)(A1 + (size_t)arow0 * 256 + c0 * 8);
    if (arow1 < nrows) p1 = *(const s16x8*)(A1 + (size_t)arow1 * 256 + c1 * 8);

    for (int k0 = 0; k0 < 256; k0 += 32) {
        {
            s16x8 hh, ll;
#pragma unroll
            for (int j = 0; j < 8; ++j) {
                float v = h2f(p0[j]);
                short hs = bfhi(v);
                hh[j] = hs; ll[j] = bfhi(v - bf2f(hs));
            }
            *(s16x8*)&Ah[aoff0] = hh; *(s16x8*)&Al[aoff0] = ll;
#pragma unroll
            for (int j = 0; j < 8; ++j) {
                float v = h2f(p1[j]);
                short hs = bfhi(v);
                hh[j] = hs; ll[j] = bfhi(v - bf2f(hs));
            }
            *(s16x8*)&Ah[aoff1] = hh; *(s16x8*)&Al[aoff1] = ll;
        }
#pragma unroll
        for (int u = 0; u < 2; ++u) {
            int idx = t * 2 + u;
            int n = idx >> 2, c = idx & 3;
            s16x8 h = *(const s16x8*)(Wthi + (size_t)n * 256 + k0 + c * 8);
            s16x8 l = *(const s16x8*)(Wtlo + (size_t)n * 256 + k0 + c * 8);
            int off = n * 32 + ((c ^ ((n >> 1) & 3)) << 3);
            *(s16x8*)&Bh[off] = h;
            *(s16x8*)&Bl[off] = l;
        }
        __syncthreads();
        if (k0 + 32 < 256) {
            p0 = s16x8{0,0,0,0,0,0,0,0}; p1 = s16x8{0,0,0,0,0,0,0,0};
            if (arow0 < nrows) p0 = *(const s16x8*)(A1 + (size_t)arow0 * 256 + k0 + 32 + c0 * 8);
            if (arow1 < nrows) p1 = *(const s16x8*)(A1 + (size_t)arow1 * 256 + k0 + 32 + c1 * 8);
        }
        int fr = lane & 15, ac = lane >> 4;
        s16x8 afh[4], afl[4], bfh[4], bfl[4];
#pragma unroll
        for (int i = 0; i < 4; ++i) {
            int rr = wm * 64 + i * 16 + fr;
            int off = rr * 32 + ((ac ^ ((rr >> 1) & 3)) << 3);
            afh[i] = *(const s16x8*)&Ah[off];
            afl[i] = *(const s16x8*)&Al[off];
        }
#pragma unroll
        for (int j = 0; j < 4; ++j) {
            int n = wn * 64 + j * 16 + fr;
            int off = n * 32 + ((ac ^ ((n >> 1) & 3)) << 3);
            bfh[j] = *(const s16x8*)&Bh[off];
            bfl[j] = *(const s16x8*)&Bl[off];
        }
#pragma unroll
        for (int i = 0; i < 4; ++i)
#pragma unroll
            for (int j = 0; j < 4; ++j) {
                acc[i][j] = __builtin_amdgcn_mfma_f32_16x16x32_bf16(afh[i], bfh[j], acc[i][j], 0, 0, 0);
                acc[i][j] = __builtin_amdgcn_mfma_f32_16x16x32_bf16(afh[i], bfl[j], acc[i][j], 0, 0, 0);
                acc[i][j] = __builtin_amdgcn_mfma_f32_16x16x32_bf16(afl[i], bfh[j], acc[i][j], 0, 0, 0);
            }
        __syncthreads();
    }

    float* wp = (float*)&Ah[0];
    if (t < 3) wp[t] = 0.f;
    __syncthreads();
    int fr = lane & 15, ac = lane >> 4;
    if (wn == 0) {
        float b1v[4], w2v[4];
#pragma unroll
        for (int j = 0; j < 4; ++j) {
            int col = j * 16 + fr;
            b1v[j] = b1[col];
            w2v[j] = w2[col];
        }
#pragma unroll
        for (int i = 0; i < 4; ++i)
#pragma unroll
            for (int q = 0; q < 4; ++q) {
                float ep = tanhf(acc[i][0][q] + b1v[0]) * w2v[0]
                         + tanhf(acc[i][1][q] + b1v[1]) * w2v[1]
                         + tanhf(acc[i][2][q] + b1v[2]) * w2v[2]
                         + tanhf(acc[i][3][q] + b1v[3]) * w2v[3];
#pragma unroll
                for (int msk = 1; msk < 16; msk <<= 1) ep += __shfl_xor(ep, msk);
                if (fr == 0) {
                    int row = row0 + wm * 64 + i * 16 + ac * 4 + q;
                    if (row < nrows) atomicAdd(&wp[row / NN], ep);
                }
            }
    } else {
#pragma unroll
        for (int i = 0; i < 4; ++i) {
            int rbase = row0 + wm * 64 + i * 16 + ac * 4;
#pragma unroll
            for (int j = 0; j < 4; ++j) {
                int pcol = j * 16 + fr;
#pragma unroll
                for (int q = 0; q < 4; ++q) {
                    int row = rbase + q;
                    if (row < nrows) P[(size_t)row * 64 + pcol] = acc[i][j][q];
                }
            }
        }
    }
    __syncthreads();
    if (t < 3) atomicAdd(&wsum[t], wp[t]);
}

// ---------------- edge-softmax aggregation (metapath-merged, fp16 out) ------

__global__ __launch_bounds__(256) void agg_edges_kernel(const half_t* __restrict__ featA,
                                                        const float* __restrict__ elA,
                                                        const float* __restrict__ erA,
                                                        const int* __restrict__ row_ptrA,
                                                        const int* __restrict__ ssrcA,
                                                        const float* __restrict__ biasL,
                                                        half_t* __restrict__ HbA) {
    const int m = blockIdx.y;
    const half_t* feat = featA + (size_t)m * NN * 256;
    const float* el = elA + (size_t)m * NN * 4;
    const float* er = erA + (size_t)m * NN * 4;
    const int* row_ptr = row_ptrA + (size_t)m * (NN + 1);
    const int* ssrc = ssrcA + (size_t)m * EE;
    const float* bias = biasL + m * 256;
    half_t* out = HbA + (size_t)m * NN * 256;

    int wave = threadIdx.x >> 6;
    int lane = threadIdx.x & 63;
    int n = blockIdx.x * 2 + (wave >> 1);
    int w = wave & 1;
    int h = 2 * w + (lane >> 5);
    int elem = (lane & 31) * 2;
    int beg = row_ptr[n], end = row_ptr[n + 1];
    float ern = er[n * 4 + h];
    const h16x2* fb = (const h16x2*)feat + w * 64 + lane;
    float accA0 = 0.f, accA1 = 0.f, denA = 0.f;
    float accB0 = 0.f, accB1 = 0.f, denB = 0.f;
    int j = beg;
    for (; j + 1 < end; j += 2) {
        int sA = ssrc[j], sB = ssrc[j + 1];
        float eA = el[sA * 4 + h];
        float eB = el[sB * 4 + h];
        h16x2 fA = fb[(size_t)sA * 128];
        h16x2 fB = fb[(size_t)sB * 128];
        eA += ern; eA = eA > 0.f ? eA : 0.2f * eA; float wA = __expf(eA);
        eB += ern; eB = eB > 0.f ? eB : 0.2f * eB; float wB = __expf(eB);
        accA0 = fmaf(wA, (float)fA.x, accA0);
        accA1 = fmaf(wA, (float)fA.y, accA1); denA += wA;
        accB0 = fmaf(wB, (float)fB.x, accB0);
        accB1 = fmaf(wB, (float)fB.y, accB1); denB += wB;
    }
    if (j < end) {
        int s = ssrc[j];
        float e = el[s * 4 + h] + ern;
        e = e > 0.f ? e : 0.2f * e;
        float wgt = __expf(e);
        h16x2 f = fb[(size_t)s * 128];
        accA0 = fmaf(wgt, (float)f.x, accA0);
        accA1 = fmaf(wgt, (float)f.y, accA1); denA += wgt;
    }
    float den = fmaxf(denA + denB, 1e-9f);
    float o0 = (accA0 + accB0) / den + bias[h * 64 + elem];
    float o1 = (accA1 + accB1) / den + bias[h * 64 + elem + 1];
    o0 = o0 > 0.f ? o0 : __expf(o0) - 1.0f;
    o1 = o1 > 0.f ? o1 : __expf(o1) - 1.0f;
    size_t idx = (size_t)n * 256 + h * 64 + elem;
    h16x2 ov; ov.x = (half_t)o0; ov.y = (half_t)o1;
    *(h16x2*)&out[idx] = ov;
}

// ---------------- beta + final combine ----------------

__global__ void beta_kernel(const float* __restrict__ wsum, float* __restrict__ beta) {
    if (threadIdx.x == 0 && blockIdx.x == 0) {
        float w0 = wsum[0] / (float)NN, w1 = wsum[1] / (float)NN, w2 = wsum[2] / (float)NN;
        float mx = fmaxf(w0, fmaxf(w1, w2));
        float e0 = __expf(w0 - mx), e1 = __expf(w1 - mx), e2 = __expf(w2 - mx);
        float s = e0 + e1 + e2;
        beta[0] = e0 / s; beta[1] = e1 / s; beta[2] = e2 / s;
    }
}

__global__ __launch_bounds__(256) void combine_out_kernel(const float* __restrict__ P,
                                                          const float* __restrict__ beta,
                                                          const float* __restrict__ bp,
                                                          float* __restrict__ out) {
    int idx4 = blockIdx.x * 256 + threadIdx.x;
    if (idx4 >= NN * 64 / 4) return;
    float b0 = beta[0], b1 = beta[1], b2 = beta[2];
    float4 p0 = ((const float4*)P)[idx4];
    float4 p1 = ((const float4*)P)[idx4 + NN * 16];
    float4 p2 = ((const float4*)P)[idx4 + NN * 32];
    float4 bpv = *(const float4*)(bp + ((idx4 * 4) & 63));
    float4 o;
    o.x = b0 * p0.x + b1 * p1.x + b2 * p2.x + bpv.x;
    o.y = b0 * p0.y + b1 * p1.y + b2 * p2.y + bpv.y;
    o.z = b0 * p0.z + b1 * p1.z + b2 * p2.z + bpv.z;
    o.w = b0 * p0.w + b1 * p1.w + b2 * p2.w + bpv.w;
    ((float4*)out)[idx4] = o;
}

// ---------------- host launch ----------------

extern "C" void kernel_launch(void* const* d_in, const int* in_sizes, int n_in,
                              void* d_out, int out_size, void* d_ws, size_t ws_size,
                              hipStream_t stream) {
    const float* x        = (const float*)d_in[0];
    const float* W_gat    = (const float*)d_in[1];
    const float* attn_l   = (const float*)d_in[2];
    const float* attn_r   = (const float*)d_in[3];
    const float* bias_gat = (const float*)d_in[4];
    const float* W1       = (const float*)d_in[5];
    const float* b1       = (const float*)d_in[6];
    const float* W2       = (const float*)d_in[7];
    const float* Wp       = (const float*)d_in[8];
    const float* bp       = (const float*)d_in[9];
    const int*   src      = (const int*)d_in[10];
    const int*   dst      = (const int*)d_in[11];
    float* out = (float*)d_out;

    char* ws = (char*)d_ws;
    size_t off = 0;
    auto alloc = [&](size_t bytes) { size_t o = off; off = (off + bytes + 255) & ~(size_t)255; return o; };
    half_t* Hb      = (half_t*)(ws + alloc((size_t)MM * NN * 256 * 2));
    half_t* feat    = (half_t*)(ws + alloc((size_t)MM * NN * 256 * 2));
    float*  P       = (float*)(ws + alloc((size_t)MM * NN * 64 * 4));
    float*  el      = (float*)(ws + alloc((size_t)MM * NN * 4 * 4));
    float*  er      = (float*)(ws + alloc((size_t)MM * NN * 4 * 4));
    int*    counts  = (int*)(ws + alloc((size_t)MM * NN * 4));
    int*    row_ptr = (int*)(ws + alloc((size_t)MM * (NN + 1) * 4));
    int*    cursor  = (int*)(ws + alloc((size_t)MM * (NN + 1) * 4));
    int*    ssrc    = (int*)(ws + alloc((size_t)MM * EE * 4));
    int*    bsum    = (int*)(ws + alloc((size_t)MM * NCHUNK * 4));
    short*  Whi     = (short*)(ws + alloc((size_t)W_TOT * 2));
    short*  Wlo     = (short*)(ws + alloc((size_t)W_TOT * 2));
    float*  wsum    = (float*)(ws + alloc(16));
    float*  beta    = (float*)(ws + alloc(16));

    init_kernel<<<dim3((MM * NN + 255) / 256), 256, 0, stream>>>(counts, wsum);
    hist_kernel<<<dim3((EE + 255) / 256, MM), 256, 0, stream>>>(dst, counts);
    scan_partial_kernel<<<dim3(NCHUNK, MM), 256, 0, stream>>>(counts, row_ptr, bsum);
    scan_top_kernel<<<dim3(1), 256, 0, stream>>>(bsum);
    scan_add_kernel<<<dim3(NCHUNK, MM), 256, 0, stream>>>(bsum, row_ptr, cursor);
    scatter_kernel<<<dim3((EE + 255) / 256, MM), 256, 0, stream>>>(src, dst, cursor, ssrc);
    splitW_kernel<<<dim3((W_TOT + 255) / 256), 256, 0, stream>>>(W_gat, W1, Wp, Whi, Wlo);

    const int rowTiles = (NN + 63) / 64;

    for (int l = 0; l < 2; ++l) {
        const short* wh = Whi + (size_t)l * MM * 65536;
        const short* wl = Wlo + (size_t)l * MM * 65536;
        const float* alp = attn_l + (size_t)l * MM * 256;
        const float* arp = attn_r + (size_t)l * MM * 256;
        if (l == 0)
            mfma_gemm<0><<<dim3(rowTiles, MM), 256, 0, stream>>>(
                x, nullptr, wh, wl, feat, alp, arp, el, er);
        else
            mfma_gemm<1><<<dim3(rowTiles, MM), 256, 0, stream>>>(
                nullptr, Hb, wh, wl, feat, alp, arp, el, er);
        agg_edges_kernel<<<dim3(NN / 2, MM), 256, 0, stream>>>(
            feat, el, er, row_ptr, ssrc, bias_gat + (size_t)l * MM * 256, Hb);
    }

    // merged semantic + projection pass over all 3 metapaths (Hb contiguous)
    sem_gemm<<<dim3((MM * NN + 127) / 128), 256, 0, stream>>>(
        Hb, Whi + WG_ELEMS, Wlo + WG_ELEMS, P, b1, W2, wsum, MM * NN);
    beta_kernel<<<dim3(1), 64, 0, stream>>>(wsum, beta);
    combine_out_kernel<<<dim3((NN * 16 + 255) / 256), 256, 0, stream>>>(P, beta, bp, out);
}

// Round 10
// 666.922 us; speedup vs baseline: 5.3614x; 1.1935x over previous
//
#include <hip/hip_runtime.h>

#define NN 50000
#define EE 400000
#define MM 3
#define CHUNK 2048
#define NCHUNK ((NN + CHUNK - 1) / CHUNK)   // 25

typedef float f32x4 __attribute__((ext_vector_type(4)));
typedef short s16x8 __attribute__((ext_vector_type(8)));
typedef _Float16 half_t;
typedef _Float16 h16x2 __attribute__((ext_vector_type(2)));
typedef _Float16 h16x4 __attribute__((ext_vector_type(4)));

union FU { float f; unsigned u; };

__device__ inline short bfhi(float x) {
    FU c; c.f = x;
    unsigned u = c.u;
    return (short)((u + 0x7fffu + ((u >> 16) & 1u)) >> 16);
}
__device__ inline float bf2f(short h) {
    FU c; c.u = ((unsigned)(unsigned short)h) << 16;
    return c.f;
}
__device__ inline float h2f(short bits) {
    union HU { short s; _Float16 h; } u; u.s = bits; return (float)u.h;
}

// ---------------- CSR build ----------------

__global__ __launch_bounds__(256) void init_kernel(int* counts, float* wsum) {
    int idx = blockIdx.x * 256 + threadIdx.x;
    if (idx < MM * NN) counts[idx] = 0;
    if (idx < MM) wsum[idx] = 0.0f;
}

__global__ __launch_bounds__(256) void hist_kernel(const int* __restrict__ dst,
                                                   int* __restrict__ counts) {
    int m = blockIdx.y;
    int e = blockIdx.x * 256 + threadIdx.x;
    if (e < EE) atomicAdd(&counts[m * NN + dst[m * EE + e]], 1);
}

__global__ __launch_bounds__(256) void scan_partial_kernel(const int* __restrict__ counts,
                                                           int* __restrict__ rp,
                                                           int* __restrict__ bsum) {
    int m = blockIdx.y, ch = blockIdx.x;
    const int* c = counts + m * NN;
    int* r = rp + m * (NN + 1);
    int t = threadIdx.x, lane = t & 63, wave = t >> 6;
    int i0 = ch * CHUNK + t * 8;
    int v[8]; int s = 0;
#pragma unroll
    for (int k = 0; k < 8; ++k) { int i = i0 + k; v[k] = (i < NN) ? c[i] : 0; s += v[k]; }
    int incl = s;
#pragma unroll
    for (int off = 1; off < 64; off <<= 1) {
        int u = __shfl_up(incl, off);
        if (lane >= off) incl += u;
    }
    int excl = incl - s;
    __shared__ int wsh[4];
    if (lane == 63) wsh[wave] = incl;
    __syncthreads();
    int woff = 0;
    for (int w = 0; w < wave; ++w) woff += wsh[w];
    int run = excl + woff;
#pragma unroll
    for (int k = 0; k < 8; ++k) { int i = i0 + k; if (i < NN) r[i] = run; run += v[k]; }
    if (t == 255) bsum[m * NCHUNK + ch] = woff + incl;
}

__global__ __launch_bounds__(256) void scan_top_kernel(int* __restrict__ bsum) {
    int wave = threadIdx.x >> 6, lane = threadIdx.x & 63;
    if (wave < MM) {
        int v = (lane < NCHUNK) ? bsum[wave * NCHUNK + lane] : 0;
        int incl = v;
#pragma unroll
        for (int off = 1; off < 64; off <<= 1) {
            int u = __shfl_up(incl, off);
            if (lane >= off) incl += u;
        }
        if (lane < NCHUNK) bsum[wave * NCHUNK + lane] = incl - v;
    }
}

__global__ __launch_bounds__(256) void scan_add_kernel(const int* __restrict__ bsum,
                                                       int* __restrict__ rp,
                                                       int* __restrict__ cur) {
    int m = blockIdx.y, ch = blockIdx.x;
    int off = bsum[m * NCHUNK + ch];
    int* r = rp + m * (NN + 1);
    int* q = cur + m * (NN + 1);
    int i0 = ch * CHUNK + threadIdx.x * 8;
#pragma unroll
    for (int k = 0; k < 8; ++k) {
        int i = i0 + k;
        if (i < NN) { int val = r[i] + off; r[i] = val; q[i] = val; }
    }
    if (ch == 0 && threadIdx.x == 0) r[NN] = EE;
}

__global__ __launch_bounds__(256) void scatter_kernel(const int* __restrict__ src,
                                                      const int* __restrict__ dst,
                                                      int* __restrict__ cursor,
                                                      int* __restrict__ ssrc) {
    int m = blockIdx.y;
    int e = blockIdx.x * 256 + threadIdx.x;
    if (e < EE) {
        int d = dst[m * EE + e];
        int pos = atomicAdd(&cursor[m * (NN + 1) + d], 1);
        __builtin_nontemporal_store(src[m * EE + e], &ssrc[m * EE + pos]);
    }
}

// ---------------- weight transpose + split ----------------
// Layout: [6][256n][256k] W_gat, then [128n][256k] sem weights (64 W1 | 64 Wp).

#define WG_ELEMS (6 * 256 * 256)
#define W_TOT (WG_ELEMS + 128 * 256)

__global__ __launch_bounds__(256) void splitW_kernel(const float* __restrict__ Wg,
                                                     const float* __restrict__ W1,
                                                     const float* __restrict__ Wp,
                                                     short* __restrict__ Whi,
                                                     short* __restrict__ Wlo) {
    int idx = blockIdx.x * 256 + threadIdx.x;
    if (idx >= W_TOT) return;
    float v;
    if (idx < WG_ELEMS) {
        int mat = idx >> 16, rem = idx & 65535;
        int n = rem >> 8, k = rem & 255;
        v = Wg[mat * 65536 + k * 256 + n];
    } else {
        int i2 = idx - WG_ELEMS;
        int n = i2 >> 8, k = i2 & 255;
        v = (n < 64) ? W1[k * 64 + n] : Wp[k * 64 + n - 64];
    }
    short h = bfhi(v);
    Whi[idx] = h;
    Wlo[idx] = bfhi(v - bf2f(h));
}

// ---------------- main MFMA GEMM: BM=64 x BN=256, metapath-merged ----------

template<int AMODE>
__global__ __launch_bounds__(256) void mfma_gemm(
    const float* __restrict__ Af, const half_t* __restrict__ A16,
    const short* __restrict__ Wthi, const short* __restrict__ Wtlo,
    half_t* __restrict__ featA,
    const float* __restrict__ alA, const float* __restrict__ arA,
    float* __restrict__ elA, float* __restrict__ erA) {
    __shared__ short Ah[64 * 32], Al[64 * 32], Bh[256 * 32], Bl[256 * 32];  // 40960 B
    const int m = blockIdx.y;
    const int t = threadIdx.x;
    const int lane = t & 63;
    const int wn = t >> 6;
    const int row0 = blockIdx.x * 64;
    const float*  A0 = Af + (size_t)m * NN * 256;
    const short*  A1 = (const short*)(A16 + (size_t)m * NN * 256);
    const short*  Bgh = Wthi + (size_t)m * 65536;
    const short*  Bgl = Wtlo + (size_t)m * 65536;
    half_t* Ch = featA + (size_t)m * NN * 256;
    const float* al = alA + m * 256;
    const float* ar = arA + m * 256;
    float* el = elA + (size_t)m * NN * 4;
    float* er = erA + (size_t)m * NN * 4;
    f32x4 acc[4][4] = {};

    const int r = t >> 2, c0 = t & 3;
    const int aoff = r * 32 + ((c0 ^ ((r >> 1) & 3)) << 3);
    const int arow = row0 + r;
    const bool aval = (arow < NN);

    s16x8 praw = {0,0,0,0,0,0,0,0};
    float4 pf0 = make_float4(0.f,0.f,0.f,0.f), pf1 = make_float4(0.f,0.f,0.f,0.f);

    if (AMODE == 1) {
        if (aval) praw = *(const s16x8*)(A1 + (size_t)arow * 256 + c0 * 8);
    } else {
        if (aval) {
            pf0 = *(const float4*)(A0 + (size_t)arow * 256 + c0 * 8);
            pf1 = *(const float4*)(A0 + (size_t)arow * 256 + c0 * 8 + 4);
        }
    }

    for (int k0 = 0; k0 < 256; k0 += 32) {
        {
            float v[8];
            if (AMODE == 1) {
#pragma unroll
                for (int j = 0; j < 8; ++j) v[j] = h2f(praw[j]);
            } else {
                v[0] = pf0.x; v[1] = pf0.y; v[2] = pf0.z; v[3] = pf0.w;
                v[4] = pf1.x; v[5] = pf1.y; v[6] = pf1.z; v[7] = pf1.w;
            }
            s16x8 hh, ll;
#pragma unroll
            for (int j = 0; j < 8; ++j) {
                short hs = bfhi(v[j]);
                hh[j] = hs;
                ll[j] = bfhi(v[j] - bf2f(hs));
            }
            *(s16x8*)&Ah[aoff] = hh;
            *(s16x8*)&Al[aoff] = ll;
        }
#pragma unroll
        for (int u = 0; u < 4; ++u) {
            int n = u * 64 + (t >> 2), c = t & 3;
            s16x8 h = *(const s16x8*)(Bgh + (size_t)n * 256 + k0 + c * 8);
            s16x8 l = *(const s16x8*)(Bgl + (size_t)n * 256 + k0 + c * 8);
            int off = n * 32 + ((c ^ ((n >> 1) & 3)) << 3);
            *(s16x8*)&Bh[off] = h;
            *(s16x8*)&Bl[off] = l;
        }
        __syncthreads();
        if (k0 + 32 < 256) {
            if (AMODE == 1) {
                praw = s16x8{0,0,0,0,0,0,0,0};
                if (aval) praw = *(const s16x8*)(A1 + (size_t)arow * 256 + k0 + 32 + c0 * 8);
            } else {
                pf0 = make_float4(0.f,0.f,0.f,0.f); pf1 = make_float4(0.f,0.f,0.f,0.f);
                if (aval) {
                    pf0 = *(const float4*)(A0 + (size_t)arow * 256 + k0 + 32 + c0 * 8);
                    pf1 = *(const float4*)(A0 + (size_t)arow * 256 + k0 + 32 + c0 * 8 + 4);
                }
            }
        }
        int fr = lane & 15, ac = lane >> 4;
        s16x8 afh[4], afl[4], bfh[4], bfl[4];
#pragma unroll
        for (int i = 0; i < 4; ++i) {
            int rr = i * 16 + fr;
            int off = rr * 32 + ((ac ^ ((rr >> 1) & 3)) << 3);
            afh[i] = *(const s16x8*)&Ah[off];
            afl[i] = *(const s16x8*)&Al[off];
        }
#pragma unroll
        for (int j = 0; j < 4; ++j) {
            int n = wn * 64 + j * 16 + fr;
            int off = n * 32 + ((ac ^ ((n >> 1) & 3)) << 3);
            bfh[j] = *(const s16x8*)&Bh[off];
            bfl[j] = *(const s16x8*)&Bl[off];
        }
#pragma unroll
        for (int i = 0; i < 4; ++i)
#pragma unroll
            for (int j = 0; j < 4; ++j) {
                acc[i][j] = __builtin_amdgcn_mfma_f32_16x16x32_bf16(afh[i], bfh[j], acc[i][j], 0, 0, 0);
                acc[i][j] = __builtin_amdgcn_mfma_f32_16x16x32_bf16(afh[i], bfl[j], acc[i][j], 0, 0, 0);
                acc[i][j] = __builtin_amdgcn_mfma_f32_16x16x32_bf16(afl[i], bfh[j], acc[i][j], 0, 0, 0);
            }
        __syncthreads();
    }

#pragma unroll
    for (int i = 0; i < 4; ++i) {
        int rbase = row0 + i * 16 + (lane >> 4) * 4;
#pragma unroll
        for (int j = 0; j < 4; ++j) {
            int col = wn * 64 + j * 16 + (lane & 15);
#pragma unroll
            for (int q = 0; q < 4; ++q) {
                int row = rbase + q;
                if (row < NN) Ch[(size_t)row * 256 + col] = (half_t)acc[i][j][q];
            }
        }
    }
    float alv[4], arv[4];
#pragma unroll
    for (int j = 0; j < 4; ++j) {
        int col = wn * 64 + j * 16 + (lane & 15);
        alv[j] = al[col];
        arv[j] = ar[col];
    }
#pragma unroll
    for (int i = 0; i < 4; ++i)
#pragma unroll
        for (int q = 0; q < 4; ++q) {
            float ep = acc[i][0][q] * alv[0] + acc[i][1][q] * alv[1]
                     + acc[i][2][q] * alv[2] + acc[i][3][q] * alv[3];
            float rp_ = acc[i][0][q] * arv[0] + acc[i][1][q] * arv[1]
                      + acc[i][2][q] * arv[2] + acc[i][3][q] * arv[3];
#pragma unroll
            for (int msk = 1; msk < 16; msk <<= 1) {
                ep += __shfl_xor(ep, msk);
                rp_ += __shfl_xor(rp_, msk);
            }
            if ((lane & 15) == 0) {
                int row = row0 + i * 16 + (lane >> 4) * 4 + q;
                if (row < NN) {
                    el[row * 4 + wn] = ep;
                    er[row * 4 + wn] = rp_;
                }
            }
        }
}

// ---------------- semantic GEMM: BM=128 x BN=128, fp16 A ----------------

__global__ __launch_bounds__(256) void sem_gemm(
    const half_t* __restrict__ A16,
    const short* __restrict__ Wthi, const short* __restrict__ Wtlo,
    float* __restrict__ P,
    const float* __restrict__ b1, const float* __restrict__ w2,
    float* __restrict__ wsum,
    int nrows) {
    __shared__ short Ah[128 * 32], Al[128 * 32], Bh[128 * 32], Bl[128 * 32]; // 32 KB
    const int t = threadIdx.x;
    const int lane = t & 63;
    const int wave = t >> 6;
    const int wm = wave >> 1, wn = wave & 1;
    const int row0 = blockIdx.x * 128;
    const short* A1 = (const short*)A16;
    f32x4 acc[4][4] = {};

    const int r0 = (t * 2) >> 2, c0 = (t * 2) & 3;
    const int r1 = (t * 2 + 1) >> 2, c1 = (t * 2 + 1) & 3;
    const int aoff0 = r0 * 32 + ((c0 ^ ((r0 >> 1) & 3)) << 3);
    const int aoff1 = r1 * 32 + ((c1 ^ ((r1 >> 1) & 3)) << 3);
    const int arow0 = row0 + r0, arow1 = row0 + r1;

    s16x8 p0 = {0,0,0,0,0,0,0,0}, p1 = {0,0,0,0,0,0,0,0};
    if (arow0 < nrows) p0 = *(const s16x8*)(A1 + (size_t)arow0 * 256 + c0 * 8);
    if (arow1 < nrows) p1 = *(const s16x8*)(A1 + (size_t)arow1 * 256 + c1 * 8);

    for (int k0 = 0; k0 < 256; k0 += 32) {
        {
            s16x8 hh, ll;
#pragma unroll
            for (int j = 0; j < 8; ++j) {
                float v = h2f(p0[j]);
                short hs = bfhi(v);
                hh[j] = hs; ll[j] = bfhi(v - bf2f(hs));
            }
            *(s16x8*)&Ah[aoff0] = hh; *(s16x8*)&Al[aoff0] = ll;
#pragma unroll
            for (int j = 0; j < 8; ++j) {
                float v = h2f(p1[j]);
                short hs = bfhi(v);
                hh[j] = hs; ll[j] = bfhi(v - bf2f(hs));
            }
            *(s16x8*)&Ah[aoff1] = hh; *(s16x8*)&Al[aoff1] = ll;
        }
#pragma unroll
        for (int u = 0; u < 2; ++u) {
            int idx = t * 2 + u;
            int n = idx >> 2, c = idx & 3;
            s16x8 h = *(const s16x8*)(Wthi + (size_t)n * 256 + k0 + c * 8);
            s16x8 l = *(const s16x8*)(Wtlo + (size_t)n * 256 + k0 + c * 8);
            int off = n * 32 + ((c ^ ((n >> 1) & 3)) << 3);
            *(s16x8*)&Bh[off] = h;
            *(s16x8*)&Bl[off] = l;
        }
        __syncthreads();
        if (k0 + 32 < 256) {
            p0 = s16x8{0,0,0,0,0,0,0,0}; p1 = s16x8{0,0,0,0,0,0,0,0};
            if (arow0 < nrows) p0 = *(const s16x8*)(A1 + (size_t)arow0 * 256 + k0 + 32 + c0 * 8);
            if (arow1 < nrows) p1 = *(const s16x8*)(A1 + (size_t)arow1 * 256 + k0 + 32 + c1 * 8);
        }
        int fr = lane & 15, ac = lane >> 4;
        s16x8 afh[4], afl[4], bfh[4], bfl[4];
#pragma unroll
        for (int i = 0; i < 4; ++i) {
            int rr = wm * 64 + i * 16 + fr;
            int off = rr * 32 + ((ac ^ ((rr >> 1) & 3)) << 3);
            afh[i] = *(const s16x8*)&Ah[off];
            afl[i] = *(const s16x8*)&Al[off];
        }
#pragma unroll
        for (int j = 0; j < 4; ++j) {
            int n = wn * 64 + j * 16 + fr;
            int off = n * 32 + ((ac ^ ((n >> 1) & 3)) << 3);
            bfh[j] = *(const s16x8*)&Bh[off];
            bfl[j] = *(const s16x8*)&Bl[off];
        }
#pragma unroll
        for (int i = 0; i < 4; ++i)
#pragma unroll
            for (int j = 0; j < 4; ++j) {
                acc[i][j] = __builtin_amdgcn_mfma_f32_16x16x32_bf16(afh[i], bfh[j], acc[i][j], 0, 0, 0);
                acc[i][j] = __builtin_amdgcn_mfma_f32_16x16x32_bf16(afh[i], bfl[j], acc[i][j], 0, 0, 0);
                acc[i][j] = __builtin_amdgcn_mfma_f32_16x16x32_bf16(afl[i], bfh[j], acc[i][j], 0, 0, 0);
            }
        __syncthreads();
    }

    float* wp = (float*)&Ah[0];
    if (t < 3) wp[t] = 0.f;
    __syncthreads();
    int fr = lane & 15, ac = lane >> 4;
    if (wn == 0) {
        float b1v[4], w2v[4];
#pragma unroll
        for (int j = 0; j < 4; ++j) {
            int col = j * 16 + fr;
            b1v[j] = b1[col];
            w2v[j] = w2[col];
        }
#pragma unroll
        for (int i = 0; i < 4; ++i)
#pragma unroll
            for (int q = 0; q < 4; ++q) {
                float ep = tanhf(acc[i][0][q] + b1v[0]) * w2v[0]
                         + tanhf(acc[i][1][q] + b1v[1]) * w2v[1]
                         + tanhf(acc[i][2][q] + b1v[2]) * w2v[2]
                         + tanhf(acc[i][3][q] + b1v[3]) * w2v[3];
#pragma unroll
                for (int msk = 1; msk < 16; msk <<= 1) ep += __shfl_xor(ep, msk);
                if (fr == 0) {
                    int row = row0 + wm * 64 + i * 16 + ac * 4 + q;
                    if (row < nrows) atomicAdd(&wp[row / NN], ep);
                }
            }
    } else {
#pragma unroll
        for (int i = 0; i < 4; ++i) {
            int rbase = row0 + wm * 64 + i * 16 + ac * 4;
#pragma unroll
            for (int j = 0; j < 4; ++j) {
                int pcol = j * 16 + fr;
#pragma unroll
                for (int q = 0; q < 4; ++q) {
                    int row = rbase + q;
                    if (row < nrows) P[(size_t)row * 64 + pcol] = acc[i][j][q];
                }
            }
        }
    }
    __syncthreads();
    if (t < 3) atomicAdd(&wsum[t], wp[t]);
}

// ---------------- edge-softmax aggregation ----------------
// 1 wave per node, all 4 heads, 8 B/lane (h16x4): per-edge scalar work
// (ssrc/el/addr/exp/den) issued ONCE instead of twice; gather instr count
// halved at equal bytes. Unroll x2 = 2 independent gather chains.

__global__ __launch_bounds__(256) void agg_edges_kernel(const half_t* __restrict__ featA,
                                                        const float* __restrict__ elA,
                                                        const float* __restrict__ erA,
                                                        const int* __restrict__ row_ptrA,
                                                        const int* __restrict__ ssrcA,
                                                        const float* __restrict__ biasL,
                                                        half_t* __restrict__ HbA) {
    const int m = blockIdx.y;
    const half_t* feat = featA + (size_t)m * NN * 256;
    const float* el = elA + (size_t)m * NN * 4;
    const float* er = erA + (size_t)m * NN * 4;
    const int* row_ptr = row_ptrA + (size_t)m * (NN + 1);
    const int* ssrc = ssrcA + (size_t)m * EE;
    const float* bias = biasL + m * 256;
    half_t* out = HbA + (size_t)m * NN * 256;

    int wave = threadIdx.x >> 6;
    int lane = threadIdx.x & 63;
    int n = blockIdx.x * 4 + wave;
    int h = lane >> 4;                       // head for this lane's 4 elems
    int beg = row_ptr[n], end = row_ptr[n + 1];
    float ern = er[n * 4 + h];
    const h16x4* fb = (const h16x4*)feat + lane;   // + s*64 per row
    float a0A = 0.f, a1A = 0.f, a2A = 0.f, a3A = 0.f, dA = 0.f;
    float a0B = 0.f, a1B = 0.f, a2B = 0.f, a3B = 0.f, dB = 0.f;
    int j = beg;
    for (; j + 1 < end; j += 2) {
        int sA = ssrc[j], sB = ssrc[j + 1];
        float eA = el[sA * 4 + h];
        float eB = el[sB * 4 + h];
        h16x4 fA = fb[(size_t)sA * 64];
        h16x4 fB = fb[(size_t)sB * 64];
        eA += ern; eA = eA > 0.f ? eA : 0.2f * eA; float wA = __expf(eA);
        eB += ern; eB = eB > 0.f ? eB : 0.2f * eB; float wB = __expf(eB);
        a0A = fmaf(wA, (float)fA.x, a0A); a1A = fmaf(wA, (float)fA.y, a1A);
        a2A = fmaf(wA, (float)fA.z, a2A); a3A = fmaf(wA, (float)fA.w, a3A); dA += wA;
        a0B = fmaf(wB, (float)fB.x, a0B); a1B = fmaf(wB, (float)fB.y, a1B);
        a2B = fmaf(wB, (float)fB.z, a2B); a3B = fmaf(wB, (float)fB.w, a3B); dB += wB;
    }
    if (j < end) {
        int s = ssrc[j];
        float e = el[s * 4 + h] + ern;
        e = e > 0.f ? e : 0.2f * e;
        float wgt = __expf(e);
        h16x4 f = fb[(size_t)s * 64];
        a0A = fmaf(wgt, (float)f.x, a0A); a1A = fmaf(wgt, (float)f.y, a1A);
        a2A = fmaf(wgt, (float)f.z, a2A); a3A = fmaf(wgt, (float)f.w, a3A); dA += wgt;
    }
    float den = fmaxf(dA + dB, 1e-9f);
    int col = lane * 4;
    float o0 = (a0A + a0B) / den + bias[col + 0];
    float o1 = (a1A + a1B) / den + bias[col + 1];
    float o2 = (a2A + a2B) / den + bias[col + 2];
    float o3 = (a3A + a3B) / den + bias[col + 3];
    o0 = o0 > 0.f ? o0 : __expf(o0) - 1.0f;
    o1 = o1 > 0.f ? o1 : __expf(o1) - 1.0f;
    o2 = o2 > 0.f ? o2 : __expf(o2) - 1.0f;
    o3 = o3 > 0.f ? o3 : __expf(o3) - 1.0f;
    h16x4 ov; ov.x = (half_t)o0; ov.y = (half_t)o1; ov.z = (half_t)o2; ov.w = (half_t)o3;
    ((h16x4*)(out + (size_t)n * 256))[lane] = ov;
}

// ---------------- beta + final combine ----------------

__global__ void beta_kernel(const float* __restrict__ wsum, float* __restrict__ beta) {
    if (threadIdx.x == 0 && blockIdx.x == 0) {
        float w0 = wsum[0] / (float)NN, w1 = wsum[1] / (float)NN, w2 = wsum[2] / (float)NN;
        float mx = fmaxf(w0, fmaxf(w1, w2));
        float e0 = __expf(w0 - mx), e1 = __expf(w1 - mx), e2 = __expf(w2 - mx);
        float s = e0 + e1 + e2;
        beta[0] = e0 / s; beta[1] = e1 / s; beta[2] = e2 / s;
    }
}

__global__ __launch_bounds__(256) void combine_out_kernel(const float* __restrict__ P,
                                                          const float* __restrict__ beta,
                                                          const float* __restrict__ bp,
                                                          float* __restrict__ out) {
    int idx4 = blockIdx.x * 256 + threadIdx.x;
    if (idx4 >= NN * 64 / 4) return;
    float b0 = beta[0], b1 = beta[1], b2 = beta[2];
    float4 p0 = ((const float4*)P)[idx4];
    float4 p1 = ((const float4*)P)[idx4 + NN * 16];
    float4 p2 = ((const float4*)P)[idx4 + NN * 32];
    float4 bpv = *(const float4*)(bp + ((idx4 * 4) & 63));
    float4 o;
    o.x = b0 * p0.x + b1 * p1.x + b2 * p2.x + bpv.x;
    o.y = b0 * p0.y + b1 * p1.y + b2 * p2.y + bpv.y;
    o.z = b0 * p0.z + b1 * p1.z + b2 * p2.z + bpv.z;
    o.w = b0 * p0.w + b1 * p1.w + b2 * p2.w + bpv.w;
    ((float4*)out)[idx4] = o;
}

// ---------------- host launch ----------------

extern "C" void kernel_launch(void* const* d_in, const int* in_sizes, int n_in,
                              void* d_out, int out_size, void* d_ws, size_t ws_size,
                              hipStream_t stream) {
    const float* x        = (const float*)d_in[0];
    const float* W_gat    = (const float*)d_in[1];
    const float* attn_l   = (const float*)d_in[2];
    const float* attn_r   = (const float*)d_in[3];
    const float* bias_gat = (const float*)d_in[4];
    const float* W1       = (const float*)d_in[5];
    const float* b1       = (const float*)d_in[6];
    const float* W2       = (const float*)d_in[7];
    const float* Wp       = (const float*)d_in[8];
    const float* bp       = (const float*)d_in[9];
    const int*   src      = (const int*)d_in[10];
    const int*   dst      = (const int*)d_in[11];
    float* out = (float*)d_out;

    char* ws = (char*)d_ws;
    size_t off = 0;
    auto alloc = [&](size_t bytes) { size_t o = off; off = (off + bytes + 255) & ~(size_t)255; return o; };
    half_t* Hb      = (half_t*)(ws + alloc((size_t)MM * NN * 256 * 2));
    half_t* feat    = (half_t*)(ws + alloc((size_t)MM * NN * 256 * 2));
    float*  P       = (float*)(ws + alloc((size_t)MM * NN * 64 * 4));
    float*  el      = (float*)(ws + alloc((size_t)MM * NN * 4 * 4));
    float*  er      = (float*)(ws + alloc((size_t)MM * NN * 4 * 4));
    int*    counts  = (int*)(ws + alloc((size_t)MM * NN * 4));
    int*    row_ptr = (int*)(ws + alloc((size_t)MM * (NN + 1) * 4));
    int*    cursor  = (int*)(ws + alloc((size_t)MM * (NN + 1) * 4));
    int*    ssrc    = (int*)(ws + alloc((size_t)MM * EE * 4));
    int*    bsum    = (int*)(ws + alloc((size_t)MM * NCHUNK * 4));
    short*  Whi     = (short*)(ws + alloc((size_t)W_TOT * 2));
    short*  Wlo     = (short*)(ws + alloc((size_t)W_TOT * 2));
    float*  wsum    = (float*)(ws + alloc(16));
    float*  beta    = (float*)(ws + alloc(16));

    init_kernel<<<dim3((MM * NN + 255) / 256), 256, 0, stream>>>(counts, wsum);
    hist_kernel<<<dim3((EE + 255) / 256, MM), 256, 0, stream>>>(dst, counts);
    scan_partial_kernel<<<dim3(NCHUNK, MM), 256, 0, stream>>>(counts, row_ptr, bsum);
    scan_top_kernel<<<dim3(1), 256, 0, stream>>>(bsum);
    scan_add_kernel<<<dim3(NCHUNK, MM), 256, 0, stream>>>(bsum, row_ptr, cursor);
    scatter_kernel<<<dim3((EE + 255) / 256, MM), 256, 0, stream>>>(src, dst, cursor, ssrc);
    splitW_kernel<<<dim3((W_TOT + 255) / 256), 256, 0, stream>>>(W_gat, W1, Wp, Whi, Wlo);

    const int rowTiles = (NN + 63) / 64;

    for (int l = 0; l < 2; ++l) {
        const short* wh = Whi + (size_t)l * MM * 65536;
        const short* wl = Wlo + (size_t)l * MM * 65536;
        const float* alp = attn_l + (size_t)l * MM * 256;
        const float* arp = attn_r + (size_t)l * MM * 256;
        if (l == 0)
            mfma_gemm<0><<<dim3(rowTiles, MM), 256, 0, stream>>>(
                x, nullptr, wh, wl, feat, alp, arp, el, er);
        else
            mfma_gemm<1><<<dim3(rowTiles, MM), 256, 0, stream>>>(
                nullptr, Hb, wh, wl, feat, alp, arp, el, er);
        agg_edges_kernel<<<dim3(NN / 4, MM), 256, 0, stream>>>(
            feat, el, er, row_ptr, ssrc, bias_gat + (size_t)l * MM * 256, Hb);
    }

    // merged semantic + projection pass over all 3 metapaths (Hb contiguous)
    sem_gemm<<<dim3((MM * NN + 127) / 128), 256, 0, stream>>>(
        Hb, Whi + WG_ELEMS, Wlo + WG_ELEMS, P, b1, W2, wsum, MM * NN);
    beta_kernel<<<dim3(1), 64, 0, stream>>>(wsum, beta);
    combine_out_kernel<<<dim3((NN * 16 + 255) / 256), 256, 0, stream>>>(P, beta, bp, out);
}